// Round 11
// baseline (1091.741 us; speedup 1.0000x reference)
//
#include <hip/hip_runtime.h>
#include <cmath>

#define B_ 8
#define T_ 2048
#define BT_ 16384
#define D_ 512
#define H_ 1536
#define CM_ 192
#define KE_ 1344      // embed K = 192*7 (divisible by 32)
#define TP_ 2054      // padded t-rows per batch in melTp (3 zero pad each side)
#define NFFT_ 1024
#define NF_ 513
#define HOP_ 256
#define NO2_ 1026
#define NPAD_ 1152    // head N padded to tile multiple
#define KI_ 1088      // ISTFT K (= 1026 padded to 32-multiple)
#define LOUT_ 524032

typedef _Float16 f16;
typedef f16 f16x8 __attribute__((ext_vector_type(8)));
typedef float f32x4 __attribute__((ext_vector_type(4)));

// tanh-form GELU: |err| vs exact-erf gelu <= ~3e-4, far under budget
__device__ __forceinline__ float gelu_f(float v) {
    float u = 0.7978845608028654f * v * (1.0f + 0.044715f * v * v);
    float e = __expf(2.0f * u);
    float t = 1.0f - 2.0f * __builtin_amdgcn_rcpf(e + 1.0f);
    return 0.5f * v * (1.0f + t);
}

__device__ __forceinline__ void gload16(const void* g, void* s) {
    __builtin_amdgcn_global_load_lds((const __attribute__((address_space(1))) void*)g,
                                     (__attribute__((address_space(3))) void*)s, 16, 0, 0);
}

// ---------------- conversion / prep kernels ----------------

__global__ __launch_bounds__(256) void k_cvt(const float* __restrict__ src,
                                             f16* __restrict__ dst, int n) {
    int i = blockIdx.x * 256 + threadIdx.x;
    if (i < n) dst[i] = (f16)src[i];
}

// head weights (1026,512) -> fp16 (1152,512) zero-padded rows
__global__ __launch_bounds__(256) void k_cvt_head(const float* __restrict__ src,
                                                  f16* __restrict__ dst) {
    int i = blockIdx.x * 256 + threadIdx.x;
    if (i >= NPAD_ * D_) return;
    int row = i >> 9;
    dst[i] = (row < NO2_) ? (f16)src[i] : (f16)0.0f;
}

__global__ __launch_bounds__(256) void k_pad_hb(const float* __restrict__ src,
                                                float* __restrict__ dst) {
    int i = blockIdx.x * 256 + threadIdx.x;
    if (i < NPAD_) dst[i] = (i < NO2_) ? src[i] : 0.0f;
}

// embed_w (D,Cm,7) -> we_h[d][tap*192 + c]  (tap-major K-order, matches A_h)
__global__ __launch_bounds__(256) void k_cvt_embed(const float* __restrict__ src,
                                                   f16* __restrict__ dst) {
    int i = blockIdx.x * 256 + threadIdx.x;
    if (i >= D_ * KE_) return;
    int d = i / KE_;
    int r2 = i - d * KE_;
    int tap = r2 / CM_;
    int c = r2 - tap * CM_;
    dst[i] = (f16)src[(d * CM_ + c) * 7 + tap];
}

// dw (8,512,7) -> dwT[bl][k][d]
__global__ __launch_bounds__(256) void k_cvtdw(const float* __restrict__ dw,
                                               float* __restrict__ dwT) {
    int i = blockIdx.x * 256 + threadIdx.x;
    if (i >= 8 * 7 * 512) return;
    int bl = i / 3584;
    int rem = i - bl * 3584;
    int k = rem >> 9;
    int d = rem & 511;
    dwT[i] = dw[bl * 3584 + d * 7 + k];
}

// mel (B,Cm,T) fp32 -> melTp[b][tp 0..2053][c 0..191] fp16, tp=t+3, pad rows zero
__global__ __launch_bounds__(256) void k_melT(const float* __restrict__ mel,
                                              f16* __restrict__ mt) {
    int idx = blockIdx.x * 256 + threadIdx.x;   // B_*TP_*24
    if (idx >= B_ * TP_ * 24) return;
    int c8 = idx % 24;
    int rem = idx / 24;
    int tp = rem % TP_;
    int b = rem / TP_;
    int t = tp - 3;
    f16x8 v;
    if (t >= 0 && t < T_) {
        const float* mp = mel + ((size_t)b * CM_ + c8 * 8) * T_ + t;
#pragma unroll
        for (int i = 0; i < 8; ++i) v[i] = (f16)mp[(size_t)i * T_];
    } else {
#pragma unroll
        for (int i = 0; i < 8; ++i) v[i] = (f16)0.0f;
    }
    *(f16x8*)(mt + (size_t)idx * 8) = v;
}

// expand melTp -> A_h: row bt = contiguous 1344 f16 starting at melTp[b][t][0]
__global__ __launch_bounds__(256) void k_expand(const f16* __restrict__ mt,
                                               f16* __restrict__ A) {
    int g = blockIdx.x * 256 + threadIdx.x;    // BT_*168 chunks of 8 f16
    if (g >= BT_ * 168) return;
    int bt = g / 168;
    int k8 = g - bt * 168;
    int b = bt >> 11;
    int t = bt & (T_ - 1);
    f16x8 v = *(const f16x8*)(mt + ((size_t)(b * TP_ + t) * CM_) + k8 * 8);
    *(f16x8*)(A + (size_t)bt * KE_ + k8 * 8) = v;
}

// ISTFT basis fp16: wmat[n][f2], f2<513: cos*scale ; 513..1025: -sin*scale ; pad 0
__global__ __launch_bounds__(256) void k_build_wmat(f16* __restrict__ wmat) {
    int idx = blockIdx.x * 256 + threadIdx.x;
    if (idx >= NFFT_ * KI_) return;
    int n = idx / KI_;
    int f2 = idx - n * KI_;
    float v = 0.0f;
    if (f2 < NF_) {
        int r = (n * f2) & (NFFT_ - 1);
        float sc = (f2 == 0 || f2 == NF_ - 1) ? (1.0f / NFFT_) : (2.0f / NFFT_);
        v = cospif((float)r * (2.0f / NFFT_)) * sc;
    } else if (f2 < NO2_) {
        int f = f2 - NF_;
        int r = (n * f) & (NFFT_ - 1);
        float sc = (f == 0 || f == NF_ - 1) ? (1.0f / NFFT_) : (2.0f / NFFT_);
        v = -sinpif((float)r * (2.0f / NFFT_)) * sc;
    }
    wmat[idx] = (f16)v;
}

// ---------------- LayerNorm over D=512, one wave per row ----------------
template <bool HOUT>
__global__ __launch_bounds__(64) void k_ln(const float* __restrict__ in,
                                           void* __restrict__ out,
                                           const float* __restrict__ w,
                                           const float* __restrict__ b) {
    int row = blockIdx.x;
    int lane = threadIdx.x;
    const float* p = in + (size_t)row * D_ + lane * 8;
    float4 v0 = *(const float4*)p;
    float4 v1 = *(const float4*)(p + 4);
    float s  = v0.x + v0.y + v0.z + v0.w + v1.x + v1.y + v1.z + v1.w;
    float ss = v0.x * v0.x + v0.y * v0.y + v0.z * v0.z + v0.w * v0.w +
               v1.x * v1.x + v1.y * v1.y + v1.z * v1.z + v1.w * v1.w;
#pragma unroll
    for (int off = 32; off > 0; off >>= 1) {
        s  += __shfl_xor(s, off);
        ss += __shfl_xor(ss, off);
    }
    float mean = s * (1.0f / 512.0f);
    float var  = ss * (1.0f / 512.0f) - mean * mean;
    float rs = rsqrtf(var + 1e-5f);
    const float* wp = w + lane * 8;
    const float* bp = b + lane * 8;
    float4 w0 = *(const float4*)wp, w1 = *(const float4*)(wp + 4);
    float4 b0 = *(const float4*)bp, b1 = *(const float4*)(bp + 4);
    float o[8];
    o[0] = (v0.x - mean) * rs * w0.x + b0.x;
    o[1] = (v0.y - mean) * rs * w0.y + b0.y;
    o[2] = (v0.z - mean) * rs * w0.z + b0.z;
    o[3] = (v0.w - mean) * rs * w0.w + b0.w;
    o[4] = (v1.x - mean) * rs * w1.x + b1.x;
    o[5] = (v1.y - mean) * rs * w1.y + b1.y;
    o[6] = (v1.z - mean) * rs * w1.z + b1.z;
    o[7] = (v1.w - mean) * rs * w1.w + b1.w;
    if constexpr (HOUT) {
        f16x8 h;
#pragma unroll
        for (int i = 0; i < 8; ++i) h[i] = (f16)o[i];
        *(f16x8*)((f16*)out + (size_t)row * D_ + lane * 8) = h;
    } else {
        float* q = (float*)out + (size_t)row * D_ + lane * 8;
        *(float4*)q = make_float4(o[0], o[1], o[2], o[3]);
        *(float4*)(q + 4) = make_float4(o[4], o[5], o[6], o[7]);
    }
}

// ---- fused depthwise conv + LayerNorm, t-tiled via LDS (r10-proven) ----
__global__ __launch_bounds__(256) void k_dwln2(const float* __restrict__ x,
                                               const float* __restrict__ dwT,
                                               const float* __restrict__ db,
                                               const float* __restrict__ nw,
                                               const float* __restrict__ nb,
                                               f16* __restrict__ out) {
    __shared__ float xs[22][512];
    int tid = threadIdx.x;
    int blk = blockIdx.x;            // b*128 + tc
    int b = blk >> 7;
    int t0 = (blk & 127) << 4;
    const float* xb = x + ((size_t)b << 20);   // b * T_ * D_
#pragma unroll
    for (int i = 0; i < 11; ++i) {
        int idx = tid + (i << 8);    // float4 index over 22*128
        int row = idx >> 7;
        int c4 = idx & 127;
        int t = t0 + row - 3;
        float4 v = make_float4(0.f, 0.f, 0.f, 0.f);
        if (t >= 0 && t < T_) v = *(const float4*)(xb + ((size_t)t << 9) + (c4 << 2));
        *(float4*)&xs[row][c4 << 2] = v;
    }
    __syncthreads();

    int o = tid & 63;          // d-octet
    int slot = tid >> 6;       // wave id = t-group
    int d0 = o << 3;
    float acc[4][8];
    {
        float4 b0 = *(const float4*)(db + d0);
        float4 b1 = *(const float4*)(db + d0 + 4);
#pragma unroll
        for (int u = 0; u < 4; ++u) {
            acc[u][0] = b0.x; acc[u][1] = b0.y; acc[u][2] = b0.z; acc[u][3] = b0.w;
            acc[u][4] = b1.x; acc[u][5] = b1.y; acc[u][6] = b1.z; acc[u][7] = b1.w;
        }
    }
#pragma unroll
    for (int k = 0; k < 7; ++k) {
        float w8[8];
        *(float4*)&w8[0] = *(const float4*)(dwT + (k << 9) + d0);
        *(float4*)&w8[4] = *(const float4*)(dwT + (k << 9) + d0 + 4);
#pragma unroll
        for (int u = 0; u < 4; ++u) {
            int row = (slot << 2) + u + k;   // t_local + k, in [0,21]
            float x8[8];
            *(float4*)&x8[0] = *(const float4*)&xs[row][d0];
            *(float4*)&x8[4] = *(const float4*)&xs[row][d0 + 4];
#pragma unroll
            for (int i = 0; i < 8; ++i) acc[u][i] = fmaf(w8[i], x8[i], acc[u][i]);
        }
    }
    float4 w0 = *(const float4*)(nw + d0), w1 = *(const float4*)(nw + d0 + 4);
    float4 n0 = *(const float4*)(nb + d0), n1 = *(const float4*)(nb + d0 + 4);
    float nwv[8] = {w0.x, w0.y, w0.z, w0.w, w1.x, w1.y, w1.z, w1.w};
    float nbv[8] = {n0.x, n0.y, n0.z, n0.w, n1.x, n1.y, n1.z, n1.w};
#pragma unroll
    for (int u = 0; u < 4; ++u) {
        float s = 0.f, ss = 0.f;
#pragma unroll
        for (int i = 0; i < 8; ++i) { s += acc[u][i]; ss = fmaf(acc[u][i], acc[u][i], ss); }
#pragma unroll
        for (int off = 32; off > 0; off >>= 1) {
            s  += __shfl_xor(s, off);
            ss += __shfl_xor(ss, off);
        }
        float mean = s * (1.0f / 512.0f);
        float var  = ss * (1.0f / 512.0f) - mean * mean;
        float rs = rsqrtf(var + 1e-5f);
        f16x8 h;
#pragma unroll
        for (int i = 0; i < 8; ++i)
            h[i] = (f16)((acc[u][i] - mean) * rs * nwv[i] + nbv[i]);
        int t = t0 + (slot << 2) + u;
        *(f16x8*)(out + (((size_t)(b << 11) + t) << 9) + d0) = h;
    }
}

// ---- fp16 MFMA GEMM v7: 256x128 block, wave-tile 128x64, BK=32, 3-ring, vmcnt(6) ----
// Same proven mechanisms as v5 (r6/r8/r10): zero-conflict XOR-swizzled A/B staging via
// pre-swizzled global src + linear global_load_lds dest + same-XOR read; 3-deep ring;
// counted vmcnt; setprio around MFMA cluster; m89-verified C/D layout.
// Delta vs v5: block tile 256x128 (wave 2x2 grid, wave-tile 128x64 = 8x4 fragments)
// -> LDS traffic 0.5625 KB/MFMA vs 0.75 (1.33x less). Ring slot = A(256x32)+B(128x32)
// = 24 KB, ring 72 KB -> 2 blocks/CU. 6 load-issues/iter (A:4 + B:2) -> vmcnt(6)
// drains tile t+1, leaves t+2 in flight (identical FIFO argument as v5's vmcnt(4)).
#define ASZ_ 8192   // f16 elems per A tile (256x32)
#define BSZ_ 4096   // f16 elems per B tile (128x32)
#define RSZ_ 12288  // ring slot

__device__ __forceinline__ void stageA256(const f16* __restrict__ g, f16* s,
                                          int K, int kof, int tid) {
    int dr0 = tid >> 3;        // 0..31
    int sl  = tid & 7;
#pragma unroll
    for (int i = 0; i < 4; ++i) {
        int d  = dr0 + (i << 5);           // double-row 0..127
        int gs = sl ^ (d & 7);             // pre-swizzled global slot
        int row = (d << 1) + (gs >> 2);    // 0..255
        int kc  = gs & 3;
        gload16(g + (size_t)row * K + kof + (kc << 3),
                s + (d << 6) + (sl << 3));
    }
}

__device__ __forceinline__ void stageB128(const f16* __restrict__ g, f16* s,
                                          int K, int kof, int tid) {
    int dr0 = tid >> 3;
    int sl  = tid & 7;
#pragma unroll
    for (int i = 0; i < 2; ++i) {
        int d  = dr0 + (i << 5);           // double-row 0..63
        int gs = sl ^ (d & 7);
        int row = (d << 1) + (gs >> 2);    // 0..127
        int kc  = gs & 3;
        gload16(g + (size_t)row * K + kof + (kc << 3),
                s + (d << 6) + (sl << 3));
    }
}

#define MF(d, a, b) d = __builtin_amdgcn_mfma_f32_16x16x32_f16(a, b, d, 0, 0, 0)

template <int EPI>
__global__ __launch_bounds__(256, 2) void k_hgemm7(const f16* __restrict__ A,
                                                   const f16* __restrict__ W,
                                                   const float* __restrict__ bias,
                                                   const float* __restrict__ gamma,
                                                   void* __restrict__ C,
                                                   int K, int ldc, int nNt) {
    __shared__ f16 lds[3 * RSZ_];
    int tid = threadIdx.x;
    int nwg = gridDim.x, bid = blockIdx.x;
    int q = nwg >> 3, r = nwg & 7;
    int xcd = bid & 7, lin = bid >> 3;
    int swz = (xcd < r ? xcd * (q + 1) : r * (q + 1) + (xcd - r) * q) + lin;
    int bm = (swz / nNt) << 8;      // 256-row M tiles
    int bn = (swz % nNt) << 7;      // 128-col N tiles
    const f16* gA = A + (size_t)bm * K;
    const f16* gW = W + (size_t)bn * K;

    int l = tid & 63;
    int wv = tid >> 6;
    int wm = (wv & 1) << 7;    // 2 wave-rows of 128
    int wn = (wv >> 1) << 6;   // 2 wave-cols of 64
    int lr = l & 15;
    int lk = l >> 4;
    int lrh = lr >> 1;
    int s0l = ((lr & 1) << 2) | lk;   // logical slot for this lane's (row-half, chunk)

    // loop-invariant read offsets (f16 units), proven zero-conflict geometry
    int offA[8], offB[4];
#pragma unroll
    for (int i = 0; i < 8; ++i) {
        int dA = (wm >> 1) + i * 8 + lrh;           // double-row 0..127
        offA[i] = (dA << 6) + ((s0l ^ (dA & 7)) << 3);
    }
#pragma unroll
    for (int j = 0; j < 4; ++j) {
        int dB = (wn >> 1) + j * 8 + lrh;           // double-row 0..63
        offB[j] = (dB << 6) + ((s0l ^ (dB & 7)) << 3);
    }

    f32x4 acc[8][4];
#pragma unroll
    for (int i = 0; i < 8; ++i)
#pragma unroll
        for (int j = 0; j < 4; ++j) acc[i][j] = {0.f, 0.f, 0.f, 0.f};

    int nk = K >> 5;
    f16* s0 = lds;
    f16* s1 = lds + RSZ_;
    f16* s2 = lds + 2 * RSZ_;

    // prologue: stage tiles 0,1 (12 loads); vmcnt(6) completes tile 0 (6 loads)
    stageA256(gA, s0, K, 0, tid);      stageB128(gW, s0 + ASZ_, K, 0, tid);
    stageA256(gA, s1, K, 32, tid);     stageB128(gW, s1 + ASZ_, K, 32, tid);
    asm volatile("s_waitcnt vmcnt(6)" ::: "memory");
    __builtin_amdgcn_s_barrier();

    for (int t = 0; t < nk; ++t) {
        bool stg = (t + 2 < nk);
        if (stg) {
            int ko = (t + 2) << 5;
            stageA256(gA, s2, K, ko, tid);
            stageB128(gW, s2 + ASZ_, K, ko, tid);
        }
        f16x8 af[8], bf[4];
#pragma unroll
        for (int i = 0; i < 8; ++i) af[i] = *(const f16x8*)(s0 + offA[i]);
#pragma unroll
        for (int j = 0; j < 4; ++j) bf[j] = *(const f16x8*)(s0 + ASZ_ + offB[j]);
        __builtin_amdgcn_s_setprio(1);
#pragma unroll
        for (int i = 0; i < 8; ++i)
#pragma unroll
            for (int j = 0; j < 4; ++j) MF(acc[i][j], af[i], bf[j]);
        __builtin_amdgcn_s_setprio(0);
        if (stg)               asm volatile("s_waitcnt vmcnt(6)" ::: "memory");
        else if (t + 1 < nk)   asm volatile("s_waitcnt vmcnt(0)" ::: "memory");
        if (t + 1 < nk) {
            __builtin_amdgcn_s_barrier();
            asm volatile("" ::: "memory");
        }
        f16* tmp = s0; s0 = s1; s1 = s2; s2 = tmp;
    }

    // epilogue: C/D layout col = lane&15, row = (lane>>4)*4 + reg (m89-verified)
    int lk4 = lk << 2;
#pragma unroll
    for (int i = 0; i < 8; ++i) {
#pragma unroll
        for (int rr = 0; rr < 4; ++rr) {
            int row = bm + wm + i * 16 + lk4 + rr;
            size_t moff = (size_t)row * ldc;
#pragma unroll
            for (int j = 0; j < 4; ++j) {
                int col = bn + wn + j * 16 + lr;
                float v = acc[i][j][rr];
                if constexpr (EPI == 0) {
                    ((float*)C)[moff + col] = v + bias[col];
                } else if constexpr (EPI == 1) {
                    ((f16*)C)[moff + col] = (f16)gelu_f(v + bias[col]);
                } else if constexpr (EPI == 2) {
                    ((float*)C)[moff + col] += gamma[col] * (v + bias[col]);
                } else {
                    ((f16*)C)[moff + col] = (f16)(v * bias[col]);
                }
            }
        }
    }
}

// ---------------- head fp32 (stride 1152) -> S fp16 (stride 1088, padded) ----------------
__global__ __launch_bounds__(256) void k_srsi(const float* __restrict__ o,
                                              f16* __restrict__ S) {
    int idx = blockIdx.x * 256 + threadIdx.x;
    if (idx >= BT_ * KI_) return;
    int m = idx / KI_;
    int f2 = idx - m * KI_;
    size_t base = (size_t)m * NPAD_;
    float v = 0.0f;
    if (f2 < NF_) {
        float mag = fminf(__expf(o[base + f2]), 100.0f);
        float sn, cs;
        __sincosf(o[base + NF_ + f2], &sn, &cs);
        v = mag * cs;
    } else if (f2 < NO2_) {
        int f = f2 - NF_;
        float mag = fminf(__expf(o[base + f]), 100.0f);
        float sn, cs;
        __sincosf(o[base + NF_ + f], &sn, &cs);
        v = mag * sn;
    }
    S[idx] = (f16)v;
}

// ---------------- overlap-add + win_env + crop (deterministic gather, f16 frames) ------
__global__ __launch_bounds__(256) void k_gather(const f16* __restrict__ frames,
                                                const float* __restrict__ win,
                                                float* __restrict__ out) {
    int idx = blockIdx.x * 256 + threadIdx.x;
    int b  = idx / LOUT_;
    int lp = idx - b * LOUT_;
    int l = lp + (NFFT_ / 2);
    int thi = l >> 8;
    if (thi > T_ - 1) thi = T_ - 1;
    int tlo = l - (NFFT_ - 1) + (HOP_ - 1);
    tlo = (tlo < 0) ? 0 : (tlo >> 8);
    float num = 0.0f, den = 0.0f;
    for (int t = tlo; t <= thi; ++t) {
        int n = l - (t << 8);
        float wv = win[n];
        num += (float)frames[((size_t)(b * T_ + t) << 10) + n];
        den = fmaf(wv, wv, den);
    }
    out[idx] = num / (den + 1e-11f);
}

// ---------------- launch ----------------
extern "C" void kernel_launch(void* const* d_in, const int* in_sizes, int n_in,
                              void* d_out, int out_size, void* d_ws, size_t ws_size,
                              hipStream_t stream) {
    (void)in_sizes; (void)n_in; (void)out_size; (void)ws_size;
    const float* mel     = (const float*)d_in[0];
    const float* embed_w = (const float*)d_in[1];
    const float* embed_b = (const float*)d_in[2];
    const float* norm_w  = (const float*)d_in[3];
    const float* norm_b  = (const float*)d_in[4];
    const float* bdw = (const float*)d_in[5];
    const float* bdb = (const float*)d_in[6];
    const float* bnw = (const float*)d_in[7];
    const float* bnb = (const float*)d_in[8];
    const float* bw1 = (const float*)d_in[9];
    const float* bb1 = (const float*)d_in[10];
    const float* bw2 = (const float*)d_in[11];
    const float* bb2 = (const float*)d_in[12];
    const float* bg  = (const float*)d_in[13];
    const float* fnw = (const float*)d_in[14];
    const float* fnb = (const float*)d_in[15];
    const float* hw  = (const float*)d_in[16];
    const float* hb  = (const float*)d_in[17];
    const float* win = (const float*)d_in[18];

    char* ws = (char*)d_ws;
    // region A: [0, 50.3MB): xbuf fp32 + ybuf_h fp16; melTp transiently at base (dead
    // once embed GEMM writes xbuf); S_h overlays later
    float* xbuf   = (float*)ws;
    f16*   melTp  = (f16*)ws;                     // 6,309,888 B, dead after k_expand
    f16*   ybuf_h = (f16*)(ws + 33554432);
    f16*   S_h    = (f16*)ws;
    // region R: [50.3MB, 134.2MB): A_h / obuf / frames_h at base; hbuf_h at +33.5MB
    char* R = ws + 50331648;
    f16*   hbuf_h = (f16*)(R + 33554432);
    f16*   A_h    = (f16*)R;
    float* obuf   = (float*)R;
    f16*   frames_h = (f16*)R;
    // region W: [134.2MB, ...): converted weights (r6-proven envelope)
    char* Wr = ws + 134217728;
    f16*   w1_h   = (f16*)Wr;                     // 12,582,912
    f16*   w2_h   = (f16*)(Wr + 12582912);        // 12,582,912
    f16*   head_h = (f16*)(Wr + 25165824);        // 1,179,648
    f16*   wmat_h = (f16*)(Wr + 26345472);        // 2,228,224
    f16*   we_h   = (f16*)(Wr + 28573696);        // 1,376,256
    float* hb_pad = (float*)(Wr + 29949952);      // 4,608
    float* dwT    = (float*)(Wr + 29954560);      // 114,688

    const int nW1 = 8 * H_ * D_;
    k_cvt<<<(nW1 + 255) / 256, 256, 0, stream>>>(bw1, w1_h, nW1);
    k_cvt<<<(nW1 + 255) / 256, 256, 0, stream>>>(bw2, w2_h, nW1);
    k_cvt_embed<<<(D_ * KE_ + 255) / 256, 256, 0, stream>>>(embed_w, we_h);
    k_cvt_head<<<(NPAD_ * D_ + 255) / 256, 256, 0, stream>>>(hw, head_h);
    k_pad_hb<<<5, 256, 0, stream>>>(hb, hb_pad);
    k_cvtdw<<<(8 * 3584 + 255) / 256, 256, 0, stream>>>(bdw, dwT);
    k_build_wmat<<<(NFFT_ * KI_ + 255) / 256, 256, 0, stream>>>(wmat_h);

    // embed conv: mel -> melTp (fp16 t-major) -> A_h (im2col via contiguous row copies)
    k_melT<<<(B_ * TP_ * 24 + 255) / 256, 256, 0, stream>>>(mel, melTp);
    k_expand<<<(BT_ * 168 + 255) / 256, 256, 0, stream>>>(melTp, A_h);
    k_hgemm7<0><<<64 * 4, 256, 0, stream>>>(A_h, we_h, embed_b, nullptr, xbuf,
                                            KE_, D_, 4);
    k_ln<false><<<BT_, 64, 0, stream>>>(xbuf, xbuf, norm_w, norm_b);

    for (int bl = 0; bl < 8; ++bl) {
        k_dwln2<<<B_ * 128, 256, 0, stream>>>(xbuf, dwT + bl * 3584, bdb + bl * D_,
                                              bnw + bl * D_, bnb + bl * D_, ybuf_h);
        k_hgemm7<1><<<64 * 12, 256, 0, stream>>>(ybuf_h, w1_h + (size_t)bl * H_ * D_,
                                                 bb1 + bl * H_, nullptr, hbuf_h,
                                                 D_, H_, 12);
        k_hgemm7<2><<<64 * 4, 256, 0, stream>>>(hbuf_h, w2_h + (size_t)bl * D_ * H_,
                                                bb2 + bl * D_, bg + bl * D_, xbuf,
                                                H_, D_, 4);
    }

    k_ln<true><<<BT_, 64, 0, stream>>>(xbuf, ybuf_h, fnw, fnb);
    k_hgemm7<0><<<64 * 9, 256, 0, stream>>>(ybuf_h, head_h, hb_pad, nullptr, obuf,
                                            D_, NPAD_, 9);
    k_srsi<<<(BT_ * KI_ + 255) / 256, 256, 0, stream>>>(obuf, S_h);
    k_hgemm7<3><<<64 * 8, 256, 0, stream>>>(S_h, wmat_h, win, nullptr, frames_h,
                                            KI_, NFFT_, 8);
    k_gather<<<B_ * LOUT_ / 256, 256, 0, stream>>>(frames_h, win, (float*)d_out);
}

// Round 12
// 1074.348 us; speedup vs baseline: 1.0162x; 1.0162x over previous
//
#include <hip/hip_runtime.h>
#include <cmath>

#define B_ 8
#define T_ 2048
#define BT_ 16384
#define D_ 512
#define H_ 1536
#define CM_ 192
#define KE_ 1344      // embed K = 192*7 (divisible by 32)
#define TP_ 2054      // padded t-rows per batch in melTp (3 zero pad each side)
#define NFFT_ 1024
#define NF_ 513
#define HOP_ 256
#define NO2_ 1026
#define NPAD_ 1152    // head N padded to tile multiple
#define KI_ 1088      // ISTFT K (= 1026 padded to 32-multiple)
#define LOUT_ 524032

typedef _Float16 f16;
typedef f16 f16x8 __attribute__((ext_vector_type(8)));
typedef float f32x4 __attribute__((ext_vector_type(4)));

// tanh-form GELU: |err| vs exact-erf gelu <= ~3e-4, far under budget
__device__ __forceinline__ float gelu_f(float v) {
    float u = 0.7978845608028654f * v * (1.0f + 0.044715f * v * v);
    float e = __expf(2.0f * u);
    float t = 1.0f - 2.0f * __builtin_amdgcn_rcpf(e + 1.0f);
    return 0.5f * v * (1.0f + t);
}

__device__ __forceinline__ void gload16(const void* g, void* s) {
    __builtin_amdgcn_global_load_lds((const __attribute__((address_space(1))) void*)g,
                                     (__attribute__((address_space(3))) void*)s, 16, 0, 0);
}

// ---------------- conversion / prep kernels ----------------

__global__ __launch_bounds__(256) void k_cvt(const float* __restrict__ src,
                                             f16* __restrict__ dst, int n) {
    int i = blockIdx.x * 256 + threadIdx.x;
    if (i < n) dst[i] = (f16)src[i];
}

// head weights (1026,512) -> fp16 (1152,512) zero-padded rows
__global__ __launch_bounds__(256) void k_cvt_head(const float* __restrict__ src,
                                                  f16* __restrict__ dst) {
    int i = blockIdx.x * 256 + threadIdx.x;
    if (i >= NPAD_ * D_) return;
    int row = i >> 9;
    dst[i] = (row < NO2_) ? (f16)src[i] : (f16)0.0f;
}

__global__ __launch_bounds__(256) void k_pad_hb(const float* __restrict__ src,
                                                float* __restrict__ dst) {
    int i = blockIdx.x * 256 + threadIdx.x;
    if (i < NPAD_) dst[i] = (i < NO2_) ? src[i] : 0.0f;
}

// embed_w (D,Cm,7) -> we_h[d][tap*192 + c]  (tap-major K-order, matches A_h)
__global__ __launch_bounds__(256) void k_cvt_embed(const float* __restrict__ src,
                                                   f16* __restrict__ dst) {
    int i = blockIdx.x * 256 + threadIdx.x;
    if (i >= D_ * KE_) return;
    int d = i / KE_;
    int r2 = i - d * KE_;
    int tap = r2 / CM_;
    int c = r2 - tap * CM_;
    dst[i] = (f16)src[(d * CM_ + c) * 7 + tap];
}

// dw (8,512,7) -> dwT[bl][k][d]
__global__ __launch_bounds__(256) void k_cvtdw(const float* __restrict__ dw,
                                               float* __restrict__ dwT) {
    int i = blockIdx.x * 256 + threadIdx.x;
    if (i >= 8 * 7 * 512) return;
    int bl = i / 3584;
    int rem = i - bl * 3584;
    int k = rem >> 9;
    int d = rem & 511;
    dwT[i] = dw[bl * 3584 + d * 7 + k];
}

// mel (B,Cm,T) fp32 -> melTp[b][tp 0..2053][c 0..191] fp16, tp=t+3, pad rows zero
__global__ __launch_bounds__(256) void k_melT(const float* __restrict__ mel,
                                              f16* __restrict__ mt) {
    int idx = blockIdx.x * 256 + threadIdx.x;   // B_*TP_*24
    if (idx >= B_ * TP_ * 24) return;
    int c8 = idx % 24;
    int rem = idx / 24;
    int tp = rem % TP_;
    int b = rem / TP_;
    int t = tp - 3;
    f16x8 v;
    if (t >= 0 && t < T_) {
        const float* mp = mel + ((size_t)b * CM_ + c8 * 8) * T_ + t;
#pragma unroll
        for (int i = 0; i < 8; ++i) v[i] = (f16)mp[(size_t)i * T_];
    } else {
#pragma unroll
        for (int i = 0; i < 8; ++i) v[i] = (f16)0.0f;
    }
    *(f16x8*)(mt + (size_t)idx * 8) = v;
}

// expand melTp -> A_h: row bt = contiguous 1344 f16 starting at melTp[b][t][0]
__global__ __launch_bounds__(256) void k_expand(const f16* __restrict__ mt,
                                               f16* __restrict__ A) {
    int g = blockIdx.x * 256 + threadIdx.x;    // BT_*168 chunks of 8 f16
    if (g >= BT_ * 168) return;
    int bt = g / 168;
    int k8 = g - bt * 168;
    int b = bt >> 11;
    int t = bt & (T_ - 1);
    f16x8 v = *(const f16x8*)(mt + ((size_t)(b * TP_ + t) * CM_) + k8 * 8);
    *(f16x8*)(A + (size_t)bt * KE_ + k8 * 8) = v;
}

// ISTFT basis fp16: wmat[n][f2], f2<513: cos*scale ; 513..1025: -sin*scale ; pad 0
__global__ __launch_bounds__(256) void k_build_wmat(f16* __restrict__ wmat) {
    int idx = blockIdx.x * 256 + threadIdx.x;
    if (idx >= NFFT_ * KI_) return;
    int n = idx / KI_;
    int f2 = idx - n * KI_;
    float v = 0.0f;
    if (f2 < NF_) {
        int r = (n * f2) & (NFFT_ - 1);
        float sc = (f2 == 0 || f2 == NF_ - 1) ? (1.0f / NFFT_) : (2.0f / NFFT_);
        v = cospif((float)r * (2.0f / NFFT_)) * sc;
    } else if (f2 < NO2_) {
        int f = f2 - NF_;
        int r = (n * f) & (NFFT_ - 1);
        float sc = (f == 0 || f == NF_ - 1) ? (1.0f / NFFT_) : (2.0f / NFFT_);
        v = -sinpif((float)r * (2.0f / NFFT_)) * sc;
    }
    wmat[idx] = (f16)v;
}

// ---------------- LayerNorm over D=512, one wave per row ----------------
template <bool HOUT>
__global__ __launch_bounds__(64) void k_ln(const float* __restrict__ in,
                                           void* __restrict__ out,
                                           const float* __restrict__ w,
                                           const float* __restrict__ b) {
    int row = blockIdx.x;
    int lane = threadIdx.x;
    const float* p = in + (size_t)row * D_ + lane * 8;
    float4 v0 = *(const float4*)p;
    float4 v1 = *(const float4*)(p + 4);
    float s  = v0.x + v0.y + v0.z + v0.w + v1.x + v1.y + v1.z + v1.w;
    float ss = v0.x * v0.x + v0.y * v0.y + v0.z * v0.z + v0.w * v0.w +
               v1.x * v1.x + v1.y * v1.y + v1.z * v1.z + v1.w * v1.w;
#pragma unroll
    for (int off = 32; off > 0; off >>= 1) {
        s  += __shfl_xor(s, off);
        ss += __shfl_xor(ss, off);
    }
    float mean = s * (1.0f / 512.0f);
    float var  = ss * (1.0f / 512.0f) - mean * mean;
    float rs = rsqrtf(var + 1e-5f);
    const float* wp = w + lane * 8;
    const float* bp = b + lane * 8;
    float4 w0 = *(const float4*)wp, w1 = *(const float4*)(wp + 4);
    float4 b0 = *(const float4*)bp, b1 = *(const float4*)(bp + 4);
    float o[8];
    o[0] = (v0.x - mean) * rs * w0.x + b0.x;
    o[1] = (v0.y - mean) * rs * w0.y + b0.y;
    o[2] = (v0.z - mean) * rs * w0.z + b0.z;
    o[3] = (v0.w - mean) * rs * w0.w + b0.w;
    o[4] = (v1.x - mean) * rs * w1.x + b1.x;
    o[5] = (v1.y - mean) * rs * w1.y + b1.y;
    o[6] = (v1.z - mean) * rs * w1.z + b1.z;
    o[7] = (v1.w - mean) * rs * w1.w + b1.w;
    if constexpr (HOUT) {
        f16x8 h;
#pragma unroll
        for (int i = 0; i < 8; ++i) h[i] = (f16)o[i];
        *(f16x8*)((f16*)out + (size_t)row * D_ + lane * 8) = h;
    } else {
        float* q = (float*)out + (size_t)row * D_ + lane * 8;
        *(float4*)q = make_float4(o[0], o[1], o[2], o[3]);
        *(float4*)(q + 4) = make_float4(o[4], o[5], o[6], o[7]);
    }
}

// ---- fused depthwise conv + LayerNorm, t-tiled via LDS (r10-proven) ----
__global__ __launch_bounds__(256) void k_dwln2(const float* __restrict__ x,
                                               const float* __restrict__ dwT,
                                               const float* __restrict__ db,
                                               const float* __restrict__ nw,
                                               const float* __restrict__ nb,
                                               f16* __restrict__ out) {
    __shared__ float xs[22][512];
    int tid = threadIdx.x;
    int blk = blockIdx.x;            // b*128 + tc
    int b = blk >> 7;
    int t0 = (blk & 127) << 4;
    const float* xb = x + ((size_t)b << 20);   // b * T_ * D_
#pragma unroll
    for (int i = 0; i < 11; ++i) {
        int idx = tid + (i << 8);    // float4 index over 22*128
        int row = idx >> 7;
        int c4 = idx & 127;
        int t = t0 + row - 3;
        float4 v = make_float4(0.f, 0.f, 0.f, 0.f);
        if (t >= 0 && t < T_) v = *(const float4*)(xb + ((size_t)t << 9) + (c4 << 2));
        *(float4*)&xs[row][c4 << 2] = v;
    }
    __syncthreads();

    int o = tid & 63;          // d-octet
    int slot = tid >> 6;       // wave id = t-group
    int d0 = o << 3;
    float acc[4][8];
    {
        float4 b0 = *(const float4*)(db + d0);
        float4 b1 = *(const float4*)(db + d0 + 4);
#pragma unroll
        for (int u = 0; u < 4; ++u) {
            acc[u][0] = b0.x; acc[u][1] = b0.y; acc[u][2] = b0.z; acc[u][3] = b0.w;
            acc[u][4] = b1.x; acc[u][5] = b1.y; acc[u][6] = b1.z; acc[u][7] = b1.w;
        }
    }
#pragma unroll
    for (int k = 0; k < 7; ++k) {
        float w8[8];
        *(float4*)&w8[0] = *(const float4*)(dwT + (k << 9) + d0);
        *(float4*)&w8[4] = *(const float4*)(dwT + (k << 9) + d0 + 4);
#pragma unroll
        for (int u = 0; u < 4; ++u) {
            int row = (slot << 2) + u + k;   // t_local + k, in [0,21]
            float x8[8];
            *(float4*)&x8[0] = *(const float4*)&xs[row][d0];
            *(float4*)&x8[4] = *(const float4*)&xs[row][d0 + 4];
#pragma unroll
            for (int i = 0; i < 8; ++i) acc[u][i] = fmaf(w8[i], x8[i], acc[u][i]);
        }
    }
    float4 w0 = *(const float4*)(nw + d0), w1 = *(const float4*)(nw + d0 + 4);
    float4 n0 = *(const float4*)(nb + d0), n1 = *(const float4*)(nb + d0 + 4);
    float nwv[8] = {w0.x, w0.y, w0.z, w0.w, w1.x, w1.y, w1.z, w1.w};
    float nbv[8] = {n0.x, n0.y, n0.z, n0.w, n1.x, n1.y, n1.z, n1.w};
#pragma unroll
    for (int u = 0; u < 4; ++u) {
        float s = 0.f, ss = 0.f;
#pragma unroll
        for (int i = 0; i < 8; ++i) { s += acc[u][i]; ss = fmaf(acc[u][i], acc[u][i], ss); }
#pragma unroll
        for (int off = 32; off > 0; off >>= 1) {
            s  += __shfl_xor(s, off);
            ss += __shfl_xor(ss, off);
        }
        float mean = s * (1.0f / 512.0f);
        float var  = ss * (1.0f / 512.0f) - mean * mean;
        float rs = rsqrtf(var + 1e-5f);
        f16x8 h;
#pragma unroll
        for (int i = 0; i < 8; ++i)
            h[i] = (f16)((acc[u][i] - mean) * rs * nwv[i] + nbv[i]);
        int t = t0 + (slot << 2) + u;
        *(f16x8*)(out + (((size_t)(b << 11) + t) << 9) + d0) = h;
    }
}

#define MF(d, a, b) d = __builtin_amdgcn_mfma_f32_16x16x32_f16(a, b, d, 0, 0, 0)

// ---- fp16 MFMA GEMM v5 (r6/r8/r10-proven): 128x128, BK=32, 3-ring, vmcnt(4) ----
// Used for shapes where BM=256 would leave the grid at 1 block/CU (pw2, embed: N=512).
#define TSZ_ 4096   // f16 elems per matrix tile (128x32)

__device__ __forceinline__ void stage32(const f16* __restrict__ g, f16* s,
                                        int K, int kof, int tid) {
    int dr0 = tid >> 3;        // 0..31
    int sl  = tid & 7;
#pragma unroll
    for (int i = 0; i < 2; ++i) {
        int d  = dr0 + (i << 5);           // double-row 0..63
        int gs = sl ^ (d & 7);             // pre-swizzled global slot
        int row = (d << 1) + (gs >> 2);
        int kc  = gs & 3;
        gload16(g + (size_t)row * K + kof + (kc << 3),
                s + (d << 6) + (sl << 3)); // linear dest: wave base + lane*16B
    }
}

template <int EPI>
__global__ __launch_bounds__(256, 3) void k_hgemm5(const f16* __restrict__ A,
                                                   const f16* __restrict__ W,
                                                   const float* __restrict__ bias,
                                                   const float* __restrict__ gamma,
                                                   void* __restrict__ C,
                                                   int K, int ldc, int nNt) {
    __shared__ f16 lds[3 * 2 * TSZ_];
    int tid = threadIdx.x;
    int nwg = gridDim.x, bid = blockIdx.x;
    int q = nwg >> 3, r = nwg & 7;
    int xcd = bid & 7, lin = bid >> 3;
    int swz = (xcd < r ? xcd * (q + 1) : r * (q + 1) + (xcd - r) * q) + lin;
    int bm = (swz / nNt) << 7;
    int bn = (swz % nNt) << 7;
    const f16* gA = A + (size_t)bm * K;
    const f16* gW = W + (size_t)bn * K;

    int l = tid & 63;
    int wv = tid >> 6;
    int wm = (wv & 1) << 6;    // 2 wave-rows of 64
    int wn = (wv >> 1) << 6;   // 2 wave-cols of 64
    int lr = l & 15;
    int lk = l >> 4;
    int lrh = lr >> 1;
    int s0l = ((lr & 1) << 2) | lk;   // logical slot for this lane's (row-half, chunk)

    int offA[4], offB[4];
#pragma unroll
    for (int i = 0; i < 4; ++i) {
        int dA = (wm >> 1) + i * 8 + lrh;
        offA[i] = (dA << 6) + ((s0l ^ (dA & 7)) << 3);
        int dB = (wn >> 1) + i * 8 + lrh;
        offB[i] = (dB << 6) + ((s0l ^ (dB & 7)) << 3);
    }

    f32x4 acc[4][4];
#pragma unroll
    for (int i = 0; i < 4; ++i)
#pragma unroll
        for (int j = 0; j < 4; ++j) acc[i][j] = {0.f, 0.f, 0.f, 0.f};

    int nk = K >> 5;
    f16* s0 = lds;
    f16* s1 = lds + 2 * TSZ_;
    f16* s2 = lds + 4 * TSZ_;

    stage32(gA, s0, K, 0, tid);        stage32(gW, s0 + TSZ_, K, 0, tid);
    stage32(gA, s1, K, 32, tid);       stage32(gW, s1 + TSZ_, K, 32, tid);
    asm volatile("s_waitcnt vmcnt(4)" ::: "memory");
    __builtin_amdgcn_s_barrier();

    for (int t = 0; t < nk; ++t) {
        bool stg = (t + 2 < nk);
        if (stg) {
            int ko = (t + 2) << 5;
            stage32(gA, s2, K, ko, tid);
            stage32(gW, s2 + TSZ_, K, ko, tid);
        }
        f16x8 af[4], bf[4];
#pragma unroll
        for (int i = 0; i < 4; ++i) af[i] = *(const f16x8*)(s0 + offA[i]);
#pragma unroll
        for (int j = 0; j < 4; ++j) bf[j] = *(const f16x8*)(s0 + TSZ_ + offB[j]);
        __builtin_amdgcn_s_setprio(1);
#pragma unroll
        for (int i = 0; i < 4; ++i)
#pragma unroll
            for (int j = 0; j < 4; ++j) MF(acc[i][j], af[i], bf[j]);
        __builtin_amdgcn_s_setprio(0);
        if (stg)               asm volatile("s_waitcnt vmcnt(4)" ::: "memory");
        else if (t + 1 < nk)   asm volatile("s_waitcnt vmcnt(0)" ::: "memory");
        if (t + 1 < nk) {
            __builtin_amdgcn_s_barrier();
            asm volatile("" ::: "memory");
        }
        f16* tmp = s0; s0 = s1; s1 = s2; s2 = tmp;
    }

    int lk4 = lk << 2;
#pragma unroll
    for (int i = 0; i < 4; ++i) {
#pragma unroll
        for (int rr = 0; rr < 4; ++rr) {
            int row = bm + wm + i * 16 + lk4 + rr;
            size_t moff = (size_t)row * ldc;
#pragma unroll
            for (int j = 0; j < 4; ++j) {
                int col = bn + wn + j * 16 + lr;
                float v = acc[i][j][rr];
                if constexpr (EPI == 0) {
                    ((float*)C)[moff + col] = v + bias[col];
                } else if constexpr (EPI == 1) {
                    ((f16*)C)[moff + col] = (f16)gelu_f(v + bias[col]);
                } else if constexpr (EPI == 2) {
                    ((float*)C)[moff + col] += gamma[col] * (v + bias[col]);
                } else {
                    ((f16*)C)[moff + col] = (f16)(v * bias[col]);
                }
            }
        }
    }
}

// ---- fp16 MFMA GEMM v7 (r11-proven): 256x128 block, wave 128x64, BK=32, vmcnt(6) ----
// Used for shapes with grid >= 512 blocks at BM=256 (pw1, head, istft).
#define ASZ_ 8192   // f16 elems per A tile (256x32)
#define RSZ_ 12288  // ring slot (A + B)

__device__ __forceinline__ void stageA256(const f16* __restrict__ g, f16* s,
                                          int K, int kof, int tid) {
    int dr0 = tid >> 3;        // 0..31
    int sl  = tid & 7;
#pragma unroll
    for (int i = 0; i < 4; ++i) {
        int d  = dr0 + (i << 5);           // double-row 0..127
        int gs = sl ^ (d & 7);
        int row = (d << 1) + (gs >> 2);    // 0..255
        int kc  = gs & 3;
        gload16(g + (size_t)row * K + kof + (kc << 3),
                s + (d << 6) + (sl << 3));
    }
}

__device__ __forceinline__ void stageB128(const f16* __restrict__ g, f16* s,
                                          int K, int kof, int tid) {
    int dr0 = tid >> 3;
    int sl  = tid & 7;
#pragma unroll
    for (int i = 0; i < 2; ++i) {
        int d  = dr0 + (i << 5);           // double-row 0..63
        int gs = sl ^ (d & 7);
        int row = (d << 1) + (gs >> 2);    // 0..127
        int kc  = gs & 3;
        gload16(g + (size_t)row * K + kof + (kc << 3),
                s + (d << 6) + (sl << 3));
    }
}

template <int EPI>
__global__ __launch_bounds__(256, 2) void k_hgemm7(const f16* __restrict__ A,
                                                   const f16* __restrict__ W,
                                                   const float* __restrict__ bias,
                                                   const float* __restrict__ gamma,
                                                   void* __restrict__ C,
                                                   int K, int ldc, int nNt) {
    __shared__ f16 lds[3 * RSZ_];
    int tid = threadIdx.x;
    int nwg = gridDim.x, bid = blockIdx.x;
    int q = nwg >> 3, r = nwg & 7;
    int xcd = bid & 7, lin = bid >> 3;
    int swz = (xcd < r ? xcd * (q + 1) : r * (q + 1) + (xcd - r) * q) + lin;
    int bm = (swz / nNt) << 8;      // 256-row M tiles
    int bn = (swz % nNt) << 7;      // 128-col N tiles
    const f16* gA = A + (size_t)bm * K;
    const f16* gW = W + (size_t)bn * K;

    int l = tid & 63;
    int wv = tid >> 6;
    int wm = (wv & 1) << 7;    // 2 wave-rows of 128
    int wn = (wv >> 1) << 6;   // 2 wave-cols of 64
    int lr = l & 15;
    int lk = l >> 4;
    int lrh = lr >> 1;
    int s0l = ((lr & 1) << 2) | lk;

    int offA[8], offB[4];
#pragma unroll
    for (int i = 0; i < 8; ++i) {
        int dA = (wm >> 1) + i * 8 + lrh;           // double-row 0..127
        offA[i] = (dA << 6) + ((s0l ^ (dA & 7)) << 3);
    }
#pragma unroll
    for (int j = 0; j < 4; ++j) {
        int dB = (wn >> 1) + j * 8 + lrh;           // double-row 0..63
        offB[j] = (dB << 6) + ((s0l ^ (dB & 7)) << 3);
    }

    f32x4 acc[8][4];
#pragma unroll
    for (int i = 0; i < 8; ++i)
#pragma unroll
        for (int j = 0; j < 4; ++j) acc[i][j] = {0.f, 0.f, 0.f, 0.f};

    int nk = K >> 5;
    f16* s0 = lds;
    f16* s1 = lds + RSZ_;
    f16* s2 = lds + 2 * RSZ_;

    stageA256(gA, s0, K, 0, tid);      stageB128(gW, s0 + ASZ_, K, 0, tid);
    stageA256(gA, s1, K, 32, tid);     stageB128(gW, s1 + ASZ_, K, 32, tid);
    asm volatile("s_waitcnt vmcnt(6)" ::: "memory");
    __builtin_amdgcn_s_barrier();

    for (int t = 0; t < nk; ++t) {
        bool stg = (t + 2 < nk);
        if (stg) {
            int ko = (t + 2) << 5;
            stageA256(gA, s2, K, ko, tid);
            stageB128(gW, s2 + ASZ_, K, ko, tid);
        }
        f16x8 af[8], bf[4];
#pragma unroll
        for (int i = 0; i < 8; ++i) af[i] = *(const f16x8*)(s0 + offA[i]);
#pragma unroll
        for (int j = 0; j < 4; ++j) bf[j] = *(const f16x8*)(s0 + ASZ_ + offB[j]);
        __builtin_amdgcn_s_setprio(1);
#pragma unroll
        for (int i = 0; i < 8; ++i)
#pragma unroll
            for (int j = 0; j < 4; ++j) MF(acc[i][j], af[i], bf[j]);
        __builtin_amdgcn_s_setprio(0);
        if (stg)               asm volatile("s_waitcnt vmcnt(6)" ::: "memory");
        else if (t + 1 < nk)   asm volatile("s_waitcnt vmcnt(0)" ::: "memory");
        if (t + 1 < nk) {
            __builtin_amdgcn_s_barrier();
            asm volatile("" ::: "memory");
        }
        f16* tmp = s0; s0 = s1; s1 = s2; s2 = tmp;
    }

    int lk4 = lk << 2;
#pragma unroll
    for (int i = 0; i < 8; ++i) {
#pragma unroll
        for (int rr = 0; rr < 4; ++rr) {
            int row = bm + wm + i * 16 + lk4 + rr;
            size_t moff = (size_t)row * ldc;
#pragma unroll
            for (int j = 0; j < 4; ++j) {
                int col = bn + wn + j * 16 + lr;
                float v = acc[i][j][rr];
                if constexpr (EPI == 0) {
                    ((float*)C)[moff + col] = v + bias[col];
                } else if constexpr (EPI == 1) {
                    ((f16*)C)[moff + col] = (f16)gelu_f(v + bias[col]);
                } else if constexpr (EPI == 2) {
                    ((float*)C)[moff + col] += gamma[col] * (v + bias[col]);
                } else {
                    ((f16*)C)[moff + col] = (f16)(v * bias[col]);
                }
            }
        }
    }
}

// ---------------- head fp32 (stride 1152) -> S fp16 (stride 1088, padded) ----------------
__global__ __launch_bounds__(256) void k_srsi(const float* __restrict__ o,
                                              f16* __restrict__ S) {
    int idx = blockIdx.x * 256 + threadIdx.x;
    if (idx >= BT_ * KI_) return;
    int m = idx / KI_;
    int f2 = idx - m * KI_;
    size_t base = (size_t)m * NPAD_;
    float v = 0.0f;
    if (f2 < NF_) {
        float mag = fminf(__expf(o[base + f2]), 100.0f);
        float sn, cs;
        __sincosf(o[base + NF_ + f2], &sn, &cs);
        v = mag * cs;
    } else if (f2 < NO2_) {
        int f = f2 - NF_;
        float mag = fminf(__expf(o[base + f]), 100.0f);
        float sn, cs;
        __sincosf(o[base + NF_ + f], &sn, &cs);
        v = mag * sn;
    }
    S[idx] = (f16)v;
}

// ---------------- overlap-add + win_env + crop (deterministic gather, f16 frames) ------
__global__ __launch_bounds__(256) void k_gather(const f16* __restrict__ frames,
                                                const float* __restrict__ win,
                                                float* __restrict__ out) {
    int idx = blockIdx.x * 256 + threadIdx.x;
    int b  = idx / LOUT_;
    int lp = idx - b * LOUT_;
    int l = lp + (NFFT_ / 2);
    int thi = l >> 8;
    if (thi > T_ - 1) thi = T_ - 1;
    int tlo = l - (NFFT_ - 1) + (HOP_ - 1);
    tlo = (tlo < 0) ? 0 : (tlo >> 8);
    float num = 0.0f, den = 0.0f;
    for (int t = tlo; t <= thi; ++t) {
        int n = l - (t << 8);
        float wv = win[n];
        num += (float)frames[((size_t)(b * T_ + t) << 10) + n];
        den = fmaf(wv, wv, den);
    }
    out[idx] = num / (den + 1e-11f);
}

// ---------------- launch ----------------
extern "C" void kernel_launch(void* const* d_in, const int* in_sizes, int n_in,
                              void* d_out, int out_size, void* d_ws, size_t ws_size,
                              hipStream_t stream) {
    (void)in_sizes; (void)n_in; (void)out_size; (void)ws_size;
    const float* mel     = (const float*)d_in[0];
    const float* embed_w = (const float*)d_in[1];
    const float* embed_b = (const float*)d_in[2];
    const float* norm_w  = (const float*)d_in[3];
    const float* norm_b  = (const float*)d_in[4];
    const float* bdw = (const float*)d_in[5];
    const float* bdb = (const float*)d_in[6];
    const float* bnw = (const float*)d_in[7];
    const float* bnb = (const float*)d_in[8];
    const float* bw1 = (const float*)d_in[9];
    const float* bb1 = (const float*)d_in[10];
    const float* bw2 = (const float*)d_in[11];
    const float* bb2 = (const float*)d_in[12];
    const float* bg  = (const float*)d_in[13];
    const float* fnw = (const float*)d_in[14];
    const float* fnb = (const float*)d_in[15];
    const float* hw  = (const float*)d_in[16];
    const float* hb  = (const float*)d_in[17];
    const float* win = (const float*)d_in[18];

    char* ws = (char*)d_ws;
    float* xbuf   = (float*)ws;
    f16*   melTp  = (f16*)ws;                     // transient, dead after k_expand
    f16*   ybuf_h = (f16*)(ws + 33554432);
    f16*   S_h    = (f16*)ws;
    char* R = ws + 50331648;
    f16*   hbuf_h = (f16*)(R + 33554432);
    f16*   A_h    = (f16*)R;
    float* obuf   = (float*)R;
    f16*   frames_h = (f16*)R;
    char* Wr = ws + 134217728;
    f16*   w1_h   = (f16*)Wr;                     // 12,582,912
    f16*   w2_h   = (f16*)(Wr + 12582912);        // 12,582,912
    f16*   head_h = (f16*)(Wr + 25165824);        // 1,179,648
    f16*   wmat_h = (f16*)(Wr + 26345472);        // 2,228,224
    f16*   we_h   = (f16*)(Wr + 28573696);        // 1,376,256
    float* hb_pad = (float*)(Wr + 29949952);      // 4,608
    float* dwT    = (float*)(Wr + 29954560);      // 114,688

    const int nW1 = 8 * H_ * D_;
    k_cvt<<<(nW1 + 255) / 256, 256, 0, stream>>>(bw1, w1_h, nW1);
    k_cvt<<<(nW1 + 255) / 256, 256, 0, stream>>>(bw2, w2_h, nW1);
    k_cvt_embed<<<(D_ * KE_ + 255) / 256, 256, 0, stream>>>(embed_w, we_h);
    k_cvt_head<<<(NPAD_ * D_ + 255) / 256, 256, 0, stream>>>(hw, head_h);
    k_pad_hb<<<5, 256, 0, stream>>>(hb, hb_pad);
    k_cvtdw<<<(8 * 3584 + 255) / 256, 256, 0, stream>>>(bdw, dwT);
    k_build_wmat<<<(NFFT_ * KI_ + 255) / 256, 256, 0, stream>>>(wmat_h);

    // embed conv: mel -> melTp (fp16 t-major) -> A_h (im2col via contiguous row copies)
    k_melT<<<(B_ * TP_ * 24 + 255) / 256, 256, 0, stream>>>(mel, melTp);
    k_expand<<<(BT_ * 168 + 255) / 256, 256, 0, stream>>>(melTp, A_h);
    // N=512 shapes -> v5 (grid 512, 3 blocks/CU); big-N shapes -> v7 (grid >= 512)
    k_hgemm5<0><<<128 * 4, 256, 0, stream>>>(A_h, we_h, embed_b, nullptr, xbuf,
                                             KE_, D_, 4);
    k_ln<false><<<BT_, 64, 0, stream>>>(xbuf, xbuf, norm_w, norm_b);

    for (int bl = 0; bl < 8; ++bl) {
        k_dwln2<<<B_ * 128, 256, 0, stream>>>(xbuf, dwT + bl * 3584, bdb + bl * D_,
                                              bnw + bl * D_, bnb + bl * D_, ybuf_h);
        k_hgemm7<1><<<64 * 12, 256, 0, stream>>>(ybuf_h, w1_h + (size_t)bl * H_ * D_,
                                                 bb1 + bl * H_, nullptr, hbuf_h,
                                                 D_, H_, 12);
        k_hgemm5<2><<<128 * 4, 256, 0, stream>>>(hbuf_h, w2_h + (size_t)bl * D_ * H_,
                                                 bb2 + bl * D_, bg + bl * D_, xbuf,
                                                 H_, D_, 4);
    }

    k_ln<true><<<BT_, 64, 0, stream>>>(xbuf, ybuf_h, fnw, fnb);
    k_hgemm7<0><<<64 * 9, 256, 0, stream>>>(ybuf_h, head_h, hb_pad, nullptr, obuf,
                                            D_, NPAD_, 9);
    k_srsi<<<(BT_ * KI_ + 255) / 256, 256, 0, stream>>>(obuf, S_h);
    k_hgemm7<3><<<64 * 8, 256, 0, stream>>>(S_h, wmat_h, win, nullptr, frames_h,
                                            KI_, NFFT_, 8);
    k_gather<<<B_ * LOUT_ / 256, 256, 0, stream>>>(frames_h, win, (float*)d_out);
}

// Round 13
// 986.862 us; speedup vs baseline: 1.1063x; 1.0887x over previous
//
#include <hip/hip_runtime.h>
#include <cmath>

#define B_ 8
#define T_ 2048
#define BT_ 16384
#define D_ 512
#define H_ 1536
#define CM_ 192
#define KE_ 1344      // embed K = 192*7 (divisible by 32)
#define TP_ 2054      // padded t-rows per batch in melTp (3 zero pad each side)
#define NFFT_ 1024
#define NF_ 513
#define HOP_ 256
#define NO2_ 1026
#define NPAD_ 1152    // head N padded to tile multiple
#define KI_ 1088      // ISTFT K (= 1026 padded to 32-multiple)
#define LOUT_ 524032

typedef _Float16 f16;
typedef f16 f16x8 __attribute__((ext_vector_type(8)));
typedef float f32x4 __attribute__((ext_vector_type(4)));

// tanh-form GELU: |err| vs exact-erf gelu <= ~3e-4, far under budget
__device__ __forceinline__ float gelu_f(float v) {
    float u = 0.7978845608028654f * v * (1.0f + 0.044715f * v * v);
    float e = __expf(2.0f * u);
    float t = 1.0f - 2.0f * __builtin_amdgcn_rcpf(e + 1.0f);
    return 0.5f * v * (1.0f + t);
}

__device__ __forceinline__ void gload16(const void* g, void* s) {
    __builtin_amdgcn_global_load_lds((const __attribute__((address_space(1))) void*)g,
                                     (__attribute__((address_space(3))) void*)s, 16, 0, 0);
}

// ---------------- conversion / prep kernels ----------------

__global__ __launch_bounds__(256) void k_cvt(const float* __restrict__ src,
                                             f16* __restrict__ dst, int n) {
    int i = blockIdx.x * 256 + threadIdx.x;
    if (i < n) dst[i] = (f16)src[i];
}

// head weights (1026,512) -> fp16 (1152,512) zero-padded rows
__global__ __launch_bounds__(256) void k_cvt_head(const float* __restrict__ src,
                                                  f16* __restrict__ dst) {
    int i = blockIdx.x * 256 + threadIdx.x;
    if (i >= NPAD_ * D_) return;
    int row = i >> 9;
    dst[i] = (row < NO2_) ? (f16)src[i] : (f16)0.0f;
}

__global__ __launch_bounds__(256) void k_pad_hb(const float* __restrict__ src,
                                                float* __restrict__ dst) {
    int i = blockIdx.x * 256 + threadIdx.x;
    if (i < NPAD_) dst[i] = (i < NO2_) ? src[i] : 0.0f;
}

// embed_w (D,Cm,7) -> we_h[d][tap*192 + c]  (tap-major K-order, matches A_h)
__global__ __launch_bounds__(256) void k_cvt_embed(const float* __restrict__ src,
                                                   f16* __restrict__ dst) {
    int i = blockIdx.x * 256 + threadIdx.x;
    if (i >= D_ * KE_) return;
    int d = i / KE_;
    int r2 = i - d * KE_;
    int tap = r2 / CM_;
    int c = r2 - tap * CM_;
    dst[i] = (f16)src[(d * CM_ + c) * 7 + tap];
}

// dw (8,512,7) -> dwT[bl][k][d]
__global__ __launch_bounds__(256) void k_cvtdw(const float* __restrict__ dw,
                                               float* __restrict__ dwT) {
    int i = blockIdx.x * 256 + threadIdx.x;
    if (i >= 8 * 7 * 512) return;
    int bl = i / 3584;
    int rem = i - bl * 3584;
    int k = rem >> 9;
    int d = rem & 511;
    dwT[i] = dw[bl * 3584 + d * 7 + k];
}

// mel (B,Cm,T) fp32 -> melTp[b][tp 0..2053][c 0..191] fp16, tp=t+3, pad rows zero
__global__ __launch_bounds__(256) void k_melT(const float* __restrict__ mel,
                                              f16* __restrict__ mt) {
    int idx = blockIdx.x * 256 + threadIdx.x;   // B_*TP_*24
    if (idx >= B_ * TP_ * 24) return;
    int c8 = idx % 24;
    int rem = idx / 24;
    int tp = rem % TP_;
    int b = rem / TP_;
    int t = tp - 3;
    f16x8 v;
    if (t >= 0 && t < T_) {
        const float* mp = mel + ((size_t)b * CM_ + c8 * 8) * T_ + t;
#pragma unroll
        for (int i = 0; i < 8; ++i) v[i] = (f16)mp[(size_t)i * T_];
    } else {
#pragma unroll
        for (int i = 0; i < 8; ++i) v[i] = (f16)0.0f;
    }
    *(f16x8*)(mt + (size_t)idx * 8) = v;
}

// expand melTp -> A_h: row bt = contiguous 1344 f16 starting at melTp[b][t][0]
__global__ __launch_bounds__(256) void k_expand(const f16* __restrict__ mt,
                                               f16* __restrict__ A) {
    int g = blockIdx.x * 256 + threadIdx.x;    // BT_*168 chunks of 8 f16
    if (g >= BT_ * 168) return;
    int bt = g / 168;
    int k8 = g - bt * 168;
    int b = bt >> 11;
    int t = bt & (T_ - 1);
    f16x8 v = *(const f16x8*)(mt + ((size_t)(b * TP_ + t) * CM_) + k8 * 8);
    *(f16x8*)(A + (size_t)bt * KE_ + k8 * 8) = v;
}

// ISTFT basis fp16: wmat[n][f2], f2<513: cos*scale ; 513..1025: -sin*scale ; pad 0
__global__ __launch_bounds__(256) void k_build_wmat(f16* __restrict__ wmat) {
    int idx = blockIdx.x * 256 + threadIdx.x;
    if (idx >= NFFT_ * KI_) return;
    int n = idx / KI_;
    int f2 = idx - n * KI_;
    float v = 0.0f;
    if (f2 < NF_) {
        int r = (n * f2) & (NFFT_ - 1);
        float sc = (f2 == 0 || f2 == NF_ - 1) ? (1.0f / NFFT_) : (2.0f / NFFT_);
        v = cospif((float)r * (2.0f / NFFT_)) * sc;
    } else if (f2 < NO2_) {
        int f = f2 - NF_;
        int r = (n * f) & (NFFT_ - 1);
        float sc = (f == 0 || f == NF_ - 1) ? (1.0f / NFFT_) : (2.0f / NFFT_);
        v = -sinpif((float)r * (2.0f / NFFT_)) * sc;
    }
    wmat[idx] = (f16)v;
}

// ---------------- LayerNorm over D=512, f16 in -> f16 out, one wave per row ----------------
__global__ __launch_bounds__(64) void k_lnh(const f16* __restrict__ in,
                                            f16* __restrict__ out,
                                            const float* __restrict__ w,
                                            const float* __restrict__ b) {
    int row = blockIdx.x;
    int lane = threadIdx.x;
    f16x8 hv = *(const f16x8*)(in + (size_t)row * D_ + lane * 8);
    float x[8];
#pragma unroll
    for (int i = 0; i < 8; ++i) x[i] = (float)hv[i];
    float s = 0.f, ss = 0.f;
#pragma unroll
    for (int i = 0; i < 8; ++i) { s += x[i]; ss = fmaf(x[i], x[i], ss); }
#pragma unroll
    for (int off = 32; off > 0; off >>= 1) {
        s  += __shfl_xor(s, off);
        ss += __shfl_xor(ss, off);
    }
    float mean = s * (1.0f / 512.0f);
    float var  = ss * (1.0f / 512.0f) - mean * mean;
    float rs = rsqrtf(var + 1e-5f);
    const float* wp = w + lane * 8;
    const float* bp = b + lane * 8;
    float4 w0 = *(const float4*)wp, w1 = *(const float4*)(wp + 4);
    float4 b0 = *(const float4*)bp, b1 = *(const float4*)(bp + 4);
    float wv[8] = {w0.x, w0.y, w0.z, w0.w, w1.x, w1.y, w1.z, w1.w};
    float bv[8] = {b0.x, b0.y, b0.z, b0.w, b1.x, b1.y, b1.z, b1.w};
    f16x8 h;
#pragma unroll
    for (int i = 0; i < 8; ++i) h[i] = (f16)((x[i] - mean) * rs * wv[i] + bv[i]);
    *(f16x8*)(out + (size_t)row * D_ + lane * 8) = h;
}

// ---- fused depthwise conv + LayerNorm, t-tiled via LDS, f16 trunk input ----
// One block = 16 output t-rows x D=512 for one batch; stages 22 rows (halo 3+3) into
// float LDS (converted once at staging). Same compute/reduce as r10-proven dwln2.
__global__ __launch_bounds__(256) void k_dwln2h(const f16* __restrict__ x,
                                                const float* __restrict__ dwT,
                                                const float* __restrict__ db,
                                                const float* __restrict__ nw,
                                                const float* __restrict__ nb,
                                                f16* __restrict__ out) {
    __shared__ float xs[22][512];
    int tid = threadIdx.x;
    int blk = blockIdx.x;            // b*128 + tc
    int b = blk >> 7;
    int t0 = (blk & 127) << 4;
    const f16* xb = x + ((size_t)b << 20);     // b * T_ * D_ (f16)
#pragma unroll
    for (int i = 0; i < 6; ++i) {
        int idx = tid + (i << 8);    // chunk of 8 f16 over 22*64
        if (idx < 22 * 64) {
            int row = idx >> 6;
            int c8 = idx & 63;
            int t = t0 + row - 3;
            float v[8];
            if (t >= 0 && t < T_) {
                f16x8 hv = *(const f16x8*)(xb + ((size_t)t << 9) + (c8 << 3));
#pragma unroll
                for (int u = 0; u < 8; ++u) v[u] = (float)hv[u];
            } else {
#pragma unroll
                for (int u = 0; u < 8; ++u) v[u] = 0.0f;
            }
            *(float4*)&xs[row][c8 << 3] = make_float4(v[0], v[1], v[2], v[3]);
            *(float4*)&xs[row][(c8 << 3) + 4] = make_float4(v[4], v[5], v[6], v[7]);
        }
    }
    __syncthreads();

    int o = tid & 63;          // d-octet
    int slot = tid >> 6;       // wave id = t-group
    int d0 = o << 3;
    float acc[4][8];
    {
        float4 b0 = *(const float4*)(db + d0);
        float4 b1 = *(const float4*)(db + d0 + 4);
#pragma unroll
        for (int u = 0; u < 4; ++u) {
            acc[u][0] = b0.x; acc[u][1] = b0.y; acc[u][2] = b0.z; acc[u][3] = b0.w;
            acc[u][4] = b1.x; acc[u][5] = b1.y; acc[u][6] = b1.z; acc[u][7] = b1.w;
        }
    }
#pragma unroll
    for (int k = 0; k < 7; ++k) {
        float w8[8];
        *(float4*)&w8[0] = *(const float4*)(dwT + (k << 9) + d0);
        *(float4*)&w8[4] = *(const float4*)(dwT + (k << 9) + d0 + 4);
#pragma unroll
        for (int u = 0; u < 4; ++u) {
            int row = (slot << 2) + u + k;   // t_local + k, in [0,21]
            float x8[8];
            *(float4*)&x8[0] = *(const float4*)&xs[row][d0];
            *(float4*)&x8[4] = *(const float4*)&xs[row][d0 + 4];
#pragma unroll
            for (int i = 0; i < 8; ++i) acc[u][i] = fmaf(w8[i], x8[i], acc[u][i]);
        }
    }
    float4 w0 = *(const float4*)(nw + d0), w1 = *(const float4*)(nw + d0 + 4);
    float4 n0 = *(const float4*)(nb + d0), n1 = *(const float4*)(nb + d0 + 4);
    float nwv[8] = {w0.x, w0.y, w0.z, w0.w, w1.x, w1.y, w1.z, w1.w};
    float nbv[8] = {n0.x, n0.y, n0.z, n0.w, n1.x, n1.y, n1.z, n1.w};
#pragma unroll
    for (int u = 0; u < 4; ++u) {
        float s = 0.f, ss = 0.f;
#pragma unroll
        for (int i = 0; i < 8; ++i) { s += acc[u][i]; ss = fmaf(acc[u][i], acc[u][i], ss); }
#pragma unroll
        for (int off = 32; off > 0; off >>= 1) {
            s  += __shfl_xor(s, off);
            ss += __shfl_xor(ss, off);
        }
        float mean = s * (1.0f / 512.0f);
        float var  = ss * (1.0f / 512.0f) - mean * mean;
        float rs = rsqrtf(var + 1e-5f);
        f16x8 h;
#pragma unroll
        for (int i = 0; i < 8; ++i)
            h[i] = (f16)((acc[u][i] - mean) * rs * nwv[i] + nbv[i]);
        int t = t0 + (slot << 2) + u;
        *(f16x8*)(out + (((size_t)(b << 11) + t) << 9) + d0) = h;
    }
}

#define MF(d, a, b) d = __builtin_amdgcn_mfma_f32_16x16x32_f16(a, b, d, 0, 0, 0)

// ---- fp16 MFMA GEMM v5 (r6/r8/r10-proven): 128x128, BK=32, 3-ring, vmcnt(4) ----
// Routed to all shapes except istft (grid quantization: v5's 3/CU splits benignly).
// EPI: 0 = fp32 +bias (head) ; 1 = f16 gelu (pw1) ; 4 = f16 +bias (embed) ;
//      5 = f16 residual RMW: C = C + gamma*(v+bias)  (pw2, fp16 trunk)
#define TSZ_ 4096   // f16 elems per matrix tile (128x32)

__device__ __forceinline__ void stage32(const f16* __restrict__ g, f16* s,
                                        int K, int kof, int tid) {
    int dr0 = tid >> 3;        // 0..31
    int sl  = tid & 7;
#pragma unroll
    for (int i = 0; i < 2; ++i) {
        int d  = dr0 + (i << 5);           // double-row 0..63
        int gs = sl ^ (d & 7);             // pre-swizzled global slot
        int row = (d << 1) + (gs >> 2);
        int kc  = gs & 3;
        gload16(g + (size_t)row * K + kof + (kc << 3),
                s + (d << 6) + (sl << 3)); // linear dest: wave base + lane*16B
    }
}

template <int EPI>
__global__ __launch_bounds__(256, 3) void k_hgemm5(const f16* __restrict__ A,
                                                   const f16* __restrict__ W,
                                                   const float* __restrict__ bias,
                                                   const float* __restrict__ gamma,
                                                   void* __restrict__ C,
                                                   int K, int ldc, int nNt) {
    __shared__ f16 lds[3 * 2 * TSZ_];
    int tid = threadIdx.x;
    int nwg = gridDim.x, bid = blockIdx.x;
    int q = nwg >> 3, r = nwg & 7;
    int xcd = bid & 7, lin = bid >> 3;
    int swz = (xcd < r ? xcd * (q + 1) : r * (q + 1) + (xcd - r) * q) + lin;
    int bm = (swz / nNt) << 7;
    int bn = (swz % nNt) << 7;
    const f16* gA = A + (size_t)bm * K;
    const f16* gW = W + (size_t)bn * K;

    int l = tid & 63;
    int wv = tid >> 6;
    int wm = (wv & 1) << 6;    // 2 wave-rows of 64
    int wn = (wv >> 1) << 6;   // 2 wave-cols of 64
    int lr = l & 15;
    int lk = l >> 4;
    int lrh = lr >> 1;
    int s0l = ((lr & 1) << 2) | lk;   // logical slot for this lane's (row-half, chunk)

    int offA[4], offB[4];
#pragma unroll
    for (int i = 0; i < 4; ++i) {
        int dA = (wm >> 1) + i * 8 + lrh;
        offA[i] = (dA << 6) + ((s0l ^ (dA & 7)) << 3);
        int dB = (wn >> 1) + i * 8 + lrh;
        offB[i] = (dB << 6) + ((s0l ^ (dB & 7)) << 3);
    }

    f32x4 acc[4][4];
#pragma unroll
    for (int i = 0; i < 4; ++i)
#pragma unroll
        for (int j = 0; j < 4; ++j) acc[i][j] = {0.f, 0.f, 0.f, 0.f};

    int nk = K >> 5;
    f16* s0 = lds;
    f16* s1 = lds + 2 * TSZ_;
    f16* s2 = lds + 4 * TSZ_;

    stage32(gA, s0, K, 0, tid);        stage32(gW, s0 + TSZ_, K, 0, tid);
    stage32(gA, s1, K, 32, tid);       stage32(gW, s1 + TSZ_, K, 32, tid);
    asm volatile("s_waitcnt vmcnt(4)" ::: "memory");
    __builtin_amdgcn_s_barrier();

    for (int t = 0; t < nk; ++t) {
        bool stg = (t + 2 < nk);
        if (stg) {
            int ko = (t + 2) << 5;
            stage32(gA, s2, K, ko, tid);
            stage32(gW, s2 + TSZ_, K, ko, tid);
        }
        f16x8 af[4], bf[4];
#pragma unroll
        for (int i = 0; i < 4; ++i) af[i] = *(const f16x8*)(s0 + offA[i]);
#pragma unroll
        for (int j = 0; j < 4; ++j) bf[j] = *(const f16x8*)(s0 + TSZ_ + offB[j]);
        __builtin_amdgcn_s_setprio(1);
#pragma unroll
        for (int i = 0; i < 4; ++i)
#pragma unroll
            for (int j = 0; j < 4; ++j) MF(acc[i][j], af[i], bf[j]);
        __builtin_amdgcn_s_setprio(0);
        if (stg)               asm volatile("s_waitcnt vmcnt(4)" ::: "memory");
        else if (t + 1 < nk)   asm volatile("s_waitcnt vmcnt(0)" ::: "memory");
        if (t + 1 < nk) {
            __builtin_amdgcn_s_barrier();
            asm volatile("" ::: "memory");
        }
        f16* tmp = s0; s0 = s1; s1 = s2; s2 = tmp;
    }

    int lk4 = lk << 2;
#pragma unroll
    for (int i = 0; i < 4; ++i) {
#pragma unroll
        for (int rr = 0; rr < 4; ++rr) {
            int row = bm + wm + i * 16 + lk4 + rr;
            size_t moff = (size_t)row * ldc;
#pragma unroll
            for (int j = 0; j < 4; ++j) {
                int col = bn + wn + j * 16 + lr;
                float v = acc[i][j][rr];
                if constexpr (EPI == 0) {
                    ((float*)C)[moff + col] = v + bias[col];
                } else if constexpr (EPI == 1) {
                    ((f16*)C)[moff + col] = (f16)gelu_f(v + bias[col]);
                } else if constexpr (EPI == 4) {
                    ((f16*)C)[moff + col] = (f16)(v + bias[col]);
                } else if constexpr (EPI == 5) {
                    f16* Cp = (f16*)C;
                    float old = (float)Cp[moff + col];
                    Cp[moff + col] = (f16)(old + gamma[col] * (v + bias[col]));
                } else {
                    ((f16*)C)[moff + col] = (f16)(v * bias[col]);
                }
            }
        }
    }
}

// ---- fp16 MFMA GEMM v7 (r11/r12-proven): 256x128 block, wave 128x64, BK=32, vmcnt(6) ----
// Routed ONLY to istft (grid 512 = exactly 2 blocks/CU x 256 CU, zero tail).
#define ASZ_ 8192   // f16 elems per A tile (256x32)
#define RSZ_ 12288  // ring slot (A + B)

__device__ __forceinline__ void stageA256(const f16* __restrict__ g, f16* s,
                                          int K, int kof, int tid) {
    int dr0 = tid >> 3;        // 0..31
    int sl  = tid & 7;
#pragma unroll
    for (int i = 0; i < 4; ++i) {
        int d  = dr0 + (i << 5);           // double-row 0..127
        int gs = sl ^ (d & 7);
        int row = (d << 1) + (gs >> 2);    // 0..255
        int kc  = gs & 3;
        gload16(g + (size_t)row * K + kof + (kc << 3),
                s + (d << 6) + (sl << 3));
    }
}

__device__ __forceinline__ void stageB128(const f16* __restrict__ g, f16* s,
                                          int K, int kof, int tid) {
    int dr0 = tid >> 3;
    int sl  = tid & 7;
#pragma unroll
    for (int i = 0; i < 2; ++i) {
        int d  = dr0 + (i << 5);           // double-row 0..63
        int gs = sl ^ (d & 7);
        int row = (d << 1) + (gs >> 2);    // 0..127
        int kc  = gs & 3;
        gload16(g + (size_t)row * K + kof + (kc << 3),
                s + (d << 6) + (sl << 3));
    }
}

template <int EPI>
__global__ __launch_bounds__(256, 2) void k_hgemm7(const f16* __restrict__ A,
                                                   const f16* __restrict__ W,
                                                   const float* __restrict__ bias,
                                                   const float* __restrict__ gamma,
                                                   void* __restrict__ C,
                                                   int K, int ldc, int nNt) {
    __shared__ f16 lds[3 * RSZ_];
    int tid = threadIdx.x;
    int nwg = gridDim.x, bid = blockIdx.x;
    int q = nwg >> 3, r = nwg & 7;
    int xcd = bid & 7, lin = bid >> 3;
    int swz = (xcd < r ? xcd * (q + 1) : r * (q + 1) + (xcd - r) * q) + lin;
    int bm = (swz / nNt) << 8;      // 256-row M tiles
    int bn = (swz % nNt) << 7;      // 128-col N tiles
    const f16* gA = A + (size_t)bm * K;
    const f16* gW = W + (size_t)bn * K;

    int l = tid & 63;
    int wv = tid >> 6;
    int wm = (wv & 1) << 7;    // 2 wave-rows of 128
    int wn = (wv >> 1) << 6;   // 2 wave-cols of 64
    int lr = l & 15;
    int lk = l >> 4;
    int lrh = lr >> 1;
    int s0l = ((lr & 1) << 2) | lk;

    int offA[8], offB[4];
#pragma unroll
    for (int i = 0; i < 8; ++i) {
        int dA = (wm >> 1) + i * 8 + lrh;           // double-row 0..127
        offA[i] = (dA << 6) + ((s0l ^ (dA & 7)) << 3);
    }
#pragma unroll
    for (int j = 0; j < 4; ++j) {
        int dB = (wn >> 1) + j * 8 + lrh;           // double-row 0..63
        offB[j] = (dB << 6) + ((s0l ^ (dB & 7)) << 3);
    }

    f32x4 acc[8][4];
#pragma unroll
    for (int i = 0; i < 8; ++i)
#pragma unroll
        for (int j = 0; j < 4; ++j) acc[i][j] = {0.f, 0.f, 0.f, 0.f};

    int nk = K >> 5;
    f16* s0 = lds;
    f16* s1 = lds + RSZ_;
    f16* s2 = lds + 2 * RSZ_;

    stageA256(gA, s0, K, 0, tid);      stageB128(gW, s0 + ASZ_, K, 0, tid);
    stageA256(gA, s1, K, 32, tid);     stageB128(gW, s1 + ASZ_, K, 32, tid);
    asm volatile("s_waitcnt vmcnt(6)" ::: "memory");
    __builtin_amdgcn_s_barrier();

    for (int t = 0; t < nk; ++t) {
        bool stg = (t + 2 < nk);
        if (stg) {
            int ko = (t + 2) << 5;
            stageA256(gA, s2, K, ko, tid);
            stageB128(gW, s2 + ASZ_, K, ko, tid);
        }
        f16x8 af[8], bf[4];
#pragma unroll
        for (int i = 0; i < 8; ++i) af[i] = *(const f16x8*)(s0 + offA[i]);
#pragma unroll
        for (int j = 0; j < 4; ++j) bf[j] = *(const f16x8*)(s0 + ASZ_ + offB[j]);
        __builtin_amdgcn_s_setprio(1);
#pragma unroll
        for (int i = 0; i < 8; ++i)
#pragma unroll
            for (int j = 0; j < 4; ++j) MF(acc[i][j], af[i], bf[j]);
        __builtin_amdgcn_s_setprio(0);
        if (stg)               asm volatile("s_waitcnt vmcnt(6)" ::: "memory");
        else if (t + 1 < nk)   asm volatile("s_waitcnt vmcnt(0)" ::: "memory");
        if (t + 1 < nk) {
            __builtin_amdgcn_s_barrier();
            asm volatile("" ::: "memory");
        }
        f16* tmp = s0; s0 = s1; s1 = s2; s2 = tmp;
    }

    int lk4 = lk << 2;
#pragma unroll
    for (int i = 0; i < 8; ++i) {
#pragma unroll
        for (int rr = 0; rr < 4; ++rr) {
            int row = bm + wm + i * 16 + lk4 + rr;
            size_t moff = (size_t)row * ldc;
#pragma unroll
            for (int j = 0; j < 4; ++j) {
                int col = bn + wn + j * 16 + lr;
                float v = acc[i][j][rr];
                if constexpr (EPI == 0) {
                    ((float*)C)[moff + col] = v + bias[col];
                } else {
                    ((f16*)C)[moff + col] = (f16)(v * bias[col]);
                }
            }
        }
    }
}

// ---------------- head fp32 (stride 1152) -> S fp16 (stride 1088, padded) ----------------
__global__ __launch_bounds__(256) void k_srsi(const float* __restrict__ o,
                                              f16* __restrict__ S) {
    int idx = blockIdx.x * 256 + threadIdx.x;
    if (idx >= BT_ * KI_) return;
    int m = idx / KI_;
    int f2 = idx - m * KI_;
    size_t base = (size_t)m * NPAD_;
    float v = 0.0f;
    if (f2 < NF_) {
        float mag = fminf(__expf(o[base + f2]), 100.0f);
        float sn, cs;
        __sincosf(o[base + NF_ + f2], &sn, &cs);
        v = mag * cs;
    } else if (f2 < NO2_) {
        int f = f2 - NF_;
        float mag = fminf(__expf(o[base + f]), 100.0f);
        float sn, cs;
        __sincosf(o[base + NF_ + f], &sn, &cs);
        v = mag * sn;
    }
    S[idx] = (f16)v;
}

// ---------------- overlap-add + win_env + crop (deterministic gather, f16 frames) ------
__global__ __launch_bounds__(256) void k_gather(const f16* __restrict__ frames,
                                                const float* __restrict__ win,
                                                float* __restrict__ out) {
    int idx = blockIdx.x * 256 + threadIdx.x;
    int b  = idx / LOUT_;
    int lp = idx - b * LOUT_;
    int l = lp + (NFFT_ / 2);
    int thi = l >> 8;
    if (thi > T_ - 1) thi = T_ - 1;
    int tlo = l - (NFFT_ - 1) + (HOP_ - 1);
    tlo = (tlo < 0) ? 0 : (tlo >> 8);
    float num = 0.0f, den = 0.0f;
    for (int t = tlo; t <= thi; ++t) {
        int n = l - (t << 8);
        float wv = win[n];
        num += (float)frames[((size_t)(b * T_ + t) << 10) + n];
        den = fmaf(wv, wv, den);
    }
    out[idx] = num / (den + 1e-11f);
}

// ---------------- launch ----------------
extern "C" void kernel_launch(void* const* d_in, const int* in_sizes, int n_in,
                              void* d_out, int out_size, void* d_ws, size_t ws_size,
                              hipStream_t stream) {
    (void)in_sizes; (void)n_in; (void)out_size; (void)ws_size;
    const float* mel     = (const float*)d_in[0];
    const float* embed_w = (const float*)d_in[1];
    const float* embed_b = (const float*)d_in[2];
    const float* norm_w  = (const float*)d_in[3];
    const float* norm_b  = (const float*)d_in[4];
    const float* bdw = (const float*)d_in[5];
    const float* bdb = (const float*)d_in[6];
    const float* bnw = (const float*)d_in[7];
    const float* bnb = (const float*)d_in[8];
    const float* bw1 = (const float*)d_in[9];
    const float* bb1 = (const float*)d_in[10];
    const float* bw2 = (const float*)d_in[11];
    const float* bb2 = (const float*)d_in[12];
    const float* bg  = (const float*)d_in[13];
    const float* fnw = (const float*)d_in[14];
    const float* fnb = (const float*)d_in[15];
    const float* hw  = (const float*)d_in[16];
    const float* hb  = (const float*)d_in[17];
    const float* win = (const float*)d_in[18];

    char* ws = (char*)d_ws;
    // region A: [0, 50.3MB): xbuf_h f16 trunk [0,16.8MB); melTp transient at base (dead
    // before embed GEMM writes xbuf_h); ybuf_h at +33.5MB; S_h overlays base after
    // final LN consumes xbuf_h (same liveness argument as rounds 8-12).
    f16*   xbuf_h = (f16*)ws;
    f16*   melTp  = (f16*)ws;                     // transient, dead after k_expand
    f16*   ybuf_h = (f16*)(ws + 33554432);
    f16*   S_h    = (f16*)ws;
    char* R = ws + 50331648;
    f16*   hbuf_h = (f16*)(R + 33554432);
    f16*   A_h    = (f16*)R;
    float* obuf   = (float*)R;
    f16*   frames_h = (f16*)R;
    char* Wr = ws + 134217728;
    f16*   w1_h   = (f16*)Wr;                     // 12,582,912
    f16*   w2_h   = (f16*)(Wr + 12582912);        // 12,582,912
    f16*   head_h = (f16*)(Wr + 25165824);        // 1,179,648
    f16*   wmat_h = (f16*)(Wr + 26345472);        // 2,228,224
    f16*   we_h   = (f16*)(Wr + 28573696);        // 1,376,256
    float* hb_pad = (float*)(Wr + 29949952);      // 4,608
    float* dwT    = (float*)(Wr + 29954560);      // 114,688

    const int nW1 = 8 * H_ * D_;
    k_cvt<<<(nW1 + 255) / 256, 256, 0, stream>>>(bw1, w1_h, nW1);
    k_cvt<<<(nW1 + 255) / 256, 256, 0, stream>>>(bw2, w2_h, nW1);
    k_cvt_embed<<<(D_ * KE_ + 255) / 256, 256, 0, stream>>>(embed_w, we_h);
    k_cvt_head<<<(NPAD_ * D_ + 255) / 256, 256, 0, stream>>>(hw, head_h);
    k_pad_hb<<<5, 256, 0, stream>>>(hb, hb_pad);
    k_cvtdw<<<(8 * 3584 + 255) / 256, 256, 0, stream>>>(bdw, dwT);
    k_build_wmat<<<(NFFT_ * KI_ + 255) / 256, 256, 0, stream>>>(wmat_h);

    // embed conv: mel -> melTp (fp16 t-major) -> A_h (im2col via contiguous row copies)
    k_melT<<<(B_ * TP_ * 24 + 255) / 256, 256, 0, stream>>>(mel, melTp);
    k_expand<<<(BT_ * 168 + 255) / 256, 256, 0, stream>>>(melTp, A_h);
    k_hgemm5<4><<<128 * 4, 256, 0, stream>>>(A_h, we_h, embed_b, nullptr, xbuf_h,
                                             KE_, D_, 4);
    k_lnh<<<BT_, 64, 0, stream>>>(xbuf_h, xbuf_h, norm_w, norm_b);

    for (int bl = 0; bl < 8; ++bl) {
        k_dwln2h<<<B_ * 128, 256, 0, stream>>>(xbuf_h, dwT + bl * 3584, bdb + bl * D_,
                                               bnw + bl * D_, bnb + bl * D_, ybuf_h);
        k_hgemm5<1><<<128 * 12, 256, 0, stream>>>(ybuf_h, w1_h + (size_t)bl * H_ * D_,
                                                  bb1 + bl * H_, nullptr, hbuf_h,
                                                  D_, H_, 12);
        k_hgemm5<5><<<128 * 4, 256, 0, stream>>>(hbuf_h, w2_h + (size_t)bl * D_ * H_,
                                                 bb2 + bl * D_, bg + bl * D_, xbuf_h,
                                                 H_, D_, 4);
    }

    k_lnh<<<BT_, 64, 0, stream>>>(xbuf_h, ybuf_h, fnw, fnb);
    k_hgemm5<0><<<128 * 9, 256, 0, stream>>>(ybuf_h, head_h, hb_pad, nullptr, obuf,
                                             D_, NPAD_, 9);
    k_srsi<<<(BT_ * KI_ + 255) / 256, 256, 0, stream>>>(obuf, S_h);
    k_hgemm7<3><<<64 * 8, 256, 0, stream>>>(S_h, wmat_h, win, nullptr, frames_h,
                                            KI_, NFFT_, 8);
    k_gather<<<B_ * LOUT_ / 256, 256, 0, stream>>>(frames_h, win, (float*)d_out);
}

// Round 14
// 965.013 us; speedup vs baseline: 1.1313x; 1.0226x over previous
//
#include <hip/hip_runtime.h>
#include <cmath>

#define B_ 8
#define T_ 2048
#define BT_ 16384
#define D_ 512
#define H_ 1536
#define CM_ 192
#define KE_ 1344      // embed K = 192*7 (divisible by 32)
#define TP_ 2054      // padded t-rows per batch in melTp (3 zero pad each side)
#define NFFT_ 1024
#define NF_ 513
#define HOP_ 256
#define NO2_ 1026
#define NPAD_ 1152    // head N padded to tile multiple
#define KI_ 1088      // ISTFT K (= 1026 padded to 32-multiple)
#define LOUT_ 524032

typedef _Float16 f16;
typedef f16 f16x8 __attribute__((ext_vector_type(8)));
typedef float f32x4 __attribute__((ext_vector_type(4)));

// tanh-form GELU: |err| vs exact-erf gelu <= ~3e-4, far under budget
__device__ __forceinline__ float gelu_f(float v) {
    float u = 0.7978845608028654f * v * (1.0f + 0.044715f * v * v);
    float e = __expf(2.0f * u);
    float t = 1.0f - 2.0f * __builtin_amdgcn_rcpf(e + 1.0f);
    return 0.5f * v * (1.0f + t);
}

__device__ __forceinline__ void gload16(const void* g, void* s) {
    __builtin_amdgcn_global_load_lds((const __attribute__((address_space(1))) void*)g,
                                     (__attribute__((address_space(3))) void*)s, 16, 0, 0);
}

// ---------------- fused weight-prep (replaces 7 kernels; identical per-element math) ----
// ranges: w1(6291456) | w2(6291456) | embed(688128) | head(589824) | hb(1152)
//         | dwT(28672) | wmat(1114112)  -> total 15,004,800
__global__ __launch_bounds__(256) void k_prep(const float* __restrict__ bw1,
                                              const float* __restrict__ bw2,
                                              const float* __restrict__ embed_w,
                                              const float* __restrict__ hw,
                                              const float* __restrict__ hb,
                                              const float* __restrict__ bdw,
                                              f16* __restrict__ w1_h,
                                              f16* __restrict__ w2_h,
                                              f16* __restrict__ we_h,
                                              f16* __restrict__ head_h,
                                              float* __restrict__ hb_pad,
                                              float* __restrict__ dwT,
                                              f16* __restrict__ wmat_h) {
    int i = blockIdx.x * 256 + threadIdx.x;
    if (i < 6291456) { w1_h[i] = (f16)bw1[i]; return; }
    i -= 6291456;
    if (i < 6291456) { w2_h[i] = (f16)bw2[i]; return; }
    i -= 6291456;
    if (i < 688128) {   // embed_w (D,Cm,7) -> we_h[d][tap*192 + c]
        int d = i / KE_;
        int r2 = i - d * KE_;
        int tap = r2 / CM_;
        int c = r2 - tap * CM_;
        we_h[i] = (f16)embed_w[(d * CM_ + c) * 7 + tap];
        return;
    }
    i -= 688128;
    if (i < 589824) {   // head (1026,512) -> fp16 (1152,512) zero-padded rows
        int row = i >> 9;
        head_h[i] = (row < NO2_) ? (f16)hw[i] : (f16)0.0f;
        return;
    }
    i -= 589824;
    if (i < 1152) { hb_pad[i] = (i < NO2_) ? hb[i] : 0.0f; return; }
    i -= 1152;
    if (i < 28672) {    // dw (8,512,7) -> dwT[bl][k][d]
        int bl = i / 3584;
        int rem = i - bl * 3584;
        int k = rem >> 9;
        int d = rem & 511;
        dwT[i] = bdw[bl * 3584 + d * 7 + k];
        return;
    }
    i -= 28672;
    if (i < 1114112) {  // ISTFT basis fp16
        int n = i / KI_;
        int f2 = i - n * KI_;
        float v = 0.0f;
        if (f2 < NF_) {
            int r = (n * f2) & (NFFT_ - 1);
            float sc = (f2 == 0 || f2 == NF_ - 1) ? (1.0f / NFFT_) : (2.0f / NFFT_);
            v = cospif((float)r * (2.0f / NFFT_)) * sc;
        } else if (f2 < NO2_) {
            int f = f2 - NF_;
            int r = (n * f) & (NFFT_ - 1);
            float sc = (f == 0 || f == NF_ - 1) ? (1.0f / NFFT_) : (2.0f / NFFT_);
            v = -sinpif((float)r * (2.0f / NFFT_)) * sc;
        }
        wmat_h[i] = (f16)v;
    }
}

// mel (B,Cm,T) fp32 -> melTp[b][tp 0..2053][c 0..191] fp16, tp=t+3, pad rows zero
__global__ __launch_bounds__(256) void k_melT(const float* __restrict__ mel,
                                              f16* __restrict__ mt) {
    int idx = blockIdx.x * 256 + threadIdx.x;   // B_*TP_*24
    if (idx >= B_ * TP_ * 24) return;
    int c8 = idx % 24;
    int rem = idx / 24;
    int tp = rem % TP_;
    int b = rem / TP_;
    int t = tp - 3;
    f16x8 v;
    if (t >= 0 && t < T_) {
        const float* mp = mel + ((size_t)b * CM_ + c8 * 8) * T_ + t;
#pragma unroll
        for (int i = 0; i < 8; ++i) v[i] = (f16)mp[(size_t)i * T_];
    } else {
#pragma unroll
        for (int i = 0; i < 8; ++i) v[i] = (f16)0.0f;
    }
    *(f16x8*)(mt + (size_t)idx * 8) = v;
}

// ---------------- LayerNorm over D=512, f16 in -> f16 out, one wave per row ----------------
__global__ __launch_bounds__(64) void k_lnh(const f16* __restrict__ in,
                                            f16* __restrict__ out,
                                            const float* __restrict__ w,
                                            const float* __restrict__ b) {
    int row = blockIdx.x;
    int lane = threadIdx.x;
    f16x8 hv = *(const f16x8*)(in + (size_t)row * D_ + lane * 8);
    float x[8];
#pragma unroll
    for (int i = 0; i < 8; ++i) x[i] = (float)hv[i];
    float s = 0.f, ss = 0.f;
#pragma unroll
    for (int i = 0; i < 8; ++i) { s += x[i]; ss = fmaf(x[i], x[i], ss); }
#pragma unroll
    for (int off = 32; off > 0; off >>= 1) {
        s  += __shfl_xor(s, off);
        ss += __shfl_xor(ss, off);
    }
    float mean = s * (1.0f / 512.0f);
    float var  = ss * (1.0f / 512.0f) - mean * mean;
    float rs = rsqrtf(var + 1e-5f);
    const float* wp = w + lane * 8;
    const float* bp = b + lane * 8;
    float4 w0 = *(const float4*)wp, w1 = *(const float4*)(wp + 4);
    float4 b0 = *(const float4*)bp, b1 = *(const float4*)(bp + 4);
    float wv[8] = {w0.x, w0.y, w0.z, w0.w, w1.x, w1.y, w1.z, w1.w};
    float bv[8] = {b0.x, b0.y, b0.z, b0.w, b1.x, b1.y, b1.z, b1.w};
    f16x8 h;
#pragma unroll
    for (int i = 0; i < 8; ++i) h[i] = (f16)((x[i] - mean) * rs * wv[i] + bv[i]);
    *(f16x8*)(out + (size_t)row * D_ + lane * 8) = h;
}

// ---- fused depthwise conv + LayerNorm, t-tiled via LDS, f16 trunk input (r13-proven) ----
__global__ __launch_bounds__(256) void k_dwln2h(const f16* __restrict__ x,
                                                const float* __restrict__ dwT,
                                                const float* __restrict__ db,
                                                const float* __restrict__ nw,
                                                const float* __restrict__ nb,
                                                f16* __restrict__ out) {
    __shared__ float xs[22][512];
    int tid = threadIdx.x;
    int blk = blockIdx.x;            // b*128 + tc
    int b = blk >> 7;
    int t0 = (blk & 127) << 4;
    const f16* xb = x + ((size_t)b << 20);     // b * T_ * D_ (f16)
#pragma unroll
    for (int i = 0; i < 6; ++i) {
        int idx = tid + (i << 8);    // chunk of 8 f16 over 22*64
        if (idx < 22 * 64) {
            int row = idx >> 6;
            int c8 = idx & 63;
            int t = t0 + row - 3;
            float v[8];
            if (t >= 0 && t < T_) {
                f16x8 hv = *(const f16x8*)(xb + ((size_t)t << 9) + (c8 << 3));
#pragma unroll
                for (int u = 0; u < 8; ++u) v[u] = (float)hv[u];
            } else {
#pragma unroll
                for (int u = 0; u < 8; ++u) v[u] = 0.0f;
            }
            *(float4*)&xs[row][c8 << 3] = make_float4(v[0], v[1], v[2], v[3]);
            *(float4*)&xs[row][(c8 << 3) + 4] = make_float4(v[4], v[5], v[6], v[7]);
        }
    }
    __syncthreads();

    int o = tid & 63;          // d-octet
    int slot = tid >> 6;       // wave id = t-group
    int d0 = o << 3;
    float acc[4][8];
    {
        float4 b0 = *(const float4*)(db + d0);
        float4 b1 = *(const float4*)(db + d0 + 4);
#pragma unroll
        for (int u = 0; u < 4; ++u) {
            acc[u][0] = b0.x; acc[u][1] = b0.y; acc[u][2] = b0.z; acc[u][3] = b0.w;
            acc[u][4] = b1.x; acc[u][5] = b1.y; acc[u][6] = b1.z; acc[u][7] = b1.w;
        }
    }
#pragma unroll
    for (int k = 0; k < 7; ++k) {
        float w8[8];
        *(float4*)&w8[0] = *(const float4*)(dwT + (k << 9) + d0);
        *(float4*)&w8[4] = *(const float4*)(dwT + (k << 9) + d0 + 4);
#pragma unroll
        for (int u = 0; u < 4; ++u) {
            int row = (slot << 2) + u + k;   // t_local + k, in [0,21]
            float x8[8];
            *(float4*)&x8[0] = *(const float4*)&xs[row][d0];
            *(float4*)&x8[4] = *(const float4*)&xs[row][d0 + 4];
#pragma unroll
            for (int i = 0; i < 8; ++i) acc[u][i] = fmaf(w8[i], x8[i], acc[u][i]);
        }
    }
    float4 w0 = *(const float4*)(nw + d0), w1 = *(const float4*)(nw + d0 + 4);
    float4 n0 = *(const float4*)(nb + d0), n1 = *(const float4*)(nb + d0 + 4);
    float nwv[8] = {w0.x, w0.y, w0.z, w0.w, w1.x, w1.y, w1.z, w1.w};
    float nbv[8] = {n0.x, n0.y, n0.z, n0.w, n1.x, n1.y, n1.z, n1.w};
#pragma unroll
    for (int u = 0; u < 4; ++u) {
        float s = 0.f, ss = 0.f;
#pragma unroll
        for (int i = 0; i < 8; ++i) { s += acc[u][i]; ss = fmaf(acc[u][i], acc[u][i], ss); }
#pragma unroll
        for (int off = 32; off > 0; off >>= 1) {
            s  += __shfl_xor(s, off);
            ss += __shfl_xor(ss, off);
        }
        float mean = s * (1.0f / 512.0f);
        float var  = ss * (1.0f / 512.0f) - mean * mean;
        float rs = rsqrtf(var + 1e-5f);
        f16x8 h;
#pragma unroll
        for (int i = 0; i < 8; ++i)
            h[i] = (f16)((acc[u][i] - mean) * rs * nwv[i] + nbv[i]);
        int t = t0 + (slot << 2) + u;
        *(f16x8*)(out + (((size_t)(b << 11) + t) << 9) + d0) = h;
    }
}

#define MF(d, a, b) d = __builtin_amdgcn_mfma_f32_16x16x32_f16(a, b, d, 0, 0, 0)

// ---- fp16 MFMA GEMM v5 (r6/r8/r10/r13-proven): 128x128, BK=32, 3-ring, vmcnt(4) ----
// EMBED=true reads A through the im2col VIEW: row bt = &melTp[(b*TP+t)*192], lda=192
// (overlapping rows; identical bytes k_expand used to copy). W-path untouched.
// EPI: 0 = fp32 +bias (head) ; 1 = f16 gelu (pw1) ; 4 = f16 +bias (embed) ;
//      5 = f16 residual RMW (pw2)
#define TSZ_ 4096   // f16 elems per matrix tile (128x32)

__device__ __forceinline__ void stage32(const f16* __restrict__ g, f16* s,
                                        int lda, int kof, int tid) {
    int dr0 = tid >> 3;        // 0..31
    int sl  = tid & 7;
#pragma unroll
    for (int i = 0; i < 2; ++i) {
        int d  = dr0 + (i << 5);           // double-row 0..63
        int gs = sl ^ (d & 7);             // pre-swizzled global slot
        int row = (d << 1) + (gs >> 2);
        int kc  = gs & 3;
        gload16(g + (size_t)row * lda + kof + (kc << 3),
                s + (d << 6) + (sl << 3)); // linear dest: wave base + lane*16B
    }
}

template <int EPI, bool EMBED>
__global__ __launch_bounds__(256, 3) void k_hgemm5(const f16* __restrict__ A,
                                                   const f16* __restrict__ W,
                                                   const float* __restrict__ bias,
                                                   const float* __restrict__ gamma,
                                                   void* __restrict__ C,
                                                   int K, int ldc, int nNt) {
    __shared__ f16 lds[3 * 2 * TSZ_];
    int tid = threadIdx.x;
    int nwg = gridDim.x, bid = blockIdx.x;
    int q = nwg >> 3, r = nwg & 7;
    int xcd = bid & 7, lin = bid >> 3;
    int swz = (xcd < r ? xcd * (q + 1) : r * (q + 1) + (xcd - r) * q) + lin;
    int bm = (swz / nNt) << 7;
    int bn = (swz % nNt) << 7;
    const f16* gA;
    int lda;
    if constexpr (EMBED) {
        gA = A + ((size_t)((bm >> 11) * TP_) + (bm & (T_ - 1))) * CM_;
        lda = CM_;
    } else {
        gA = A + (size_t)bm * K;
        lda = K;
    }
    const f16* gW = W + (size_t)bn * K;

    int l = tid & 63;
    int wv = tid >> 6;
    int wm = (wv & 1) << 6;    // 2 wave-rows of 64
    int wn = (wv >> 1) << 6;   // 2 wave-cols of 64
    int lr = l & 15;
    int lk = l >> 4;
    int lrh = lr >> 1;
    int s0l = ((lr & 1) << 2) | lk;   // logical slot for this lane's (row-half, chunk)

    int offA[4], offB[4];
#pragma unroll
    for (int i = 0; i < 4; ++i) {
        int dA = (wm >> 1) + i * 8 + lrh;
        offA[i] = (dA << 6) + ((s0l ^ (dA & 7)) << 3);
        int dB = (wn >> 1) + i * 8 + lrh;
        offB[i] = (dB << 6) + ((s0l ^ (dB & 7)) << 3);
    }

    f32x4 acc[4][4];
#pragma unroll
    for (int i = 0; i < 4; ++i)
#pragma unroll
        for (int j = 0; j < 4; ++j) acc[i][j] = {0.f, 0.f, 0.f, 0.f};

    int nk = K >> 5;
    f16* s0 = lds;
    f16* s1 = lds + 2 * TSZ_;
    f16* s2 = lds + 4 * TSZ_;

    stage32(gA, s0, lda, 0, tid);      stage32(gW, s0 + TSZ_, K, 0, tid);
    stage32(gA, s1, lda, 32, tid);     stage32(gW, s1 + TSZ_, K, 32, tid);
    asm volatile("s_waitcnt vmcnt(4)" ::: "memory");
    __builtin_amdgcn_s_barrier();

    for (int t = 0; t < nk; ++t) {
        bool stg = (t + 2 < nk);
        if (stg) {
            int ko = (t + 2) << 5;
            stage32(gA, s2, lda, ko, tid);
            stage32(gW, s2 + TSZ_, K, ko, tid);
        }
        f16x8 af[4], bf[4];
#pragma unroll
        for (int i = 0; i < 4; ++i) af[i] = *(const f16x8*)(s0 + offA[i]);
#pragma unroll
        for (int j = 0; j < 4; ++j) bf[j] = *(const f16x8*)(s0 + TSZ_ + offB[j]);
        __builtin_amdgcn_s_setprio(1);
#pragma unroll
        for (int i = 0; i < 4; ++i)
#pragma unroll
            for (int j = 0; j < 4; ++j) MF(acc[i][j], af[i], bf[j]);
        __builtin_amdgcn_s_setprio(0);
        if (stg)               asm volatile("s_waitcnt vmcnt(4)" ::: "memory");
        else if (t + 1 < nk)   asm volatile("s_waitcnt vmcnt(0)" ::: "memory");
        if (t + 1 < nk) {
            __builtin_amdgcn_s_barrier();
            asm volatile("" ::: "memory");
        }
        f16* tmp = s0; s0 = s1; s1 = s2; s2 = tmp;
    }

    int lk4 = lk << 2;
#pragma unroll
    for (int i = 0; i < 4; ++i) {
#pragma unroll
        for (int rr = 0; rr < 4; ++rr) {
            int row = bm + wm + i * 16 + lk4 + rr;
            size_t moff = (size_t)row * ldc;
#pragma unroll
            for (int j = 0; j < 4; ++j) {
                int col = bn + wn + j * 16 + lr;
                float v = acc[i][j][rr];
                if constexpr (EPI == 0) {
                    ((float*)C)[moff + col] = v + bias[col];
                } else if constexpr (EPI == 1) {
                    ((f16*)C)[moff + col] = (f16)gelu_f(v + bias[col]);
                } else if constexpr (EPI == 4) {
                    ((f16*)C)[moff + col] = (f16)(v + bias[col]);
                } else if constexpr (EPI == 5) {
                    f16* Cp = (f16*)C;
                    float old = (float)Cp[moff + col];
                    Cp[moff + col] = (f16)(old + gamma[col] * (v + bias[col]));
                } else {
                    ((f16*)C)[moff + col] = (f16)(v * bias[col]);
                }
            }
        }
    }
}

// ---- fp16 MFMA GEMM v7 (r11/r12/r13-proven): 256x128 block, wave 128x64, vmcnt(6) ----
// Routed ONLY to istft (grid 512 = exactly 2 blocks/CU x 256 CU, zero tail).
#define ASZ_ 8192   // f16 elems per A tile (256x32)
#define RSZ_ 12288  // ring slot (A + B)

__device__ __forceinline__ void stageA256(const f16* __restrict__ g, f16* s,
                                          int K, int kof, int tid) {
    int dr0 = tid >> 3;        // 0..31
    int sl  = tid & 7;
#pragma unroll
    for (int i = 0; i < 4; ++i) {
        int d  = dr0 + (i << 5);           // double-row 0..127
        int gs = sl ^ (d & 7);
        int row = (d << 1) + (gs >> 2);    // 0..255
        int kc  = gs & 3;
        gload16(g + (size_t)row * K + kof + (kc << 3),
                s + (d << 6) + (sl << 3));
    }
}

__device__ __forceinline__ void stageB128(const f16* __restrict__ g, f16* s,
                                          int K, int kof, int tid) {
    int dr0 = tid >> 3;
    int sl  = tid & 7;
#pragma unroll
    for (int i = 0; i < 2; ++i) {
        int d  = dr0 + (i << 5);           // double-row 0..63
        int gs = sl ^ (d & 7);
        int row = (d << 1) + (gs >> 2);    // 0..127
        int kc  = gs & 3;
        gload16(g + (size_t)row * K + kof + (kc << 3),
                s + (d << 6) + (sl << 3));
    }
}

template <int EPI>
__global__ __launch_bounds__(256, 2) void k_hgemm7(const f16* __restrict__ A,
                                                   const f16* __restrict__ W,
                                                   const float* __restrict__ bias,
                                                   const float* __restrict__ gamma,
                                                   void* __restrict__ C,
                                                   int K, int ldc, int nNt) {
    __shared__ f16 lds[3 * RSZ_];
    int tid = threadIdx.x;
    int nwg = gridDim.x, bid = blockIdx.x;
    int q = nwg >> 3, r = nwg & 7;
    int xcd = bid & 7, lin = bid >> 3;
    int swz = (xcd < r ? xcd * (q + 1) : r * (q + 1) + (xcd - r) * q) + lin;
    int bm = (swz / nNt) << 8;      // 256-row M tiles
    int bn = (swz % nNt) << 7;      // 128-col N tiles
    const f16* gA = A + (size_t)bm * K;
    const f16* gW = W + (size_t)bn * K;

    int l = tid & 63;
    int wv = tid >> 6;
    int wm = (wv & 1) << 7;    // 2 wave-rows of 128
    int wn = (wv >> 1) << 6;   // 2 wave-cols of 64
    int lr = l & 15;
    int lk = l >> 4;
    int lrh = lr >> 1;
    int s0l = ((lr & 1) << 2) | lk;

    int offA[8], offB[4];
#pragma unroll
    for (int i = 0; i < 8; ++i) {
        int dA = (wm >> 1) + i * 8 + lrh;           // double-row 0..127
        offA[i] = (dA << 6) + ((s0l ^ (dA & 7)) << 3);
    }
#pragma unroll
    for (int j = 0; j < 4; ++j) {
        int dB = (wn >> 1) + j * 8 + lrh;           // double-row 0..63
        offB[j] = (dB << 6) + ((s0l ^ (dB & 7)) << 3);
    }

    f32x4 acc[8][4];
#pragma unroll
    for (int i = 0; i < 8; ++i)
#pragma unroll
        for (int j = 0; j < 4; ++j) acc[i][j] = {0.f, 0.f, 0.f, 0.f};

    int nk = K >> 5;
    f16* s0 = lds;
    f16* s1 = lds + RSZ_;
    f16* s2 = lds + 2 * RSZ_;

    stageA256(gA, s0, K, 0, tid);      stageB128(gW, s0 + ASZ_, K, 0, tid);
    stageA256(gA, s1, K, 32, tid);     stageB128(gW, s1 + ASZ_, K, 32, tid);
    asm volatile("s_waitcnt vmcnt(6)" ::: "memory");
    __builtin_amdgcn_s_barrier();

    for (int t = 0; t < nk; ++t) {
        bool stg = (t + 2 < nk);
        if (stg) {
            int ko = (t + 2) << 5;
            stageA256(gA, s2, K, ko, tid);
            stageB128(gW, s2 + ASZ_, K, ko, tid);
        }
        f16x8 af[8], bf[4];
#pragma unroll
        for (int i = 0; i < 8; ++i) af[i] = *(const f16x8*)(s0 + offA[i]);
#pragma unroll
        for (int j = 0; j < 4; ++j) bf[j] = *(const f16x8*)(s0 + ASZ_ + offB[j]);
        __builtin_amdgcn_s_setprio(1);
#pragma unroll
        for (int i = 0; i < 8; ++i)
#pragma unroll
            for (int j = 0; j < 4; ++j) MF(acc[i][j], af[i], bf[j]);
        __builtin_amdgcn_s_setprio(0);
        if (stg)               asm volatile("s_waitcnt vmcnt(6)" ::: "memory");
        else if (t + 1 < nk)   asm volatile("s_waitcnt vmcnt(0)" ::: "memory");
        if (t + 1 < nk) {
            __builtin_amdgcn_s_barrier();
            asm volatile("" ::: "memory");
        }
        f16* tmp = s0; s0 = s1; s1 = s2; s2 = tmp;
    }

    int lk4 = lk << 2;
#pragma unroll
    for (int i = 0; i < 8; ++i) {
#pragma unroll
        for (int rr = 0; rr < 4; ++rr) {
            int row = bm + wm + i * 16 + lk4 + rr;
            size_t moff = (size_t)row * ldc;
#pragma unroll
            for (int j = 0; j < 4; ++j) {
                int col = bn + wn + j * 16 + lr;
                float v = acc[i][j][rr];
                if constexpr (EPI == 0) {
                    ((float*)C)[moff + col] = v + bias[col];
                } else {
                    ((f16*)C)[moff + col] = (f16)(v * bias[col]);
                }
            }
        }
    }
}

// ---------------- head fp32 (stride 1152) -> S fp16 (stride 1088, padded) ----------------
__global__ __launch_bounds__(256) void k_srsi(const float* __restrict__ o,
                                              f16* __restrict__ S) {
    int idx = blockIdx.x * 256 + threadIdx.x;
    if (idx >= BT_ * KI_) return;
    int m = idx / KI_;
    int f2 = idx - m * KI_;
    size_t base = (size_t)m * NPAD_;
    float v = 0.0f;
    if (f2 < NF_) {
        float mag = fminf(__expf(o[base + f2]), 100.0f);
        float sn, cs;
        __sincosf(o[base + NF_ + f2], &sn, &cs);
        v = mag * cs;
    } else if (f2 < NO2_) {
        int f = f2 - NF_;
        float mag = fminf(__expf(o[base + f]), 100.0f);
        float sn, cs;
        __sincosf(o[base + NF_ + f], &sn, &cs);
        v = mag * sn;
    }
    S[idx] = (f16)v;
}

// ---------------- overlap-add + win_env + crop (deterministic gather, f16 frames) ------
__global__ __launch_bounds__(256) void k_gather(const f16* __restrict__ frames,
                                                const float* __restrict__ win,
                                                float* __restrict__ out) {
    int idx = blockIdx.x * 256 + threadIdx.x;
    int b  = idx / LOUT_;
    int lp = idx - b * LOUT_;
    int l = lp + (NFFT_ / 2);
    int thi = l >> 8;
    if (thi > T_ - 1) thi = T_ - 1;
    int tlo = l - (NFFT_ - 1) + (HOP_ - 1);
    tlo = (tlo < 0) ? 0 : (tlo >> 8);
    float num = 0.0f, den = 0.0f;
    for (int t = tlo; t <= thi; ++t) {
        int n = l - (t << 8);
        float wv = win[n];
        num += (float)frames[((size_t)(b * T_ + t) << 10) + n];
        den = fmaf(wv, wv, den);
    }
    out[idx] = num / (den + 1e-11f);
}

// ---------------- launch ----------------
extern "C" void kernel_launch(void* const* d_in, const int* in_sizes, int n_in,
                              void* d_out, int out_size, void* d_ws, size_t ws_size,
                              hipStream_t stream) {
    (void)in_sizes; (void)n_in; (void)out_size; (void)ws_size;
    const float* mel     = (const float*)d_in[0];
    const float* embed_w = (const float*)d_in[1];
    const float* embed_b = (const float*)d_in[2];
    const float* norm_w  = (const float*)d_in[3];
    const float* norm_b  = (const float*)d_in[4];
    const float* bdw = (const float*)d_in[5];
    const float* bdb = (const float*)d_in[6];
    const float* bnw = (const float*)d_in[7];
    const float* bnb = (const float*)d_in[8];
    const float* bw1 = (const float*)d_in[9];
    const float* bb1 = (const float*)d_in[10];
    const float* bw2 = (const float*)d_in[11];
    const float* bb2 = (const float*)d_in[12];
    const float* bg  = (const float*)d_in[13];
    const float* fnw = (const float*)d_in[14];
    const float* fnb = (const float*)d_in[15];
    const float* hw  = (const float*)d_in[16];
    const float* hb  = (const float*)d_in[17];
    const float* win = (const float*)d_in[18];

    char* ws = (char*)d_ws;
    // region A: [0, 50.3MB): xbuf_h f16 trunk [0,16.8MB); ybuf_h at +33.5MB;
    // S_h overlays base after final LN consumes xbuf_h (r13-proven liveness).
    f16*   xbuf_h = (f16*)ws;
    f16*   ybuf_h = (f16*)(ws + 33554432);
    f16*   S_h    = (f16*)ws;
    // region R: [50.3MB, 134.2MB): melTp at base (dead after embed GEMM);
    // obuf / frames_h at base later; hbuf_h at +33.5MB.
    char* R = ws + 50331648;
    f16*   melTp  = (f16*)R;                      // 6,309,888 B
    f16*   hbuf_h = (f16*)(R + 33554432);
    float* obuf   = (float*)R;
    f16*   frames_h = (f16*)R;
    // region W: [134.2MB, ...): converted weights (proven envelope)
    char* Wr = ws + 134217728;
    f16*   w1_h   = (f16*)Wr;                     // 12,582,912
    f16*   w2_h   = (f16*)(Wr + 12582912);        // 12,582,912
    f16*   head_h = (f16*)(Wr + 25165824);        // 1,179,648
    f16*   wmat_h = (f16*)(Wr + 26345472);        // 2,228,224
    f16*   we_h   = (f16*)(Wr + 28573696);        // 1,376,256
    float* hb_pad = (float*)(Wr + 29949952);      // 4,608
    float* dwT    = (float*)(Wr + 29954560);      // 114,688

    k_prep<<<58613, 256, 0, stream>>>(bw1, bw2, embed_w, hw, hb, bdw,
                                      w1_h, w2_h, we_h, head_h, hb_pad, dwT, wmat_h);
    k_melT<<<(B_ * TP_ * 24 + 255) / 256, 256, 0, stream>>>(mel, melTp);

    // embed conv: GEMM directly over the melTp im2col view (lda=192, K=1344)
    k_hgemm5<4, true><<<128 * 4, 256, 0, stream>>>(melTp, we_h, embed_b, nullptr, xbuf_h,
                                                   KE_, D_, 4);
    k_lnh<<<BT_, 64, 0, stream>>>(xbuf_h, xbuf_h, norm_w, norm_b);

    for (int bl = 0; bl < 8; ++bl) {
        k_dwln2h<<<B_ * 128, 256, 0, stream>>>(xbuf_h, dwT + bl * 3584, bdb + bl * D_,
                                               bnw + bl * D_, bnb + bl * D_, ybuf_h);
        k_hgemm5<1, false><<<128 * 12, 256, 0, stream>>>(ybuf_h, w1_h + (size_t)bl * H_ * D_,
                                                         bb1 + bl * H_, nullptr, hbuf_h,
                                                         D_, H_, 12);
        k_hgemm5<5, false><<<128 * 4, 256, 0, stream>>>(hbuf_h, w2_h + (size_t)bl * D_ * H_,
                                                        bb2 + bl * D_, bg + bl * D_, xbuf_h,
                                                        H_, D_, 4);
    }

    k_lnh<<<BT_, 64, 0, stream>>>(xbuf_h, ybuf_h, fnw, fnb);
    k_hgemm5<0, false><<<128 * 9, 256, 0, stream>>>(ybuf_h, head_h, hb_pad, nullptr, obuf,
                                                    D_, NPAD_, 9);
    k_srsi<<<(BT_ * KI_ + 255) / 256, 256, 0, stream>>>(obuf, S_h);
    k_hgemm7<3><<<64 * 8, 256, 0, stream>>>(S_h, wmat_h, win, nullptr, frames_h,
                                            KI_, NFFT_, 8);
    k_gather<<<B_ * LOUT_ / 256, 256, 0, stream>>>(frames_h, win, (float*)d_out);
}

// Round 15
// 941.957 us; speedup vs baseline: 1.1590x; 1.0245x over previous
//
#include <hip/hip_runtime.h>
#include <cmath>

#define B_ 8
#define T_ 2048
#define BT_ 16384
#define D_ 512
#define H_ 1536
#define CM_ 192
#define KE_ 1344      // embed K = 192*7 (divisible by 32)
#define TP_ 2054      // padded t-rows per batch in melTp (3 zero pad each side)
#define NFFT_ 1024
#define NF_ 513
#define HOP_ 256
#define NO2_ 1026
#define NPAD_ 1152    // head N padded to tile multiple
#define KI_ 1088      // ISTFT K (= 1026 padded to 32-multiple)
#define LOUT_ 524032

typedef _Float16 f16;
typedef f16 f16x8 __attribute__((ext_vector_type(8)));
typedef float f32x4 __attribute__((ext_vector_type(4)));

// tanh-form GELU: |err| vs exact-erf gelu <= ~3e-4, far under budget
__device__ __forceinline__ float gelu_f(float v) {
    float u = 0.7978845608028654f * v * (1.0f + 0.044715f * v * v);
    float e = __expf(2.0f * u);
    float t = 1.0f - 2.0f * __builtin_amdgcn_rcpf(e + 1.0f);
    return 0.5f * v * (1.0f + t);
}

__device__ __forceinline__ void gload16(const void* g, void* s) {
    __builtin_amdgcn_global_load_lds((const __attribute__((address_space(1))) void*)g,
                                     (__attribute__((address_space(3))) void*)s, 16, 0, 0);
}

// ---------------- fused prep (weights + melT; replaces 8 kernels) ----------------
// ranges: w1(6291456) | w2(6291456) | embed(688128) | head-interleaved(589824)
//         | hb-interleaved(1152) | dwT(28672) | wmat(1114112) | melT(394368 chunks)
// head INTERLEAVE: out-col c holds mag-row c/2 (c even) or phase-row 513+(c>>1)
// (c odd); rows >= 1026 zero. Lets the head GEMM epilogue form (mag,phase) pairs
// from lane-adjacent columns and emit S directly (fused srsi).
__global__ __launch_bounds__(256) void k_prep(const float* __restrict__ bw1,
                                              const float* __restrict__ bw2,
                                              const float* __restrict__ embed_w,
                                              const float* __restrict__ hw,
                                              const float* __restrict__ hb,
                                              const float* __restrict__ bdw,
                                              const float* __restrict__ mel,
                                              f16* __restrict__ w1_h,
                                              f16* __restrict__ w2_h,
                                              f16* __restrict__ we_h,
                                              f16* __restrict__ head_h,
                                              float* __restrict__ hb_pad,
                                              float* __restrict__ dwT,
                                              f16* __restrict__ wmat_h,
                                              f16* __restrict__ melTp) {
    int i = blockIdx.x * 256 + threadIdx.x;
    if (i < 6291456) { w1_h[i] = (f16)bw1[i]; return; }
    i -= 6291456;
    if (i < 6291456) { w2_h[i] = (f16)bw2[i]; return; }
    i -= 6291456;
    if (i < 688128) {   // embed_w (D,Cm,7) -> we_h[d][tap*192 + c]
        int d = i / KE_;
        int r2 = i - d * KE_;
        int tap = r2 / CM_;
        int c = r2 - tap * CM_;
        we_h[i] = (f16)embed_w[(d * CM_ + c) * 7 + tap];
        return;
    }
    i -= 688128;
    if (i < 589824) {   // head interleaved: col c <- hw row (c&1 ? 513+(c>>1) : c>>1)
        int row = i >> 9;
        int k = i & 511;
        f16 v = (f16)0.0f;
        if (row < NO2_) {
            int src = (row & 1) ? (NF_ + (row >> 1)) : (row >> 1);
            v = (f16)hw[(size_t)src * D_ + k];
        }
        head_h[i] = v;
        return;
    }
    i -= 589824;
    if (i < 1152) {
        float v = 0.0f;
        if (i < NO2_) {
            int src = (i & 1) ? (NF_ + (i >> 1)) : (i >> 1);
            v = hb[src];
        }
        hb_pad[i] = v;
        return;
    }
    i -= 1152;
    if (i < 28672) {    // dw (8,512,7) -> dwT[bl][k][d]
        int bl = i / 3584;
        int rem = i - bl * 3584;
        int k = rem >> 9;
        int d = rem & 511;
        dwT[i] = bdw[bl * 3584 + d * 7 + k];
        return;
    }
    i -= 28672;
    if (i < 1114112) {  // ISTFT basis fp16
        int n = i / KI_;
        int f2 = i - n * KI_;
        float v = 0.0f;
        if (f2 < NF_) {
            int r = (n * f2) & (NFFT_ - 1);
            float sc = (f2 == 0 || f2 == NF_ - 1) ? (1.0f / NFFT_) : (2.0f / NFFT_);
            v = cospif((float)r * (2.0f / NFFT_)) * sc;
        } else if (f2 < NO2_) {
            int f = f2 - NF_;
            int r = (n * f) & (NFFT_ - 1);
            float sc = (f == 0 || f == NF_ - 1) ? (1.0f / NFFT_) : (2.0f / NFFT_);
            v = -sinpif((float)r * (2.0f / NFFT_)) * sc;
        }
        wmat_h[i] = (f16)v;
        return;
    }
    i -= 1114112;
    if (i < B_ * TP_ * 24) {   // mel (B,Cm,T) fp32 -> melTp[b][t+3][c] fp16
        int c8 = i % 24;
        int rem = i / 24;
        int tp = rem % TP_;
        int b = rem / TP_;
        int t = tp - 3;
        f16x8 v;
        if (t >= 0 && t < T_) {
            const float* mp = mel + ((size_t)b * CM_ + c8 * 8) * T_ + t;
#pragma unroll
            for (int u = 0; u < 8; ++u) v[u] = (f16)mp[(size_t)u * T_];
        } else {
#pragma unroll
            for (int u = 0; u < 8; ++u) v[u] = (f16)0.0f;
        }
        *(f16x8*)(melTp + (size_t)i * 8) = v;
    }
}

// ---------------- LayerNorm over D=512, f16 in -> f16 out, one wave per row ----------------
__global__ __launch_bounds__(64) void k_lnh(const f16* __restrict__ in,
                                            f16* __restrict__ out,
                                            const float* __restrict__ w,
                                            const float* __restrict__ b) {
    int row = blockIdx.x;
    int lane = threadIdx.x;
    f16x8 hv = *(const f16x8*)(in + (size_t)row * D_ + lane * 8);
    float x[8];
#pragma unroll
    for (int i = 0; i < 8; ++i) x[i] = (float)hv[i];
    float s = 0.f, ss = 0.f;
#pragma unroll
    for (int i = 0; i < 8; ++i) { s += x[i]; ss = fmaf(x[i], x[i], ss); }
#pragma unroll
    for (int off = 32; off > 0; off >>= 1) {
        s  += __shfl_xor(s, off);
        ss += __shfl_xor(ss, off);
    }
    float mean = s * (1.0f / 512.0f);
    float var  = ss * (1.0f / 512.0f) - mean * mean;
    float rs = rsqrtf(var + 1e-5f);
    const float* wp = w + lane * 8;
    const float* bp = b + lane * 8;
    float4 w0 = *(const float4*)wp, w1 = *(const float4*)(wp + 4);
    float4 b0 = *(const float4*)bp, b1 = *(const float4*)(bp + 4);
    float wv[8] = {w0.x, w0.y, w0.z, w0.w, w1.x, w1.y, w1.z, w1.w};
    float bv[8] = {b0.x, b0.y, b0.z, b0.w, b1.x, b1.y, b1.z, b1.w};
    f16x8 h;
#pragma unroll
    for (int i = 0; i < 8; ++i) h[i] = (f16)((x[i] - mean) * rs * wv[i] + bv[i]);
    *(f16x8*)(out + (size_t)row * D_ + lane * 8) = h;
}

// ---- fused depthwise conv + LayerNorm, t-tiled via LDS, f16 trunk input (r13-proven) ----
__global__ __launch_bounds__(256) void k_dwln2h(const f16* __restrict__ x,
                                                const float* __restrict__ dwT,
                                                const float* __restrict__ db,
                                                const float* __restrict__ nw,
                                                const float* __restrict__ nb,
                                                f16* __restrict__ out) {
    __shared__ float xs[22][512];
    int tid = threadIdx.x;
    int blk = blockIdx.x;            // b*128 + tc
    int b = blk >> 7;
    int t0 = (blk & 127) << 4;
    const f16* xb = x + ((size_t)b << 20);     // b * T_ * D_ (f16)
#pragma unroll
    for (int i = 0; i < 6; ++i) {
        int idx = tid + (i << 8);    // chunk of 8 f16 over 22*64
        if (idx < 22 * 64) {
            int row = idx >> 6;
            int c8 = idx & 63;
            int t = t0 + row - 3;
            float v[8];
            if (t >= 0 && t < T_) {
                f16x8 hv = *(const f16x8*)(xb + ((size_t)t << 9) + (c8 << 3));
#pragma unroll
                for (int u = 0; u < 8; ++u) v[u] = (float)hv[u];
            } else {
#pragma unroll
                for (int u = 0; u < 8; ++u) v[u] = 0.0f;
            }
            *(float4*)&xs[row][c8 << 3] = make_float4(v[0], v[1], v[2], v[3]);
            *(float4*)&xs[row][(c8 << 3) + 4] = make_float4(v[4], v[5], v[6], v[7]);
        }
    }
    __syncthreads();

    int o = tid & 63;          // d-octet
    int slot = tid >> 6;       // wave id = t-group
    int d0 = o << 3;
    float acc[4][8];
    {
        float4 b0 = *(const float4*)(db + d0);
        float4 b1 = *(const float4*)(db + d0 + 4);
#pragma unroll
        for (int u = 0; u < 4; ++u) {
            acc[u][0] = b0.x; acc[u][1] = b0.y; acc[u][2] = b0.z; acc[u][3] = b0.w;
            acc[u][4] = b1.x; acc[u][5] = b1.y; acc[u][6] = b1.z; acc[u][7] = b1.w;
        }
    }
#pragma unroll
    for (int k = 0; k < 7; ++k) {
        float w8[8];
        *(float4*)&w8[0] = *(const float4*)(dwT + (k << 9) + d0);
        *(float4*)&w8[4] = *(const float4*)(dwT + (k << 9) + d0 + 4);
#pragma unroll
        for (int u = 0; u < 4; ++u) {
            int row = (slot << 2) + u + k;   // t_local + k, in [0,21]
            float x8[8];
            *(float4*)&x8[0] = *(const float4*)&xs[row][d0];
            *(float4*)&x8[4] = *(const float4*)&xs[row][d0 + 4];
#pragma unroll
            for (int i = 0; i < 8; ++i) acc[u][i] = fmaf(w8[i], x8[i], acc[u][i]);
        }
    }
    float4 w0 = *(const float4*)(nw + d0), w1 = *(const float4*)(nw + d0 + 4);
    float4 n0 = *(const float4*)(nb + d0), n1 = *(const float4*)(nb + d0 + 4);
    float nwv[8] = {w0.x, w0.y, w0.z, w0.w, w1.x, w1.y, w1.z, w1.w};
    float nbv[8] = {n0.x, n0.y, n0.z, n0.w, n1.x, n1.y, n1.z, n1.w};
#pragma unroll
    for (int u = 0; u < 4; ++u) {
        float s = 0.f, ss = 0.f;
#pragma unroll
        for (int i = 0; i < 8; ++i) { s += acc[u][i]; ss = fmaf(acc[u][i], acc[u][i], ss); }
#pragma unroll
        for (int off = 32; off > 0; off >>= 1) {
            s  += __shfl_xor(s, off);
            ss += __shfl_xor(ss, off);
        }
        float mean = s * (1.0f / 512.0f);
        float var  = ss * (1.0f / 512.0f) - mean * mean;
        float rs = rsqrtf(var + 1e-5f);
        f16x8 h;
#pragma unroll
        for (int i = 0; i < 8; ++i)
            h[i] = (f16)((acc[u][i] - mean) * rs * nwv[i] + nbv[i]);
        int t = t0 + (slot << 2) + u;
        *(f16x8*)(out + (((size_t)(b << 11) + t) << 9) + d0) = h;
    }
}

#define MF(d, a, b) d = __builtin_amdgcn_mfma_f32_16x16x32_f16(a, b, d, 0, 0, 0)

// ---- fp16 MFMA GEMM v5 (r6/r8/r10/r13/r14-proven): 128x128, BK=32, 3-ring, vmcnt(4) ----
// EMBED=true reads A through the melTp im2col view (lda=192).
// EPI: 1 = f16 gelu (pw1) ; 4 = f16 +bias (embed) ; 5 = f16 residual RMW (pw2) ;
//      6 = fused head->S: interleaved cols, shfl_xor(1) pairs (log-mag, phase),
//          writes S_real -> S[f], S_imag -> S[513+f] as f16 (srsi eliminated)
#define TSZ_ 4096   // f16 elems per matrix tile (128x32)

__device__ __forceinline__ void stage32(const f16* __restrict__ g, f16* s,
                                        int lda, int kof, int tid) {
    int dr0 = tid >> 3;        // 0..31
    int sl  = tid & 7;
#pragma unroll
    for (int i = 0; i < 2; ++i) {
        int d  = dr0 + (i << 5);           // double-row 0..63
        int gs = sl ^ (d & 7);             // pre-swizzled global slot
        int row = (d << 1) + (gs >> 2);
        int kc  = gs & 3;
        gload16(g + (size_t)row * lda + kof + (kc << 3),
                s + (d << 6) + (sl << 3)); // linear dest: wave base + lane*16B
    }
}

template <int EPI, bool EMBED>
__global__ __launch_bounds__(256, 3) void k_hgemm5(const f16* __restrict__ A,
                                                   const f16* __restrict__ W,
                                                   const float* __restrict__ bias,
                                                   const float* __restrict__ gamma,
                                                   void* __restrict__ C,
                                                   int K, int ldc, int nNt) {
    __shared__ f16 lds[3 * 2 * TSZ_];
    int tid = threadIdx.x;
    int nwg = gridDim.x, bid = blockIdx.x;
    int q = nwg >> 3, r = nwg & 7;
    int xcd = bid & 7, lin = bid >> 3;
    int swz = (xcd < r ? xcd * (q + 1) : r * (q + 1) + (xcd - r) * q) + lin;
    int bm = (swz / nNt) << 7;
    int bn = (swz % nNt) << 7;
    const f16* gA;
    int lda;
    if constexpr (EMBED) {
        gA = A + ((size_t)((bm >> 11) * TP_) + (bm & (T_ - 1))) * CM_;
        lda = CM_;
    } else {
        gA = A + (size_t)bm * K;
        lda = K;
    }
    const f16* gW = W + (size_t)bn * K;

    int l = tid & 63;
    int wv = tid >> 6;
    int wm = (wv & 1) << 6;    // 2 wave-rows of 64
    int wn = (wv >> 1) << 6;   // 2 wave-cols of 64
    int lr = l & 15;
    int lk = l >> 4;
    int lrh = lr >> 1;
    int s0l = ((lr & 1) << 2) | lk;   // logical slot for this lane's (row-half, chunk)

    int offA[4], offB[4];
#pragma unroll
    for (int i = 0; i < 4; ++i) {
        int dA = (wm >> 1) + i * 8 + lrh;
        offA[i] = (dA << 6) + ((s0l ^ (dA & 7)) << 3);
        int dB = (wn >> 1) + i * 8 + lrh;
        offB[i] = (dB << 6) + ((s0l ^ (dB & 7)) << 3);
    }

    f32x4 acc[4][4];
#pragma unroll
    for (int i = 0; i < 4; ++i)
#pragma unroll
        for (int j = 0; j < 4; ++j) acc[i][j] = {0.f, 0.f, 0.f, 0.f};

    int nk = K >> 5;
    f16* s0 = lds;
    f16* s1 = lds + 2 * TSZ_;
    f16* s2 = lds + 4 * TSZ_;

    stage32(gA, s0, lda, 0, tid);      stage32(gW, s0 + TSZ_, K, 0, tid);
    stage32(gA, s1, lda, 32, tid);     stage32(gW, s1 + TSZ_, K, 32, tid);
    asm volatile("s_waitcnt vmcnt(4)" ::: "memory");
    __builtin_amdgcn_s_barrier();

    for (int t = 0; t < nk; ++t) {
        bool stg = (t + 2 < nk);
        if (stg) {
            int ko = (t + 2) << 5;
            stage32(gA, s2, lda, ko, tid);
            stage32(gW, s2 + TSZ_, K, ko, tid);
        }
        f16x8 af[4], bf[4];
#pragma unroll
        for (int i = 0; i < 4; ++i) af[i] = *(const f16x8*)(s0 + offA[i]);
#pragma unroll
        for (int j = 0; j < 4; ++j) bf[j] = *(const f16x8*)(s0 + TSZ_ + offB[j]);
        __builtin_amdgcn_s_setprio(1);
#pragma unroll
        for (int i = 0; i < 4; ++i)
#pragma unroll
            for (int j = 0; j < 4; ++j) MF(acc[i][j], af[i], bf[j]);
        __builtin_amdgcn_s_setprio(0);
        if (stg)               asm volatile("s_waitcnt vmcnt(4)" ::: "memory");
        else if (t + 1 < nk)   asm volatile("s_waitcnt vmcnt(0)" ::: "memory");
        if (t + 1 < nk) {
            __builtin_amdgcn_s_barrier();
            asm volatile("" ::: "memory");
        }
        f16* tmp = s0; s0 = s1; s1 = s2; s2 = tmp;
    }

    int lk4 = lk << 2;
#pragma unroll
    for (int i = 0; i < 4; ++i) {
#pragma unroll
        for (int rr = 0; rr < 4; ++rr) {
            int row = bm + wm + i * 16 + lk4 + rr;
            size_t moff = (size_t)row * ldc;
#pragma unroll
            for (int j = 0; j < 4; ++j) {
                int col = bn + wn + j * 16 + lr;
                float v = acc[i][j][rr];
                if constexpr (EPI == 1) {
                    ((f16*)C)[moff + col] = (f16)gelu_f(v + bias[col]);
                } else if constexpr (EPI == 4) {
                    ((f16*)C)[moff + col] = (f16)(v + bias[col]);
                } else if constexpr (EPI == 5) {
                    f16* Cp = (f16*)C;
                    float old = (float)Cp[moff + col];
                    Cp[moff + col] = (f16)(old + gamma[col] * (v + bias[col]));
                } else if constexpr (EPI == 6) {
                    // fused srsi: col parity = lr parity; partner lane holds col^1
                    float vb = v + bias[col];
                    float w2 = __shfl_xor(vb, 1);
                    float a = (lr & 1) ? w2 : vb;   // log-magnitude
                    float bph = (lr & 1) ? vb : w2; // phase
                    float mag = fminf(__expf(a), 100.0f);
                    float sn, cs;
                    __sincosf(bph, &sn, &cs);
                    float sval = (lr & 1) ? mag * sn : mag * cs;
                    int f = col >> 1;
                    int dst = (lr & 1) ? (NF_ + f) : f;
                    if (col < NO2_)
                        ((f16*)C)[moff + dst] = (f16)sval;
                } else {
                    ((f16*)C)[moff + col] = (f16)(v * bias[col]);
                }
            }
        }
    }
}

// ---- fp16 MFMA GEMM v7 (r11-r14-proven): 256x128 block, wave 128x64, vmcnt(6) ----
// Routed ONLY to istft (grid 512 = exactly 2 blocks/CU x 256 CU, zero tail).
#define ASZ_ 8192   // f16 elems per A tile (256x32)
#define RSZ_ 12288  // ring slot (A + B)

__device__ __forceinline__ void stageA256(const f16* __restrict__ g, f16* s,
                                          int K, int kof, int tid) {
    int dr0 = tid >> 3;        // 0..31
    int sl  = tid & 7;
#pragma unroll
    for (int i = 0; i < 4; ++i) {
        int d  = dr0 + (i << 5);           // double-row 0..127
        int gs = sl ^ (d & 7);
        int row = (d << 1) + (gs >> 2);    // 0..255
        int kc  = gs & 3;
        gload16(g + (size_t)row * K + kof + (kc << 3),
                s + (d << 6) + (sl << 3));
    }
}

__device__ __forceinline__ void stageB128(const f16* __restrict__ g, f16* s,
                                          int K, int kof, int tid) {
    int dr0 = tid >> 3;
    int sl  = tid & 7;
#pragma unroll
    for (int i = 0; i < 2; ++i) {
        int d  = dr0 + (i << 5);           // double-row 0..63
        int gs = sl ^ (d & 7);
        int row = (d << 1) + (gs >> 2);    // 0..127
        int kc  = gs & 3;
        gload16(g + (size_t)row * K + kof + (kc << 3),
                s + (d << 6) + (sl << 3));
    }
}

template <int EPI>
__global__ __launch_bounds__(256, 2) void k_hgemm7(const f16* __restrict__ A,
                                                   const f16* __restrict__ W,
                                                   const float* __restrict__ bias,
                                                   const float* __restrict__ gamma,
                                                   void* __restrict__ C,
                                                   int K, int ldc, int nNt) {
    __shared__ f16 lds[3 * RSZ_];
    int tid = threadIdx.x;
    int nwg = gridDim.x, bid = blockIdx.x;
    int q = nwg >> 3, r = nwg & 7;
    int xcd = bid & 7, lin = bid >> 3;
    int swz = (xcd < r ? xcd * (q + 1) : r * (q + 1) + (xcd - r) * q) + lin;
    int bm = (swz / nNt) << 8;      // 256-row M tiles
    int bn = (swz % nNt) << 7;      // 128-col N tiles
    const f16* gA = A + (size_t)bm * K;
    const f16* gW = W + (size_t)bn * K;

    int l = tid & 63;
    int wv = tid >> 6;
    int wm = (wv & 1) << 7;    // 2 wave-rows of 128
    int wn = (wv >> 1) << 6;   // 2 wave-cols of 64
    int lr = l & 15;
    int lk = l >> 4;
    int lrh = lr >> 1;
    int s0l = ((lr & 1) << 2) | lk;

    int offA[8], offB[4];
#pragma unroll
    for (int i = 0; i < 8; ++i) {
        int dA = (wm >> 1) + i * 8 + lrh;           // double-row 0..127
        offA[i] = (dA << 6) + ((s0l ^ (dA & 7)) << 3);
    }
#pragma unroll
    for (int j = 0; j < 4; ++j) {
        int dB = (wn >> 1) + j * 8 + lrh;           // double-row 0..63
        offB[j] = (dB << 6) + ((s0l ^ (dB & 7)) << 3);
    }

    f32x4 acc[8][4];
#pragma unroll
    for (int i = 0; i < 8; ++i)
#pragma unroll
        for (int j = 0; j < 4; ++j) acc[i][j] = {0.f, 0.f, 0.f, 0.f};

    int nk = K >> 5;
    f16* s0 = lds;
    f16* s1 = lds + RSZ_;
    f16* s2 = lds + 2 * RSZ_;

    stageA256(gA, s0, K, 0, tid);      stageB128(gW, s0 + ASZ_, K, 0, tid);
    stageA256(gA, s1, K, 32, tid);     stageB128(gW, s1 + ASZ_, K, 32, tid);
    asm volatile("s_waitcnt vmcnt(6)" ::: "memory");
    __builtin_amdgcn_s_barrier();

    for (int t = 0; t < nk; ++t) {
        bool stg = (t + 2 < nk);
        if (stg) {
            int ko = (t + 2) << 5;
            stageA256(gA, s2, K, ko, tid);
            stageB128(gW, s2 + ASZ_, K, ko, tid);
        }
        f16x8 af[8], bf[4];
#pragma unroll
        for (int i = 0; i < 8; ++i) af[i] = *(const f16x8*)(s0 + offA[i]);
#pragma unroll
        for (int j = 0; j < 4; ++j) bf[j] = *(const f16x8*)(s0 + ASZ_ + offB[j]);
        __builtin_amdgcn_s_setprio(1);
#pragma unroll
        for (int i = 0; i < 8; ++i)
#pragma unroll
            for (int j = 0; j < 4; ++j) MF(acc[i][j], af[i], bf[j]);
        __builtin_amdgcn_s_setprio(0);
        if (stg)               asm volatile("s_waitcnt vmcnt(6)" ::: "memory");
        else if (t + 1 < nk)   asm volatile("s_waitcnt vmcnt(0)" ::: "memory");
        if (t + 1 < nk) {
            __builtin_amdgcn_s_barrier();
            asm volatile("" ::: "memory");
        }
        f16* tmp = s0; s0 = s1; s1 = s2; s2 = tmp;
    }

    int lk4 = lk << 2;
#pragma unroll
    for (int i = 0; i < 8; ++i) {
#pragma unroll
        for (int rr = 0; rr < 4; ++rr) {
            int row = bm + wm + i * 16 + lk4 + rr;
            size_t moff = (size_t)row * ldc;
#pragma unroll
            for (int j = 0; j < 4; ++j) {
                int col = bn + wn + j * 16 + lr;
                float v = acc[i][j][rr];
                if constexpr (EPI == 0) {
                    ((float*)C)[moff + col] = v + bias[col];
                } else {
                    ((f16*)C)[moff + col] = (f16)(v * bias[col]);
                }
            }
        }
    }
}

// ---------------- overlap-add + win_env + crop (deterministic gather, f16 frames) ------
__global__ __launch_bounds__(256) void k_gather(const f16* __restrict__ frames,
                                                const float* __restrict__ win,
                                                float* __restrict__ out) {
    int idx = blockIdx.x * 256 + threadIdx.x;
    int b  = idx / LOUT_;
    int lp = idx - b * LOUT_;
    int l = lp + (NFFT_ / 2);
    int thi = l >> 8;
    if (thi > T_ - 1) thi = T_ - 1;
    int tlo = l - (NFFT_ - 1) + (HOP_ - 1);
    tlo = (tlo < 0) ? 0 : (tlo >> 8);
    float num = 0.0f, den = 0.0f;
    for (int t = tlo; t <= thi; ++t) {
        int n = l - (t << 8);
        float wv = win[n];
        num += (float)frames[((size_t)(b * T_ + t) << 10) + n];
        den = fmaf(wv, wv, den);
    }
    out[idx] = num / (den + 1e-11f);
}

// ---------------- launch ----------------
extern "C" void kernel_launch(void* const* d_in, const int* in_sizes, int n_in,
                              void* d_out, int out_size, void* d_ws, size_t ws_size,
                              hipStream_t stream) {
    (void)in_sizes; (void)n_in; (void)out_size; (void)ws_size;
    const float* mel     = (const float*)d_in[0];
    const float* embed_w = (const float*)d_in[1];
    const float* embed_b = (const float*)d_in[2];
    const float* norm_w  = (const float*)d_in[3];
    const float* norm_b  = (const float*)d_in[4];
    const float* bdw = (const float*)d_in[5];
    const float* bdb = (const float*)d_in[6];
    const float* bnw = (const float*)d_in[7];
    const float* bnb = (const float*)d_in[8];
    const float* bw1 = (const float*)d_in[9];
    const float* bb1 = (const float*)d_in[10];
    const float* bw2 = (const float*)d_in[11];
    const float* bb2 = (const float*)d_in[12];
    const float* bg  = (const float*)d_in[13];
    const float* fnw = (const float*)d_in[14];
    const float* fnb = (const float*)d_in[15];
    const float* hw  = (const float*)d_in[16];
    const float* hb  = (const float*)d_in[17];
    const float* win = (const float*)d_in[18];

    char* ws = (char*)d_ws;
    // region A: [0, 50.3MB): xbuf_h f16 trunk [0,16.8MB); ybuf_h at +33.5MB;
    // S_h overlays base after final LN consumes xbuf_h (r13/r14-proven liveness).
    f16*   xbuf_h = (f16*)ws;
    f16*   ybuf_h = (f16*)(ws + 33554432);
    f16*   S_h    = (f16*)ws;
    // region R: [50.3MB, 134.2MB): melTp at base (dead after embed GEMM);
    // frames_h at base later; hbuf_h at +33.5MB.
    char* R = ws + 50331648;
    f16*   melTp  = (f16*)R;                      // 6,309,888 B
    f16*   hbuf_h = (f16*)(R + 33554432);
    f16*   frames_h = (f16*)R;
    // region W: [134.2MB, ...): converted weights (proven envelope)
    char* Wr = ws + 134217728;
    f16*   w1_h   = (f16*)Wr;                     // 12,582,912
    f16*   w2_h   = (f16*)(Wr + 12582912);        // 12,582,912
    f16*   head_h = (f16*)(Wr + 25165824);        // 1,179,648
    f16*   wmat_h = (f16*)(Wr + 26345472);        // 2,228,224
    f16*   we_h   = (f16*)(Wr + 28573696);        // 1,376,256
    float* hb_pad = (float*)(Wr + 29949952);      // 4,608
    float* dwT    = (float*)(Wr + 29954560);      // 114,688

    // fused prep: weights + melTp (15,399,168 threads)
    k_prep<<<60153, 256, 0, stream>>>(bw1, bw2, embed_w, hw, hb, bdw, mel,
                                      w1_h, w2_h, we_h, head_h, hb_pad, dwT,
                                      wmat_h, melTp);

    // embed conv: GEMM directly over the melTp im2col view (lda=192, K=1344)
    k_hgemm5<4, true><<<128 * 4, 256, 0, stream>>>(melTp, we_h, embed_b, nullptr, xbuf_h,
                                                   KE_, D_, 4);
    k_lnh<<<BT_, 64, 0, stream>>>(xbuf_h, xbuf_h, norm_w, norm_b);

    for (int bl = 0; bl < 8; ++bl) {
        k_dwln2h<<<B_ * 128, 256, 0, stream>>>(xbuf_h, dwT + bl * 3584, bdb + bl * D_,
                                               bnw + bl * D_, bnb + bl * D_, ybuf_h);
        k_hgemm5<1, false><<<128 * 12, 256, 0, stream>>>(ybuf_h, w1_h + (size_t)bl * H_ * D_,
                                                         bb1 + bl * H_, nullptr, hbuf_h,
                                                         D_, H_, 12);
        k_hgemm5<5, false><<<128 * 4, 256, 0, stream>>>(hbuf_h, w2_h + (size_t)bl * D_ * H_,
                                                        bb2 + bl * D_, bg + bl * D_, xbuf_h,
                                                        H_, D_, 4);
    }

    k_lnh<<<BT_, 64, 0, stream>>>(xbuf_h, ybuf_h, fnw, fnb);
    // head GEMM with fused srsi epilogue: writes S (f16, stride KI_) directly
    k_hgemm5<6, false><<<128 * 9, 256, 0, stream>>>(ybuf_h, head_h, hb_pad, nullptr, S_h,
                                                    D_, KI_, 9);
    k_hgemm7<3><<<64 * 8, 256, 0, stream>>>(S_h, wmat_h, win, nullptr, frames_h,
                                            KI_, NFFT_, 8);
    k_gather<<<B_ * LOUT_ / 256, 256, 0, stream>>>(frames_h, win, (float*)d_out);
}

// Round 16
// 932.871 us; speedup vs baseline: 1.1703x; 1.0097x over previous
//
#include <hip/hip_runtime.h>
#include <cmath>

#define B_ 8
#define T_ 2048
#define BT_ 16384
#define D_ 512
#define H_ 1536
#define CM_ 192
#define KE_ 1344      // embed K = 192*7 (divisible by 32)
#define TP_ 2054      // padded t-rows per batch in melTp (3 zero pad each side)
#define NFFT_ 1024
#define NF_ 513
#define HOP_ 256
#define NO2_ 1026
#define NPAD_ 1152    // head N padded to tile multiple
#define KI_ 1088      // ISTFT K (= 1026 padded to 32-multiple)
#define LOUT_ 524032

typedef _Float16 f16;
typedef f16 f16x8 __attribute__((ext_vector_type(8)));
typedef float f32x4 __attribute__((ext_vector_type(4)));

// tanh-form GELU: |err| vs exact-erf gelu <= ~3e-4, far under budget
__device__ __forceinline__ float gelu_f(float v) {
    float u = 0.7978845608028654f * v * (1.0f + 0.044715f * v * v);
    float e = __expf(2.0f * u);
    float t = 1.0f - 2.0f * __builtin_amdgcn_rcpf(e + 1.0f);
    return 0.5f * v * (1.0f + t);
}

__device__ __forceinline__ void gload16(const void* g, void* s) {
    __builtin_amdgcn_global_load_lds((const __attribute__((address_space(1))) void*)g,
                                     (__attribute__((address_space(3))) void*)s, 16, 0, 0);
}

// ---------------- fused prep, 8 elems/thread (vectorized; math identical to r15) -------
// chunk ranges (x8 elems): w1(786432) | w2(786432) | embed(86016) | head-il(73728)
//  | hb-il(144) | dwT(3584) | wmat(139264) | melT(394368)   total 2,269,968 chunks
__global__ __launch_bounds__(256) void k_prep(const float* __restrict__ bw1,
                                              const float* __restrict__ bw2,
                                              const float* __restrict__ embed_w,
                                              const float* __restrict__ hw,
                                              const float* __restrict__ hb,
                                              const float* __restrict__ bdw,
                                              const float* __restrict__ mel,
                                              f16* __restrict__ w1_h,
                                              f16* __restrict__ w2_h,
                                              f16* __restrict__ we_h,
                                              f16* __restrict__ head_h,
                                              float* __restrict__ hb_pad,
                                              float* __restrict__ dwT,
                                              f16* __restrict__ wmat_h,
                                              f16* __restrict__ melTp) {
    int i = blockIdx.x * 256 + threadIdx.x;
    if (i < 786432) {          // w1 fp32 -> f16, 8-wide
        const float4* s = (const float4*)(bw1 + (size_t)i * 8);
        float4 a = s[0], b = s[1];
        f16x8 h;
        h[0] = (f16)a.x; h[1] = (f16)a.y; h[2] = (f16)a.z; h[3] = (f16)a.w;
        h[4] = (f16)b.x; h[5] = (f16)b.y; h[6] = (f16)b.z; h[7] = (f16)b.w;
        *(f16x8*)(w1_h + (size_t)i * 8) = h;
        return;
    }
    i -= 786432;
    if (i < 786432) {          // w2
        const float4* s = (const float4*)(bw2 + (size_t)i * 8);
        float4 a = s[0], b = s[1];
        f16x8 h;
        h[0] = (f16)a.x; h[1] = (f16)a.y; h[2] = (f16)a.z; h[3] = (f16)a.w;
        h[4] = (f16)b.x; h[5] = (f16)b.y; h[6] = (f16)b.z; h[7] = (f16)b.w;
        *(f16x8*)(w2_h + (size_t)i * 8) = h;
        return;
    }
    i -= 786432;
    if (i < 86016) {           // embed_w (D,Cm,7) -> we_h[d][tap*192 + c], 8 c's
        int o = i * 8;
        int d = o / KE_;
        int r2 = o - d * KE_;
        int tap = r2 / CM_;
        int c = r2 - tap * CM_;
        const float* s = embed_w + (size_t)(d * CM_ + c) * 7 + tap;
        f16x8 h;
#pragma unroll
        for (int u = 0; u < 8; ++u) h[u] = (f16)s[u * 7];
        *(f16x8*)(we_h + o) = h;
        return;
    }
    i -= 86016;
    if (i < 73728) {           // head interleaved rows, 8 contiguous k
        int o = i * 8;
        int row = o >> 9;
        int k = o & 511;
        f16x8 h;
        if (row < NO2_) {
            int src = (row & 1) ? (NF_ + (row >> 1)) : (row >> 1);
            const float4* s = (const float4*)(hw + (size_t)src * D_ + k);
            float4 a = s[0], b = s[1];
            h[0] = (f16)a.x; h[1] = (f16)a.y; h[2] = (f16)a.z; h[3] = (f16)a.w;
            h[4] = (f16)b.x; h[5] = (f16)b.y; h[6] = (f16)b.z; h[7] = (f16)b.w;
        } else {
#pragma unroll
            for (int u = 0; u < 8; ++u) h[u] = (f16)0.0f;
        }
        *(f16x8*)(head_h + o) = h;
        return;
    }
    i -= 73728;
    if (i < 144) {             // hb interleaved (tiny)
        int o = i * 8;
#pragma unroll
        for (int u = 0; u < 8; ++u) {
            int idx = o + u;
            float v = 0.0f;
            if (idx < NO2_) {
                int src = (idx & 1) ? (NF_ + (idx >> 1)) : (idx >> 1);
                v = hb[src];
            }
            hb_pad[idx] = v;
        }
        return;
    }
    i -= 144;
    if (i < 3584) {            // dw (8,512,7) -> dwT[bl][k][d], 8 d's
        int o = i * 8;
        int bl = o / 3584;
        int rem = o - bl * 3584;
        int k = rem >> 9;
        int d = rem & 511;
        const float* s = bdw + (size_t)bl * 3584 + (size_t)d * 7 + k;
        float v[8];
#pragma unroll
        for (int u = 0; u < 8; ++u) v[u] = s[u * 7];
        *(float4*)(dwT + o) = make_float4(v[0], v[1], v[2], v[3]);
        *(float4*)(dwT + o + 4) = make_float4(v[4], v[5], v[6], v[7]);
        return;
    }
    i -= 3584;
    if (i < 139264) {          // ISTFT basis fp16, 8 f2's in one n (1088 % 8 == 0)
        int o = i * 8;
        int n = o / KI_;
        int f2b = o - n * KI_;
        f16x8 h;
#pragma unroll
        for (int u = 0; u < 8; ++u) {
            int f2 = f2b + u;
            float v = 0.0f;
            if (f2 < NF_) {
                int r = (n * f2) & (NFFT_ - 1);
                float sc = (f2 == 0 || f2 == NF_ - 1) ? (1.0f / NFFT_) : (2.0f / NFFT_);
                v = cospif((float)r * (2.0f / NFFT_)) * sc;
            } else if (f2 < NO2_) {
                int f = f2 - NF_;
                int r = (n * f) & (NFFT_ - 1);
                float sc = (f == 0 || f == NF_ - 1) ? (1.0f / NFFT_) : (2.0f / NFFT_);
                v = -sinpif((float)r * (2.0f / NFFT_)) * sc;
            }
            h[u] = (f16)v;
        }
        *(f16x8*)(wmat_h + o) = h;
        return;
    }
    i -= 139264;
    if (i < B_ * TP_ * 24) {   // mel (B,Cm,T) fp32 -> melTp[b][t+3][c] fp16 (as r15)
        int c8 = i % 24;
        int rem = i / 24;
        int tp = rem % TP_;
        int b = rem / TP_;
        int t = tp - 3;
        f16x8 v;
        if (t >= 0 && t < T_) {
            const float* mp = mel + ((size_t)b * CM_ + c8 * 8) * T_ + t;
#pragma unroll
            for (int u = 0; u < 8; ++u) v[u] = (f16)mp[(size_t)u * T_];
        } else {
#pragma unroll
            for (int u = 0; u < 8; ++u) v[u] = (f16)0.0f;
        }
        *(f16x8*)(melTp + (size_t)i * 8) = v;
    }
}

// ---------------- LayerNorm over D=512, f16 in -> f16 out, one wave per row ----------------
__global__ __launch_bounds__(64) void k_lnh(const f16* __restrict__ in,
                                            f16* __restrict__ out,
                                            const float* __restrict__ w,
                                            const float* __restrict__ b) {
    int row = blockIdx.x;
    int lane = threadIdx.x;
    f16x8 hv = *(const f16x8*)(in + (size_t)row * D_ + lane * 8);
    float x[8];
#pragma unroll
    for (int i = 0; i < 8; ++i) x[i] = (float)hv[i];
    float s = 0.f, ss = 0.f;
#pragma unroll
    for (int i = 0; i < 8; ++i) { s += x[i]; ss = fmaf(x[i], x[i], ss); }
#pragma unroll
    for (int off = 32; off > 0; off >>= 1) {
        s  += __shfl_xor(s, off);
        ss += __shfl_xor(ss, off);
    }
    float mean = s * (1.0f / 512.0f);
    float var  = ss * (1.0f / 512.0f) - mean * mean;
    float rs = rsqrtf(var + 1e-5f);
    const float* wp = w + lane * 8;
    const float* bp = b + lane * 8;
    float4 w0 = *(const float4*)wp, w1 = *(const float4*)(wp + 4);
    float4 b0 = *(const float4*)bp, b1 = *(const float4*)(bp + 4);
    float wv[8] = {w0.x, w0.y, w0.z, w0.w, w1.x, w1.y, w1.z, w1.w};
    float bv[8] = {b0.x, b0.y, b0.z, b0.w, b1.x, b1.y, b1.z, b1.w};
    f16x8 h;
#pragma unroll
    for (int i = 0; i < 8; ++i) h[i] = (f16)((x[i] - mean) * rs * wv[i] + bv[i]);
    *(f16x8*)(out + (size_t)row * D_ + lane * 8) = h;
}

// ---- fused depthwise conv + LayerNorm, t-tiled via LDS, f16 trunk input (r13-proven) ----
__global__ __launch_bounds__(256) void k_dwln2h(const f16* __restrict__ x,
                                                const float* __restrict__ dwT,
                                                const float* __restrict__ db,
                                                const float* __restrict__ nw,
                                                const float* __restrict__ nb,
                                                f16* __restrict__ out) {
    __shared__ float xs[22][512];
    int tid = threadIdx.x;
    int blk = blockIdx.x;            // b*128 + tc
    int b = blk >> 7;
    int t0 = (blk & 127) << 4;
    const f16* xb = x + ((size_t)b << 20);     // b * T_ * D_ (f16)
#pragma unroll
    for (int i = 0; i < 6; ++i) {
        int idx = tid + (i << 8);    // chunk of 8 f16 over 22*64
        if (idx < 22 * 64) {
            int row = idx >> 6;
            int c8 = idx & 63;
            int t = t0 + row - 3;
            float v[8];
            if (t >= 0 && t < T_) {
                f16x8 hv = *(const f16x8*)(xb + ((size_t)t << 9) + (c8 << 3));
#pragma unroll
                for (int u = 0; u < 8; ++u) v[u] = (float)hv[u];
            } else {
#pragma unroll
                for (int u = 0; u < 8; ++u) v[u] = 0.0f;
            }
            *(float4*)&xs[row][c8 << 3] = make_float4(v[0], v[1], v[2], v[3]);
            *(float4*)&xs[row][(c8 << 3) + 4] = make_float4(v[4], v[5], v[6], v[7]);
        }
    }
    __syncthreads();

    int o = tid & 63;          // d-octet
    int slot = tid >> 6;       // wave id = t-group
    int d0 = o << 3;
    float acc[4][8];
    {
        float4 b0 = *(const float4*)(db + d0);
        float4 b1 = *(const float4*)(db + d0 + 4);
#pragma unroll
        for (int u = 0; u < 4; ++u) {
            acc[u][0] = b0.x; acc[u][1] = b0.y; acc[u][2] = b0.z; acc[u][3] = b0.w;
            acc[u][4] = b1.x; acc[u][5] = b1.y; acc[u][6] = b1.z; acc[u][7] = b1.w;
        }
    }
#pragma unroll
    for (int k = 0; k < 7; ++k) {
        float w8[8];
        *(float4*)&w8[0] = *(const float4*)(dwT + (k << 9) + d0);
        *(float4*)&w8[4] = *(const float4*)(dwT + (k << 9) + d0 + 4);
#pragma unroll
        for (int u = 0; u < 4; ++u) {
            int row = (slot << 2) + u + k;   // t_local + k, in [0,21]
            float x8[8];
            *(float4*)&x8[0] = *(const float4*)&xs[row][d0];
            *(float4*)&x8[4] = *(const float4*)&xs[row][d0 + 4];
#pragma unroll
            for (int i = 0; i < 8; ++i) acc[u][i] = fmaf(w8[i], x8[i], acc[u][i]);
        }
    }
    float4 w0 = *(const float4*)(nw + d0), w1 = *(const float4*)(nw + d0 + 4);
    float4 n0 = *(const float4*)(nb + d0), n1 = *(const float4*)(nb + d0 + 4);
    float nwv[8] = {w0.x, w0.y, w0.z, w0.w, w1.x, w1.y, w1.z, w1.w};
    float nbv[8] = {n0.x, n0.y, n0.z, n0.w, n1.x, n1.y, n1.z, n1.w};
#pragma unroll
    for (int u = 0; u < 4; ++u) {
        float s = 0.f, ss = 0.f;
#pragma unroll
        for (int i = 0; i < 8; ++i) { s += acc[u][i]; ss = fmaf(acc[u][i], acc[u][i], ss); }
#pragma unroll
        for (int off = 32; off > 0; off >>= 1) {
            s  += __shfl_xor(s, off);
            ss += __shfl_xor(ss, off);
        }
        float mean = s * (1.0f / 512.0f);
        float var  = ss * (1.0f / 512.0f) - mean * mean;
        float rs = rsqrtf(var + 1e-5f);
        f16x8 h;
#pragma unroll
        for (int i = 0; i < 8; ++i)
            h[i] = (f16)((acc[u][i] - mean) * rs * nwv[i] + nbv[i]);
        int t = t0 + (slot << 2) + u;
        *(f16x8*)(out + (((size_t)(b << 11) + t) << 9) + d0) = h;
    }
}

#define MF(d, a, b) d = __builtin_amdgcn_mfma_f32_16x16x32_f16(a, b, d, 0, 0, 0)

// ---- fp16 MFMA GEMM v5 (r6/r8/r10/r13/r14/r15-proven): 128x128, BK=32, 3-ring ----
// EMBED=true reads A through the melTp im2col view (lda=192).
// EPI: 1 = f16 gelu (pw1) ; 4 = f16 +bias (embed) ; 5 = f16 residual RMW (pw2) ;
//      6 = fused head->S (interleaved cols, shfl_xor(1), writes S f16 directly)
#define TSZ_ 4096   // f16 elems per matrix tile (128x32)

__device__ __forceinline__ void stage32(const f16* __restrict__ g, f16* s,
                                        int lda, int kof, int tid) {
    int dr0 = tid >> 3;        // 0..31
    int sl  = tid & 7;
#pragma unroll
    for (int i = 0; i < 2; ++i) {
        int d  = dr0 + (i << 5);           // double-row 0..63
        int gs = sl ^ (d & 7);             // pre-swizzled global slot
        int row = (d << 1) + (gs >> 2);
        int kc  = gs & 3;
        gload16(g + (size_t)row * lda + kof + (kc << 3),
                s + (d << 6) + (sl << 3)); // linear dest: wave base + lane*16B
    }
}

template <int EPI, bool EMBED>
__global__ __launch_bounds__(256, 3) void k_hgemm5(const f16* __restrict__ A,
                                                   const f16* __restrict__ W,
                                                   const float* __restrict__ bias,
                                                   const float* __restrict__ gamma,
                                                   void* __restrict__ C,
                                                   int K, int ldc, int nNt) {
    __shared__ f16 lds[3 * 2 * TSZ_];
    int tid = threadIdx.x;
    int nwg = gridDim.x, bid = blockIdx.x;
    int q = nwg >> 3, r = nwg & 7;
    int xcd = bid & 7, lin = bid >> 3;
    int swz = (xcd < r ? xcd * (q + 1) : r * (q + 1) + (xcd - r) * q) + lin;
    int bm = (swz / nNt) << 7;
    int bn = (swz % nNt) << 7;
    const f16* gA;
    int lda;
    if constexpr (EMBED) {
        gA = A + ((size_t)((bm >> 11) * TP_) + (bm & (T_ - 1))) * CM_;
        lda = CM_;
    } else {
        gA = A + (size_t)bm * K;
        lda = K;
    }
    const f16* gW = W + (size_t)bn * K;

    int l = tid & 63;
    int wv = tid >> 6;
    int wm = (wv & 1) << 6;    // 2 wave-rows of 64
    int wn = (wv >> 1) << 6;   // 2 wave-cols of 64
    int lr = l & 15;
    int lk = l >> 4;
    int lrh = lr >> 1;
    int s0l = ((lr & 1) << 2) | lk;   // logical slot for this lane's (row-half, chunk)

    int offA[4], offB[4];
#pragma unroll
    for (int i = 0; i < 4; ++i) {
        int dA = (wm >> 1) + i * 8 + lrh;
        offA[i] = (dA << 6) + ((s0l ^ (dA & 7)) << 3);
        int dB = (wn >> 1) + i * 8 + lrh;
        offB[i] = (dB << 6) + ((s0l ^ (dB & 7)) << 3);
    }

    f32x4 acc[4][4];
#pragma unroll
    for (int i = 0; i < 4; ++i)
#pragma unroll
        for (int j = 0; j < 4; ++j) acc[i][j] = {0.f, 0.f, 0.f, 0.f};

    int nk = K >> 5;
    f16* s0 = lds;
    f16* s1 = lds + 2 * TSZ_;
    f16* s2 = lds + 4 * TSZ_;

    stage32(gA, s0, lda, 0, tid);      stage32(gW, s0 + TSZ_, K, 0, tid);
    stage32(gA, s1, lda, 32, tid);     stage32(gW, s1 + TSZ_, K, 32, tid);
    asm volatile("s_waitcnt vmcnt(4)" ::: "memory");
    __builtin_amdgcn_s_barrier();

    for (int t = 0; t < nk; ++t) {
        bool stg = (t + 2 < nk);
        if (stg) {
            int ko = (t + 2) << 5;
            stage32(gA, s2, lda, ko, tid);
            stage32(gW, s2 + TSZ_, K, ko, tid);
        }
        f16x8 af[4], bf[4];
#pragma unroll
        for (int i = 0; i < 4; ++i) af[i] = *(const f16x8*)(s0 + offA[i]);
#pragma unroll
        for (int j = 0; j < 4; ++j) bf[j] = *(const f16x8*)(s0 + TSZ_ + offB[j]);
        __builtin_amdgcn_s_setprio(1);
#pragma unroll
        for (int i = 0; i < 4; ++i)
#pragma unroll
            for (int j = 0; j < 4; ++j) MF(acc[i][j], af[i], bf[j]);
        __builtin_amdgcn_s_setprio(0);
        if (stg)               asm volatile("s_waitcnt vmcnt(4)" ::: "memory");
        else if (t + 1 < nk)   asm volatile("s_waitcnt vmcnt(0)" ::: "memory");
        if (t + 1 < nk) {
            __builtin_amdgcn_s_barrier();
            asm volatile("" ::: "memory");
        }
        f16* tmp = s0; s0 = s1; s1 = s2; s2 = tmp;
    }

    int lk4 = lk << 2;
#pragma unroll
    for (int i = 0; i < 4; ++i) {
#pragma unroll
        for (int rr = 0; rr < 4; ++rr) {
            int row = bm + wm + i * 16 + lk4 + rr;
            size_t moff = (size_t)row * ldc;
#pragma unroll
            for (int j = 0; j < 4; ++j) {
                int col = bn + wn + j * 16 + lr;
                float v = acc[i][j][rr];
                if constexpr (EPI == 1) {
                    ((f16*)C)[moff + col] = (f16)gelu_f(v + bias[col]);
                } else if constexpr (EPI == 4) {
                    ((f16*)C)[moff + col] = (f16)(v + bias[col]);
                } else if constexpr (EPI == 5) {
                    f16* Cp = (f16*)C;
                    float old = (float)Cp[moff + col];
                    Cp[moff + col] = (f16)(old + gamma[col] * (v + bias[col]));
                } else if constexpr (EPI == 6) {
                    // fused srsi: col parity = lr parity; partner lane holds col^1
                    float vb = v + bias[col];
                    float w2 = __shfl_xor(vb, 1);
                    float a = (lr & 1) ? w2 : vb;   // log-magnitude
                    float bph = (lr & 1) ? vb : w2; // phase
                    float mag = fminf(__expf(a), 100.0f);
                    float sn, cs;
                    __sincosf(bph, &sn, &cs);
                    float sval = (lr & 1) ? mag * sn : mag * cs;
                    int f = col >> 1;
                    int dst = (lr & 1) ? (NF_ + f) : f;
                    if (col < NO2_)
                        ((f16*)C)[moff + dst] = (f16)sval;
                } else {
                    ((f16*)C)[moff + col] = (f16)(v * bias[col]);
                }
            }
        }
    }
}

// ---- fp16 MFMA GEMM v7 (r11-r15-proven): 256x128 block, wave 128x64, vmcnt(6) ----
// Routed ONLY to istft (grid 512 = exactly 2 blocks/CU x 256 CU, zero tail).
#define ASZ_ 8192   // f16 elems per A tile (256x32)
#define RSZ_ 12288  // ring slot (A + B)

__device__ __forceinline__ void stageA256(const f16* __restrict__ g, f16* s,
                                          int K, int kof, int tid) {
    int dr0 = tid >> 3;        // 0..31
    int sl  = tid & 7;
#pragma unroll
    for (int i = 0; i < 4; ++i) {
        int d  = dr0 + (i << 5);           // double-row 0..127
        int gs = sl ^ (d & 7);
        int row = (d << 1) + (gs >> 2);    // 0..255
        int kc  = gs & 3;
        gload16(g + (size_t)row * K + kof + (kc << 3),
                s + (d << 6) + (sl << 3));
    }
}

__device__ __forceinline__ void stageB128(const f16* __restrict__ g, f16* s,
                                          int K, int kof, int tid) {
    int dr0 = tid >> 3;
    int sl  = tid & 7;
#pragma unroll
    for (int i = 0; i < 2; ++i) {
        int d  = dr0 + (i << 5);           // double-row 0..63
        int gs = sl ^ (d & 7);
        int row = (d << 1) + (gs >> 2);    // 0..127
        int kc  = gs & 3;
        gload16(g + (size_t)row * K + kof + (kc << 3),
                s + (d << 6) + (sl << 3));
    }
}

template <int EPI>
__global__ __launch_bounds__(256, 2) void k_hgemm7(const f16* __restrict__ A,
                                                   const f16* __restrict__ W,
                                                   const float* __restrict__ bias,
                                                   const float* __restrict__ gamma,
                                                   void* __restrict__ C,
                                                   int K, int ldc, int nNt) {
    __shared__ f16 lds[3 * RSZ_];
    int tid = threadIdx.x;
    int nwg = gridDim.x, bid = blockIdx.x;
    int q = nwg >> 3, r = nwg & 7;
    int xcd = bid & 7, lin = bid >> 3;
    int swz = (xcd < r ? xcd * (q + 1) : r * (q + 1) + (xcd - r) * q) + lin;
    int bm = (swz / nNt) << 8;      // 256-row M tiles
    int bn = (swz % nNt) << 7;      // 128-col N tiles
    const f16* gA = A + (size_t)bm * K;
    const f16* gW = W + (size_t)bn * K;

    int l = tid & 63;
    int wv = tid >> 6;
    int wm = (wv & 1) << 7;    // 2 wave-rows of 128
    int wn = (wv >> 1) << 6;   // 2 wave-cols of 64
    int lr = l & 15;
    int lk = l >> 4;
    int lrh = lr >> 1;
    int s0l = ((lr & 1) << 2) | lk;

    int offA[8], offB[4];
#pragma unroll
    for (int i = 0; i < 8; ++i) {
        int dA = (wm >> 1) + i * 8 + lrh;           // double-row 0..127
        offA[i] = (dA << 6) + ((s0l ^ (dA & 7)) << 3);
    }
#pragma unroll
    for (int j = 0; j < 4; ++j) {
        int dB = (wn >> 1) + j * 8 + lrh;           // double-row 0..63
        offB[j] = (dB << 6) + ((s0l ^ (dB & 7)) << 3);
    }

    f32x4 acc[8][4];
#pragma unroll
    for (int i = 0; i < 8; ++i)
#pragma unroll
        for (int j = 0; j < 4; ++j) acc[i][j] = {0.f, 0.f, 0.f, 0.f};

    int nk = K >> 5;
    f16* s0 = lds;
    f16* s1 = lds + RSZ_;
    f16* s2 = lds + 2 * RSZ_;

    stageA256(gA, s0, K, 0, tid);      stageB128(gW, s0 + ASZ_, K, 0, tid);
    stageA256(gA, s1, K, 32, tid);     stageB128(gW, s1 + ASZ_, K, 32, tid);
    asm volatile("s_waitcnt vmcnt(6)" ::: "memory");
    __builtin_amdgcn_s_barrier();

    for (int t = 0; t < nk; ++t) {
        bool stg = (t + 2 < nk);
        if (stg) {
            int ko = (t + 2) << 5;
            stageA256(gA, s2, K, ko, tid);
            stageB128(gW, s2 + ASZ_, K, ko, tid);
        }
        f16x8 af[8], bf[4];
#pragma unroll
        for (int i = 0; i < 8; ++i) af[i] = *(const f16x8*)(s0 + offA[i]);
#pragma unroll
        for (int j = 0; j < 4; ++j) bf[j] = *(const f16x8*)(s0 + ASZ_ + offB[j]);
        __builtin_amdgcn_s_setprio(1);
#pragma unroll
        for (int i = 0; i < 8; ++i)
#pragma unroll
            for (int j = 0; j < 4; ++j) MF(acc[i][j], af[i], bf[j]);
        __builtin_amdgcn_s_setprio(0);
        if (stg)               asm volatile("s_waitcnt vmcnt(6)" ::: "memory");
        else if (t + 1 < nk)   asm volatile("s_waitcnt vmcnt(0)" ::: "memory");
        if (t + 1 < nk) {
            __builtin_amdgcn_s_barrier();
            asm volatile("" ::: "memory");
        }
        f16* tmp = s0; s0 = s1; s1 = s2; s2 = tmp;
    }

    int lk4 = lk << 2;
#pragma unroll
    for (int i = 0; i < 8; ++i) {
#pragma unroll
        for (int rr = 0; rr < 4; ++rr) {
            int row = bm + wm + i * 16 + lk4 + rr;
            size_t moff = (size_t)row * ldc;
#pragma unroll
            for (int j = 0; j < 4; ++j) {
                int col = bn + wn + j * 16 + lr;
                float v = acc[i][j][rr];
                if constexpr (EPI == 0) {
                    ((float*)C)[moff + col] = v + bias[col];
                } else {
                    ((f16*)C)[moff + col] = (f16)(v * bias[col]);
                }
            }
        }
    }
}

// ---------------- overlap-add + win_env + crop (deterministic gather, f16 frames) ------
__global__ __launch_bounds__(256) void k_gather(const f16* __restrict__ frames,
                                                const float* __restrict__ win,
                                                float* __restrict__ out) {
    int idx = blockIdx.x * 256 + threadIdx.x;
    int b  = idx / LOUT_;
    int lp = idx - b * LOUT_;
    int l = lp + (NFFT_ / 2);
    int thi = l >> 8;
    if (thi > T_ - 1) thi = T_ - 1;
    int tlo = l - (NFFT_ - 1) + (HOP_ - 1);
    tlo = (tlo < 0) ? 0 : (tlo >> 8);
    float num = 0.0f, den = 0.0f;
    for (int t = tlo; t <= thi; ++t) {
        int n = l - (t << 8);
        float wv = win[n];
        num += (float)frames[((size_t)(b * T_ + t) << 10) + n];
        den = fmaf(wv, wv, den);
    }
    out[idx] = num / (den + 1e-11f);
}

// ---------------- launch ----------------
extern "C" void kernel_launch(void* const* d_in, const int* in_sizes, int n_in,
                              void* d_out, int out_size, void* d_ws, size_t ws_size,
                              hipStream_t stream) {
    (void)in_sizes; (void)n_in; (void)out_size; (void)ws_size;
    const float* mel     = (const float*)d_in[0];
    const float* embed_w = (const float*)d_in[1];
    const float* embed_b = (const float*)d_in[2];
    const float* norm_w  = (const float*)d_in[3];
    const float* norm_b  = (const float*)d_in[4];
    const float* bdw = (const float*)d_in[5];
    const float* bdb = (const float*)d_in[6];
    const float* bnw = (const float*)d_in[7];
    const float* bnb = (const float*)d_in[8];
    const float* bw1 = (const float*)d_in[9];
    const float* bb1 = (const float*)d_in[10];
    const float* bw2 = (const float*)d_in[11];
    const float* bb2 = (const float*)d_in[12];
    const float* bg  = (const float*)d_in[13];
    const float* fnw = (const float*)d_in[14];
    const float* fnb = (const float*)d_in[15];
    const float* hw  = (const float*)d_in[16];
    const float* hb  = (const float*)d_in[17];
    const float* win = (const float*)d_in[18];

    char* ws = (char*)d_ws;
    // region A: [0, 50.3MB): xbuf_h f16 trunk [0,16.8MB); ybuf_h at +33.5MB;
    // S_h overlays base after final LN consumes xbuf_h (r13-r15-proven liveness).
    f16*   xbuf_h = (f16*)ws;
    f16*   ybuf_h = (f16*)(ws + 33554432);
    f16*   S_h    = (f16*)ws;
    // region R: [50.3MB, 134.2MB): melTp at base (dead after embed GEMM);
    // frames_h at base later; hbuf_h at +33.5MB.
    char* R = ws + 50331648;
    f16*   melTp  = (f16*)R;                      // 6,309,888 B
    f16*   hbuf_h = (f16*)(R + 33554432);
    f16*   frames_h = (f16*)R;
    // region W: [134.2MB, ...): converted weights (proven envelope)
    char* Wr = ws + 134217728;
    f16*   w1_h   = (f16*)Wr;                     // 12,582,912
    f16*   w2_h   = (f16*)(Wr + 12582912);        // 12,582,912
    f16*   head_h = (f16*)(Wr + 25165824);        // 1,179,648
    f16*   wmat_h = (f16*)(Wr + 26345472);        // 2,228,224
    f16*   we_h   = (f16*)(Wr + 28573696);        // 1,376,256
    float* hb_pad = (float*)(Wr + 29949952);      // 4,608
    float* dwT    = (float*)(Wr + 29954560);      // 114,688

    // fused prep, 8 elems/thread: 2,269,968 chunks -> 8868 blocks
    k_prep<<<8868, 256, 0, stream>>>(bw1, bw2, embed_w, hw, hb, bdw, mel,
                                     w1_h, w2_h, we_h, head_h, hb_pad, dwT,
                                     wmat_h, melTp);

    // embed conv: GEMM directly over the melTp im2col view (lda=192, K=1344)
    k_hgemm5<4, true><<<128 * 4, 256, 0, stream>>>(melTp, we_h, embed_b, nullptr, xbuf_h,
                                                   KE_, D_, 4);
    k_lnh<<<BT_, 64, 0, stream>>>(xbuf_h, xbuf_h, norm_w, norm_b);

    for (int bl = 0; bl < 8; ++bl) {
        k_dwln2h<<<B_ * 128, 256, 0, stream>>>(xbuf_h, dwT + bl * 3584, bdb + bl * D_,
                                               bnw + bl * D_, bnb + bl * D_, ybuf_h);
        k_hgemm5<1, false><<<128 * 12, 256, 0, stream>>>(ybuf_h, w1_h + (size_t)bl * H_ * D_,
                                                         bb1 + bl * H_, nullptr, hbuf_h,
                                                         D_, H_, 12);
        k_hgemm5<5, false><<<128 * 4, 256, 0, stream>>>(hbuf_h, w2_h + (size_t)bl * D_ * H_,
                                                        bb2 + bl * D_, bg + bl * D_, xbuf_h,
                                                        H_, D_, 4);
    }

    k_lnh<<<BT_, 64, 0, stream>>>(xbuf_h, ybuf_h, fnw, fnb);
    // head GEMM with fused srsi epilogue: writes S (f16, stride KI_) directly
    k_hgemm5<6, false><<<128 * 9, 256, 0, stream>>>(ybuf_h, head_h, hb_pad, nullptr, S_h,
                                                    D_, KI_, 9);
    k_hgemm7<3><<<64 * 8, 256, 0, stream>>>(S_h, wmat_h, win, nullptr, frames_h,
                                            KI_, NFFT_, 8);
    k_gather<<<B_ * LOUT_ / 256, 256, 0, stream>>>(frames_h, win, (float*)d_out);
}

// Round 17
// 924.943 us; speedup vs baseline: 1.1803x; 1.0086x over previous
//
#include <hip/hip_runtime.h>
#include <cmath>

#define B_ 8
#define T_ 2048
#define BT_ 16384
#define D_ 512
#define H_ 1536
#define CM_ 192
#define KE_ 1344      // embed K = 192*7 (divisible by 32)
#define TP_ 2054      // padded t-rows per batch in melTp (3 zero pad each side)
#define NFFT_ 1024
#define NF_ 513
#define HOP_ 256
#define NO2_ 1026
#define NPAD_ 1152    // head N padded to tile multiple
#define KI_ 1088      // ISTFT K (= 1026 padded to 32-multiple)
#define LOUT_ 524032

typedef _Float16 f16;
typedef f16 f16x8 __attribute__((ext_vector_type(8)));
typedef float f32x4 __attribute__((ext_vector_type(4)));

// tanh-form GELU: |err| vs exact-erf gelu <= ~3e-4, far under budget
__device__ __forceinline__ float gelu_f(float v) {
    float u = 0.7978845608028654f * v * (1.0f + 0.044715f * v * v);
    float e = __expf(2.0f * u);
    float t = 1.0f - 2.0f * __builtin_amdgcn_rcpf(e + 1.0f);
    return 0.5f * v * (1.0f + t);
}

__device__ __forceinline__ void gload16(const void* g, void* s) {
    __builtin_amdgcn_global_load_lds((const __attribute__((address_space(1))) void*)g,
                                     (__attribute__((address_space(3))) void*)s, 16, 0, 0);
}

// ---------------- fused prep (r16-vectorized + coalesced transpose ranges) -------------
// chunk ranges: w1(786432 x8) | w2(786432 x8) | embed(98304 pairs x7) | head-il(73728 x8)
//  | hb-il(144 x8) | dwT(3584 x8) | wmat(139264 x8) | melT(394368 x8, tp-fastest)
//  total 2,282,256 chunks
__global__ __launch_bounds__(256) void k_prep(const float* __restrict__ bw1,
                                              const float* __restrict__ bw2,
                                              const float* __restrict__ embed_w,
                                              const float* __restrict__ hw,
                                              const float* __restrict__ hb,
                                              const float* __restrict__ bdw,
                                              const float* __restrict__ mel,
                                              f16* __restrict__ w1_h,
                                              f16* __restrict__ w2_h,
                                              f16* __restrict__ we_h,
                                              f16* __restrict__ head_h,
                                              float* __restrict__ hb_pad,
                                              float* __restrict__ dwT,
                                              f16* __restrict__ wmat_h,
                                              f16* __restrict__ melTp) {
    int i = blockIdx.x * 256 + threadIdx.x;
    if (i < 786432) {          // w1 fp32 -> f16, 8-wide
        const float4* s = (const float4*)(bw1 + (size_t)i * 8);
        float4 a = s[0], b = s[1];
        f16x8 h;
        h[0] = (f16)a.x; h[1] = (f16)a.y; h[2] = (f16)a.z; h[3] = (f16)a.w;
        h[4] = (f16)b.x; h[5] = (f16)b.y; h[6] = (f16)b.z; h[7] = (f16)b.w;
        *(f16x8*)(w1_h + (size_t)i * 8) = h;
        return;
    }
    i -= 786432;
    if (i < 786432) {          // w2
        const float4* s = (const float4*)(bw2 + (size_t)i * 8);
        float4 a = s[0], b = s[1];
        f16x8 h;
        h[0] = (f16)a.x; h[1] = (f16)a.y; h[2] = (f16)a.z; h[3] = (f16)a.w;
        h[4] = (f16)b.x; h[5] = (f16)b.y; h[6] = (f16)b.z; h[7] = (f16)b.w;
        *(f16x8*)(w2_h + (size_t)i * 8) = h;
        return;
    }
    i -= 786432;
    if (i < 98304) {           // embed_w: one (d,c) pair -> 7 taps
        int d = i >> 9;        // i / 192 ... careful: i over d*192+c with 512*192=98304
        int c = i & 511;       // WRONG mask if c range is 192 -- use div/mod below
        d = i / CM_;
        c = i - d * CM_;
        const float* s = embed_w + (size_t)i * 7;   // (d*192+c)*7, contiguous 7 floats
        f16* dst = we_h + (size_t)d * KE_ + c;
#pragma unroll
        for (int tap = 0; tap < 7; ++tap) dst[tap * CM_] = (f16)s[tap];
        return;
    }
    i -= 98304;
    if (i < 73728) {           // head interleaved rows, 8 contiguous k
        int o = i * 8;
        int row = o >> 9;
        int k = o & 511;
        f16x8 h;
        if (row < NO2_) {
            int src = (row & 1) ? (NF_ + (row >> 1)) : (row >> 1);
            const float4* s = (const float4*)(hw + (size_t)src * D_ + k);
            float4 a = s[0], b = s[1];
            h[0] = (f16)a.x; h[1] = (f16)a.y; h[2] = (f16)a.z; h[3] = (f16)a.w;
            h[4] = (f16)b.x; h[5] = (f16)b.y; h[6] = (f16)b.z; h[7] = (f16)b.w;
        } else {
#pragma unroll
            for (int u = 0; u < 8; ++u) h[u] = (f16)0.0f;
        }
        *(f16x8*)(head_h + o) = h;
        return;
    }
    i -= 73728;
    if (i < 144) {             // hb interleaved (tiny)
        int o = i * 8;
#pragma unroll
        for (int u = 0; u < 8; ++u) {
            int idx = o + u;
            float v = 0.0f;
            if (idx < NO2_) {
                int src = (idx & 1) ? (NF_ + (idx >> 1)) : (idx >> 1);
                v = hb[src];
            }
            hb_pad[idx] = v;
        }
        return;
    }
    i -= 144;
    if (i < 3584) {            // dw (8,512,7) -> dwT[bl][k][d], 8 d's
        int o = i * 8;
        int bl = o / 3584;
        int rem = o - bl * 3584;
        int k = rem >> 9;
        int d = rem & 511;
        const float* s = bdw + (size_t)bl * 3584 + (size_t)d * 7 + k;
        float v[8];
#pragma unroll
        for (int u = 0; u < 8; ++u) v[u] = s[u * 7];
        *(float4*)(dwT + o) = make_float4(v[0], v[1], v[2], v[3]);
        *(float4*)(dwT + o + 4) = make_float4(v[4], v[5], v[6], v[7]);
        return;
    }
    i -= 3584;
    if (i < 139264) {          // ISTFT basis fp16, 8 f2's in one n (1088 % 8 == 0)
        int o = i * 8;
        int n = o / KI_;
        int f2b = o - n * KI_;
        f16x8 h;
#pragma unroll
        for (int u = 0; u < 8; ++u) {
            int f2 = f2b + u;
            float v = 0.0f;
            if (f2 < NF_) {
                int r = (n * f2) & (NFFT_ - 1);
                float sc = (f2 == 0 || f2 == NF_ - 1) ? (1.0f / NFFT_) : (2.0f / NFFT_);
                v = cospif((float)r * (2.0f / NFFT_)) * sc;
            } else if (f2 < NO2_) {
                int f = f2 - NF_;
                int r = (n * f) & (NFFT_ - 1);
                float sc = (f == 0 || f == NF_ - 1) ? (1.0f / NFFT_) : (2.0f / NFFT_);
                v = -sinpif((float)r * (2.0f / NFFT_)) * sc;
            }
            h[u] = (f16)v;
        }
        *(f16x8*)(wmat_h + o) = h;
        return;
    }
    i -= 139264;
    if (i < B_ * TP_ * 24) {   // melT, tp-FASTEST: coalesced per-channel reads
        int c8 = i / (B_ * TP_);          // 0..23
        int rem = i - c8 * (B_ * TP_);
        int b = rem / TP_;
        int tp = rem - b * TP_;
        int t = tp - 3;
        f16x8 v;
        if (t >= 0 && t < T_) {
            const float* mp = mel + ((size_t)b * CM_ + c8 * 8) * T_ + t;
#pragma unroll
            for (int u = 0; u < 8; ++u) v[u] = (f16)mp[(size_t)u * T_];
        } else {
#pragma unroll
            for (int u = 0; u < 8; ++u) v[u] = (f16)0.0f;
        }
        *(f16x8*)(melTp + ((size_t)(b * TP_ + tp) * CM_) + c8 * 8) = v;
    }
}

// ---------------- LayerNorm over D=512, f16 in -> f16 out, one wave per row ----------------
__global__ __launch_bounds__(64) void k_lnh(const f16* __restrict__ in,
                                            f16* __restrict__ out,
                                            const float* __restrict__ w,
                                            const float* __restrict__ b) {
    int row = blockIdx.x;
    int lane = threadIdx.x;
    f16x8 hv = *(const f16x8*)(in + (size_t)row * D_ + lane * 8);
    float x[8];
#pragma unroll
    for (int i = 0; i < 8; ++i) x[i] = (float)hv[i];
    float s = 0.f, ss = 0.f;
#pragma unroll
    for (int i = 0; i < 8; ++i) { s += x[i]; ss = fmaf(x[i], x[i], ss); }
#pragma unroll
    for (int off = 32; off > 0; off >>= 1) {
        s  += __shfl_xor(s, off);
        ss += __shfl_xor(ss, off);
    }
    float mean = s * (1.0f / 512.0f);
    float var  = ss * (1.0f / 512.0f) - mean * mean;
    float rs = rsqrtf(var + 1e-5f);
    const float* wp = w + lane * 8;
    const float* bp = b + lane * 8;
    float4 w0 = *(const float4*)wp, w1 = *(const float4*)(wp + 4);
    float4 b0 = *(const float4*)bp, b1 = *(const float4*)(bp + 4);
    float wv[8] = {w0.x, w0.y, w0.z, w0.w, w1.x, w1.y, w1.z, w1.w};
    float bv[8] = {b0.x, b0.y, b0.z, b0.w, b1.x, b1.y, b1.z, b1.w};
    f16x8 h;
#pragma unroll
    for (int i = 0; i < 8; ++i) h[i] = (f16)((x[i] - mean) * rs * wv[i] + bv[i]);
    *(f16x8*)(out + (size_t)row * D_ + lane * 8) = h;
}

// ---- fused depthwise conv + LayerNorm, t-tiled via LDS, f16 trunk input (r13-proven) ----
__global__ __launch_bounds__(256) void k_dwln2h(const f16* __restrict__ x,
                                                const float* __restrict__ dwT,
                                                const float* __restrict__ db,
                                                const float* __restrict__ nw,
                                                const float* __restrict__ nb,
                                                f16* __restrict__ out) {
    __shared__ float xs[22][512];
    int tid = threadIdx.x;
    int blk = blockIdx.x;            // b*128 + tc
    int b = blk >> 7;
    int t0 = (blk & 127) << 4;
    const f16* xb = x + ((size_t)b << 20);     // b * T_ * D_ (f16)
#pragma unroll
    for (int i = 0; i < 6; ++i) {
        int idx = tid + (i << 8);    // chunk of 8 f16 over 22*64
        if (idx < 22 * 64) {
            int row = idx >> 6;
            int c8 = idx & 63;
            int t = t0 + row - 3;
            float v[8];
            if (t >= 0 && t < T_) {
                f16x8 hv = *(const f16x8*)(xb + ((size_t)t << 9) + (c8 << 3));
#pragma unroll
                for (int u = 0; u < 8; ++u) v[u] = (float)hv[u];
            } else {
#pragma unroll
                for (int u = 0; u < 8; ++u) v[u] = 0.0f;
            }
            *(float4*)&xs[row][c8 << 3] = make_float4(v[0], v[1], v[2], v[3]);
            *(float4*)&xs[row][(c8 << 3) + 4] = make_float4(v[4], v[5], v[6], v[7]);
        }
    }
    __syncthreads();

    int o = tid & 63;          // d-octet
    int slot = tid >> 6;       // wave id = t-group
    int d0 = o << 3;
    float acc[4][8];
    {
        float4 b0 = *(const float4*)(db + d0);
        float4 b1 = *(const float4*)(db + d0 + 4);
#pragma unroll
        for (int u = 0; u < 4; ++u) {
            acc[u][0] = b0.x; acc[u][1] = b0.y; acc[u][2] = b0.z; acc[u][3] = b0.w;
            acc[u][4] = b1.x; acc[u][5] = b1.y; acc[u][6] = b1.z; acc[u][7] = b1.w;
        }
    }
#pragma unroll
    for (int k = 0; k < 7; ++k) {
        float w8[8];
        *(float4*)&w8[0] = *(const float4*)(dwT + (k << 9) + d0);
        *(float4*)&w8[4] = *(const float4*)(dwT + (k << 9) + d0 + 4);
#pragma unroll
        for (int u = 0; u < 4; ++u) {
            int row = (slot << 2) + u + k;   // t_local + k, in [0,21]
            float x8[8];
            *(float4*)&x8[0] = *(const float4*)&xs[row][d0];
            *(float4*)&x8[4] = *(const float4*)&xs[row][d0 + 4];
#pragma unroll
            for (int i = 0; i < 8; ++i) acc[u][i] = fmaf(w8[i], x8[i], acc[u][i]);
        }
    }
    float4 w0 = *(const float4*)(nw + d0), w1 = *(const float4*)(nw + d0 + 4);
    float4 n0 = *(const float4*)(nb + d0), n1 = *(const float4*)(nb + d0 + 4);
    float nwv[8] = {w0.x, w0.y, w0.z, w0.w, w1.x, w1.y, w1.z, w1.w};
    float nbv[8] = {n0.x, n0.y, n0.z, n0.w, n1.x, n1.y, n1.z, n1.w};
#pragma unroll
    for (int u = 0; u < 4; ++u) {
        float s = 0.f, ss = 0.f;
#pragma unroll
        for (int i = 0; i < 8; ++i) { s += acc[u][i]; ss = fmaf(acc[u][i], acc[u][i], ss); }
#pragma unroll
        for (int off = 32; off > 0; off >>= 1) {
            s  += __shfl_xor(s, off);
            ss += __shfl_xor(ss, off);
        }
        float mean = s * (1.0f / 512.0f);
        float var  = ss * (1.0f / 512.0f) - mean * mean;
        float rs = rsqrtf(var + 1e-5f);
        f16x8 h;
#pragma unroll
        for (int i = 0; i < 8; ++i)
            h[i] = (f16)((acc[u][i] - mean) * rs * nwv[i] + nbv[i]);
        int t = t0 + (slot << 2) + u;
        *(f16x8*)(out + (((size_t)(b << 11) + t) << 9) + d0) = h;
    }
}

#define MF(d, a, b) d = __builtin_amdgcn_mfma_f32_16x16x32_f16(a, b, d, 0, 0, 0)

// ---- fp16 MFMA GEMM v5 (r6-r16-proven): 128x128, BK=32, 3-ring, vmcnt(4) ----
// EMBED=true reads A through the melTp im2col view (lda=192).
// EPI: 1 = f16 gelu (pw1) ; 4 = f16 +bias (embed) ; 5 = f16 residual RMW (pw2) ;
//      6 = fused head->S (interleaved cols, shfl_xor(1), writes S f16 directly)
#define TSZ_ 4096   // f16 elems per matrix tile (128x32)

__device__ __forceinline__ void stage32(const f16* __restrict__ g, f16* s,
                                        int lda, int kof, int tid) {
    int dr0 = tid >> 3;        // 0..31
    int sl  = tid & 7;
#pragma unroll
    for (int i = 0; i < 2; ++i) {
        int d  = dr0 + (i << 5);           // double-row 0..63
        int gs = sl ^ (d & 7);             // pre-swizzled global slot
        int row = (d << 1) + (gs >> 2);
        int kc  = gs & 3;
        gload16(g + (size_t)row * lda + kof + (kc << 3),
                s + (d << 6) + (sl << 3)); // linear dest: wave base + lane*16B
    }
}

template <int EPI, bool EMBED>
__global__ __launch_bounds__(256, 3) void k_hgemm5(const f16* __restrict__ A,
                                                   const f16* __restrict__ W,
                                                   const float* __restrict__ bias,
                                                   const float* __restrict__ gamma,
                                                   void* __restrict__ C,
                                                   int K, int ldc, int nNt) {
    __shared__ f16 lds[3 * 2 * TSZ_];
    int tid = threadIdx.x;
    int nwg = gridDim.x, bid = blockIdx.x;
    int q = nwg >> 3, r = nwg & 7;
    int xcd = bid & 7, lin = bid >> 3;
    int swz = (xcd < r ? xcd * (q + 1) : r * (q + 1) + (xcd - r) * q) + lin;
    int bm = (swz / nNt) << 7;
    int bn = (swz % nNt) << 7;
    const f16* gA;
    int lda;
    if constexpr (EMBED) {
        gA = A + ((size_t)((bm >> 11) * TP_) + (bm & (T_ - 1))) * CM_;
        lda = CM_;
    } else {
        gA = A + (size_t)bm * K;
        lda = K;
    }
    const f16* gW = W + (size_t)bn * K;

    int l = tid & 63;
    int wv = tid >> 6;
    int wm = (wv & 1) << 6;    // 2 wave-rows of 64
    int wn = (wv >> 1) << 6;   // 2 wave-cols of 64
    int lr = l & 15;
    int lk = l >> 4;
    int lrh = lr >> 1;
    int s0l = ((lr & 1) << 2) | lk;   // logical slot for this lane's (row-half, chunk)

    int offA[4], offB[4];
#pragma unroll
    for (int i = 0; i < 4; ++i) {
        int dA = (wm >> 1) + i * 8 + lrh;
        offA[i] = (dA << 6) + ((s0l ^ (dA & 7)) << 3);
        int dB = (wn >> 1) + i * 8 + lrh;
        offB[i] = (dB << 6) + ((s0l ^ (dB & 7)) << 3);
    }

    f32x4 acc[4][4];
#pragma unroll
    for (int i = 0; i < 4; ++i)
#pragma unroll
        for (int j = 0; j < 4; ++j) acc[i][j] = {0.f, 0.f, 0.f, 0.f};

    int nk = K >> 5;
    f16* s0 = lds;
    f16* s1 = lds + 2 * TSZ_;
    f16* s2 = lds + 4 * TSZ_;

    stage32(gA, s0, lda, 0, tid);      stage32(gW, s0 + TSZ_, K, 0, tid);
    stage32(gA, s1, lda, 32, tid);     stage32(gW, s1 + TSZ_, K, 32, tid);
    asm volatile("s_waitcnt vmcnt(4)" ::: "memory");
    __builtin_amdgcn_s_barrier();

    for (int t = 0; t < nk; ++t) {
        bool stg = (t + 2 < nk);
        if (stg) {
            int ko = (t + 2) << 5;
            stage32(gA, s2, lda, ko, tid);
            stage32(gW, s2 + TSZ_, K, ko, tid);
        }
        f16x8 af[4], bf[4];
#pragma unroll
        for (int i = 0; i < 4; ++i) af[i] = *(const f16x8*)(s0 + offA[i]);
#pragma unroll
        for (int j = 0; j < 4; ++j) bf[j] = *(const f16x8*)(s0 + TSZ_ + offB[j]);
        __builtin_amdgcn_s_setprio(1);
#pragma unroll
        for (int i = 0; i < 4; ++i)
#pragma unroll
            for (int j = 0; j < 4; ++j) MF(acc[i][j], af[i], bf[j]);
        __builtin_amdgcn_s_setprio(0);
        if (stg)               asm volatile("s_waitcnt vmcnt(4)" ::: "memory");
        else if (t + 1 < nk)   asm volatile("s_waitcnt vmcnt(0)" ::: "memory");
        if (t + 1 < nk) {
            __builtin_amdgcn_s_barrier();
            asm volatile("" ::: "memory");
        }
        f16* tmp = s0; s0 = s1; s1 = s2; s2 = tmp;
    }

    int lk4 = lk << 2;
#pragma unroll
    for (int i = 0; i < 4; ++i) {
#pragma unroll
        for (int rr = 0; rr < 4; ++rr) {
            int row = bm + wm + i * 16 + lk4 + rr;
            size_t moff = (size_t)row * ldc;
#pragma unroll
            for (int j = 0; j < 4; ++j) {
                int col = bn + wn + j * 16 + lr;
                float v = acc[i][j][rr];
                if constexpr (EPI == 1) {
                    ((f16*)C)[moff + col] = (f16)gelu_f(v + bias[col]);
                } else if constexpr (EPI == 4) {
                    ((f16*)C)[moff + col] = (f16)(v + bias[col]);
                } else if constexpr (EPI == 5) {
                    f16* Cp = (f16*)C;
                    float old = (float)Cp[moff + col];
                    Cp[moff + col] = (f16)(old + gamma[col] * (v + bias[col]));
                } else if constexpr (EPI == 6) {
                    // fused srsi: col parity = lr parity; partner lane holds col^1
                    float vb = v + bias[col];
                    float w2 = __shfl_xor(vb, 1);
                    float a = (lr & 1) ? w2 : vb;   // log-magnitude
                    float bph = (lr & 1) ? vb : w2; // phase
                    float mag = fminf(__expf(a), 100.0f);
                    float sn, cs;
                    __sincosf(bph, &sn, &cs);
                    float sval = (lr & 1) ? mag * sn : mag * cs;
                    int f = col >> 1;
                    int dst = (lr & 1) ? (NF_ + f) : f;
                    if (col < NO2_)
                        ((f16*)C)[moff + dst] = (f16)sval;
                } else {
                    ((f16*)C)[moff + col] = (f16)(v * bias[col]);
                }
            }
        }
    }
}

// ---- fp16 MFMA GEMM v7 (r11-r16-proven): 256x128 block, wave 128x64, vmcnt(6) ----
// Routed ONLY to istft (grid 512 = exactly 2 blocks/CU x 256 CU, zero tail).
#define ASZ_ 8192   // f16 elems per A tile (256x32)
#define RSZ_ 12288  // ring slot (A + B)

__device__ __forceinline__ void stageA256(const f16* __restrict__ g, f16* s,
                                          int K, int kof, int tid) {
    int dr0 = tid >> 3;        // 0..31
    int sl  = tid & 7;
#pragma unroll
    for (int i = 0; i < 4; ++i) {
        int d  = dr0 + (i << 5);           // double-row 0..127
        int gs = sl ^ (d & 7);
        int row = (d << 1) + (gs >> 2);    // 0..255
        int kc  = gs & 3;
        gload16(g + (size_t)row * K + kof + (kc << 3),
                s + (d << 6) + (sl << 3));
    }
}

__device__ __forceinline__ void stageB128(const f16* __restrict__ g, f16* s,
                                          int K, int kof, int tid) {
    int dr0 = tid >> 3;
    int sl  = tid & 7;
#pragma unroll
    for (int i = 0; i < 2; ++i) {
        int d  = dr0 + (i << 5);           // double-row 0..63
        int gs = sl ^ (d & 7);
        int row = (d << 1) + (gs >> 2);    // 0..127
        int kc  = gs & 3;
        gload16(g + (size_t)row * K + kof + (kc << 3),
                s + (d << 6) + (sl << 3));
    }
}

template <int EPI>
__global__ __launch_bounds__(256, 2) void k_hgemm7(const f16* __restrict__ A,
                                                   const f16* __restrict__ W,
                                                   const float* __restrict__ bias,
                                                   const float* __restrict__ gamma,
                                                   void* __restrict__ C,
                                                   int K, int ldc, int nNt) {
    __shared__ f16 lds[3 * RSZ_];
    int tid = threadIdx.x;
    int nwg = gridDim.x, bid = blockIdx.x;
    int q = nwg >> 3, r = nwg & 7;
    int xcd = bid & 7, lin = bid >> 3;
    int swz = (xcd < r ? xcd * (q + 1) : r * (q + 1) + (xcd - r) * q) + lin;
    int bm = (swz / nNt) << 8;      // 256-row M tiles
    int bn = (swz % nNt) << 7;      // 128-col N tiles
    const f16* gA = A + (size_t)bm * K;
    const f16* gW = W + (size_t)bn * K;

    int l = tid & 63;
    int wv = tid >> 6;
    int wm = (wv & 1) << 7;    // 2 wave-rows of 128
    int wn = (wv >> 1) << 6;   // 2 wave-cols of 64
    int lr = l & 15;
    int lk = l >> 4;
    int lrh = lr >> 1;
    int s0l = ((lr & 1) << 2) | lk;

    int offA[8], offB[4];
#pragma unroll
    for (int i = 0; i < 8; ++i) {
        int dA = (wm >> 1) + i * 8 + lrh;           // double-row 0..127
        offA[i] = (dA << 6) + ((s0l ^ (dA & 7)) << 3);
    }
#pragma unroll
    for (int j = 0; j < 4; ++j) {
        int dB = (wn >> 1) + j * 8 + lrh;           // double-row 0..63
        offB[j] = (dB << 6) + ((s0l ^ (dB & 7)) << 3);
    }

    f32x4 acc[8][4];
#pragma unroll
    for (int i = 0; i < 8; ++i)
#pragma unroll
        for (int j = 0; j < 4; ++j) acc[i][j] = {0.f, 0.f, 0.f, 0.f};

    int nk = K >> 5;
    f16* s0 = lds;
    f16* s1 = lds + RSZ_;
    f16* s2 = lds + 2 * RSZ_;

    stageA256(gA, s0, K, 0, tid);      stageB128(gW, s0 + ASZ_, K, 0, tid);
    stageA256(gA, s1, K, 32, tid);     stageB128(gW, s1 + ASZ_, K, 32, tid);
    asm volatile("s_waitcnt vmcnt(6)" ::: "memory");
    __builtin_amdgcn_s_barrier();

    for (int t = 0; t < nk; ++t) {
        bool stg = (t + 2 < nk);
        if (stg) {
            int ko = (t + 2) << 5;
            stageA256(gA, s2, K, ko, tid);
            stageB128(gW, s2 + ASZ_, K, ko, tid);
        }
        f16x8 af[8], bf[4];
#pragma unroll
        for (int i = 0; i < 8; ++i) af[i] = *(const f16x8*)(s0 + offA[i]);
#pragma unroll
        for (int j = 0; j < 4; ++j) bf[j] = *(const f16x8*)(s0 + ASZ_ + offB[j]);
        __builtin_amdgcn_s_setprio(1);
#pragma unroll
        for (int i = 0; i < 8; ++i)
#pragma unroll
            for (int j = 0; j < 4; ++j) MF(acc[i][j], af[i], bf[j]);
        __builtin_amdgcn_s_setprio(0);
        if (stg)               asm volatile("s_waitcnt vmcnt(6)" ::: "memory");
        else if (t + 1 < nk)   asm volatile("s_waitcnt vmcnt(0)" ::: "memory");
        if (t + 1 < nk) {
            __builtin_amdgcn_s_barrier();
            asm volatile("" ::: "memory");
        }
        f16* tmp = s0; s0 = s1; s1 = s2; s2 = tmp;
    }

    int lk4 = lk << 2;
#pragma unroll
    for (int i = 0; i < 8; ++i) {
#pragma unroll
        for (int rr = 0; rr < 4; ++rr) {
            int row = bm + wm + i * 16 + lk4 + rr;
            size_t moff = (size_t)row * ldc;
#pragma unroll
            for (int j = 0; j < 4; ++j) {
                int col = bn + wn + j * 16 + lr;
                float v = acc[i][j][rr];
                if constexpr (EPI == 0) {
                    ((float*)C)[moff + col] = v + bias[col];
                } else {
                    ((f16*)C)[moff + col] = (f16)(v * bias[col]);
                }
            }
        }
    }
}

// ---------------- overlap-add + win_env + crop (deterministic gather, f16 frames) ------
__global__ __launch_bounds__(256) void k_gather(const f16* __restrict__ frames,
                                                const float* __restrict__ win,
                                                float* __restrict__ out) {
    int idx = blockIdx.x * 256 + threadIdx.x;
    int b  = idx / LOUT_;
    int lp = idx - b * LOUT_;
    int l = lp + (NFFT_ / 2);
    int thi = l >> 8;
    if (thi > T_ - 1) thi = T_ - 1;
    int tlo = l - (NFFT_ - 1) + (HOP_ - 1);
    tlo = (tlo < 0) ? 0 : (tlo >> 8);
    float num = 0.0f, den = 0.0f;
    for (int t = tlo; t <= thi; ++t) {
        int n = l - (t << 8);
        float wv = win[n];
        num += (float)frames[((size_t)(b * T_ + t) << 10) + n];
        den = fmaf(wv, wv, den);
    }
    out[idx] = num / (den + 1e-11f);
}

// ---------------- launch ----------------
extern "C" void kernel_launch(void* const* d_in, const int* in_sizes, int n_in,
                              void* d_out, int out_size, void* d_ws, size_t ws_size,
                              hipStream_t stream) {
    (void)in_sizes; (void)n_in; (void)out_size; (void)ws_size;
    const float* mel     = (const float*)d_in[0];
    const float* embed_w = (const float*)d_in[1];
    const float* embed_b = (const float*)d_in[2];
    const float* norm_w  = (const float*)d_in[3];
    const float* norm_b  = (const float*)d_in[4];
    const float* bdw = (const float*)d_in[5];
    const float* bdb = (const float*)d_in[6];
    const float* bnw = (const float*)d_in[7];
    const float* bnb = (const float*)d_in[8];
    const float* bw1 = (const float*)d_in[9];
    const float* bb1 = (const float*)d_in[10];
    const float* bw2 = (const float*)d_in[11];
    const float* bb2 = (const float*)d_in[12];
    const float* bg  = (const float*)d_in[13];
    const float* fnw = (const float*)d_in[14];
    const float* fnb = (const float*)d_in[15];
    const float* hw  = (const float*)d_in[16];
    const float* hb  = (const float*)d_in[17];
    const float* win = (const float*)d_in[18];

    char* ws = (char*)d_ws;
    // region A: [0, 50.3MB): xbuf_h f16 trunk [0,16.8MB); ybuf_h at +33.5MB;
    // S_h overlays base after final LN consumes xbuf_h (r13-r16-proven liveness).
    f16*   xbuf_h = (f16*)ws;
    f16*   ybuf_h = (f16*)(ws + 33554432);
    f16*   S_h    = (f16*)ws;
    // region R: [50.3MB, 134.2MB): melTp at base (dead after embed GEMM);
    // frames_h at base later; hbuf_h at +33.5MB.
    char* R = ws + 50331648;
    f16*   melTp  = (f16*)R;                      // 6,309,888 B
    f16*   hbuf_h = (f16*)(R + 33554432);
    f16*   frames_h = (f16*)R;
    // region W: [134.2MB, ...): converted weights (proven envelope)
    char* Wr = ws + 134217728;
    f16*   w1_h   = (f16*)Wr;                     // 12,582,912
    f16*   w2_h   = (f16*)(Wr + 12582912);        // 12,582,912
    f16*   head_h = (f16*)(Wr + 25165824);        // 1,179,648
    f16*   wmat_h = (f16*)(Wr + 26345472);        // 2,228,224
    f16*   we_h   = (f16*)(Wr + 28573696);        // 1,376,256
    float* hb_pad = (float*)(Wr + 29949952);      // 4,608
    float* dwT    = (float*)(Wr + 29954560);      // 114,688

    // fused prep: 2,282,256 chunks -> 8916 blocks
    k_prep<<<8916, 256, 0, stream>>>(bw1, bw2, embed_w, hw, hb, bdw, mel,
                                     w1_h, w2_h, we_h, head_h, hb_pad, dwT,
                                     wmat_h, melTp);

    // embed conv: GEMM directly over the melTp im2col view (lda=192, K=1344)
    k_hgemm5<4, true><<<128 * 4, 256, 0, stream>>>(melTp, we_h, embed_b, nullptr, xbuf_h,
                                                   KE_, D_, 4);
    k_lnh<<<BT_, 64, 0, stream>>>(xbuf_h, xbuf_h, norm_w, norm_b);

    for (int bl = 0; bl < 8; ++bl) {
        k_dwln2h<<<B_ * 128, 256, 0, stream>>>(xbuf_h, dwT + bl * 3584, bdb + bl * D_,
                                               bnw + bl * D_, bnb + bl * D_, ybuf_h);
        k_hgemm5<1, false><<<128 * 12, 256, 0, stream>>>(ybuf_h, w1_h + (size_t)bl * H_ * D_,
                                                         bb1 + bl * H_, nullptr, hbuf_h,
                                                         D_, H_, 12);
        k_hgemm5<5, false><<<128 * 4, 256, 0, stream>>>(hbuf_h, w2_h + (size_t)bl * D_ * H_,
                                                        bb2 + bl * D_, bg + bl * D_, xbuf_h,
                                                        H_, D_, 4);
    }

    k_lnh<<<BT_, 64, 0, stream>>>(xbuf_h, ybuf_h, fnw, fnb);
    // head GEMM with fused srsi epilogue: writes S (f16, stride KI_) directly
    k_hgemm5<6, false><<<128 * 9, 256, 0, stream>>>(ybuf_h, head_h, hb_pad, nullptr, S_h,
                                                    D_, KI_, 9);
    k_hgemm7<3><<<64 * 8, 256, 0, stream>>>(S_h, wmat_h, win, nullptr, frames_h,
                                            KI_, NFFT_, 8);
    k_gather<<<B_ * LOUT_ / 256, 256, 0, stream>>>(frames_h, win, (float*)d_out);
}